// Round 12
// baseline (658.020 us; speedup 1.0000x reference)
//
#include <hip/hip_runtime.h>
#include <hip/hip_bf16.h>
#include <math.h>

#define EMB 768
#define NTOK 654
#define NPATCH 576
#define NTEXT 77
#define NBATCH 32
#define HD 384
#define MROWS (NBATCH * NTOK)   // 20928
#define KPAD 656                 // V^T row length (u16), 16B-aligned rows
#define LN_EPS 1e-5f
#define INV_SQRT_EMB 0.03608439182435161f

typedef unsigned int u32;
typedef unsigned short u16;
typedef float f32x4 __attribute__((ext_vector_type(4)));
typedef __bf16 bf16x8 __attribute__((ext_vector_type(8)));

union BF8 { uint4 u4; u32 w[4]; bf16x8 v; };

// async global->LDS, 16B per lane; dest = wave-uniform base + lane*16
#define GLL(gsrc, ldst) __builtin_amdgcn_global_load_lds( \
    (const __attribute__((address_space(1))) unsigned int*)(gsrc), \
    (__attribute__((address_space(3))) unsigned int*)(ldst), 16, 0, 0)

// ---------------- helpers ----------------
__device__ __forceinline__ float bf2f(u16 u) {
    union { u32 i; float f; } x; x.i = ((u32)u) << 16; return x.f;
}
__device__ __forceinline__ u16 f2bf(float f) {  // RTNE
    union { float f; u32 i; } x; x.f = f;
    u32 r = x.i + 0x7fffu + ((x.i >> 16) & 1u);
    return (u16)(r >> 16);
}
__device__ __forceinline__ u32 pk2(float lo, float hi) {
    return (u32)f2bf(lo) | ((u32)f2bf(hi) << 16);
}
__device__ __forceinline__ float blk_sum(float v, float* red, int tid) {
    red[tid] = v; __syncthreads();
    #pragma unroll
    for (int s = 128; s > 0; s >>= 1) {
        if (tid < s) red[tid] += red[tid + s];
        __syncthreads();
    }
    float r = red[0]; __syncthreads();
    return r;
}
__device__ __forceinline__ f32x4 mfma16(bf16x8 a, bf16x8 b, f32x4 c) {
    return __builtin_amdgcn_mfma_f32_16x16x32_bf16(a, b, c, 0, 0, 0);
}

// ---------------- weight transpose + bf16: Wt[n][k] = bf16(W[k][n]) ----------------
__global__ __launch_bounds__(256)
void wt_kernel(const float* __restrict__ W0, const float* __restrict__ W1,
               const float* __restrict__ W2, const float* __restrict__ W3,
               const float* __restrict__ W4, u16* __restrict__ dst)
{
    __shared__ float tile[32][33];
    const int z = blockIdx.z;
    const float* W = (z == 0) ? W0 : (z == 1) ? W1 : (z == 2) ? W2 : (z == 3) ? W3 : W4;
    u16* o = dst + (size_t)z * EMB * EMB;
    const int bi = blockIdx.y, bj = blockIdx.x;
    const int r = threadIdx.x >> 5, c = threadIdx.x & 31;
    #pragma unroll
    for (int i = 0; i < 4; i++)
        tile[r + i * 8][c] = W[(long)(bi * 32 + r + i * 8) * EMB + bj * 32 + c];
    __syncthreads();
    #pragma unroll
    for (int i = 0; i < 4; i++) {
        const int rr = r + i * 8;
        o[(long)(bj * 32 + rr) * EMB + bi * 32 + c] = f2bf(tile[c][rr]);
    }
}

// ---------------- fill cls + text rows of t (bf16) ----------------
__global__ __launch_bounds__(256)
void fill_rows_kernel(const float* __restrict__ cls, const float* __restrict__ text,
                      u16* __restrict__ t)
{
    const int b = blockIdx.y, r = blockIdx.x;
    const int tid = threadIdx.x;
    const long trow = (long)b * NTOK + (r == 0 ? 0 : NPATCH + r);
    const float* src = (r == 0) ? cls : text + ((long)b * NTEXT + (r - 1)) * EMB;
    u16* dst = t + trow * EMB;
    #pragma unroll
    for (int s = 0; s < 3; s++) dst[tid + s * 256] = f2bf(src[tid + s * 256]);
}

// ---------------- im2col: x[32,3,384,384] fp32 -> patches[18432][768] bf16 -----------
__global__ __launch_bounds__(384)
void im2col_kernel(const float* __restrict__ x, u16* __restrict__ patches)
{
    const int t = threadIdx.x;              // 0..383 = image column
    const int hh = blockIdx.y;              // 0..23
    const int gx = blockIdx.x;              // 0..511 = bb*16 + p1
    const int bb = gx >> 4, p1 = gx & 15;
    const int ww = t >> 4, p2 = t & 15;
    u16* dst = patches + ((long)(bb * NPATCH + hh * 24 + ww) * EMB) + (p1 * 16 + p2) * 3;
    #pragma unroll
    for (int c = 0; c < 3; c++) {
        const float f = x[((long)(bb * 3 + c) * 384 + hh * 16 + p1) * 384 + t];
        dst[c] = f2bf(f);
    }
}

// ---------------- LN1: t(bf16) -> h(bf16) ----------------
__global__ __launch_bounds__(256)
void ln_h_kernel(const u16* __restrict__ t, u16* __restrict__ h,
                 const float* __restrict__ g, const float* __restrict__ be)
{
    __shared__ float red[256];
    const int row = blockIdx.x, tid = threadIdx.x;
    const u16* xp = t + (long)row * EMB;
    const float v0 = bf2f(xp[tid]), v1 = bf2f(xp[tid + 256]), v2 = bf2f(xp[tid + 512]);
    const float mu = blk_sum(v0 + v1 + v2, red, tid) * (1.f / EMB);
    const float d0 = v0 - mu, d1 = v1 - mu, d2 = v2 - mu;
    const float var = blk_sum(d0 * d0 + d1 * d1 + d2 * d2, red, tid) * (1.f / EMB);
    const float rs = rsqrtf(var + LN_EPS);
    u16* o = h + (long)row * EMB;
    o[tid]       = f2bf(d0 * rs * g[tid]       + be[tid]);
    o[tid + 256] = f2bf(d1 * rs * g[tid + 256] + be[tid + 256]);
    o[tid + 512] = f2bf(d2 * rs * g[tid + 512] + be[tid + 512]);
}

// ---------------- V transpose: v[b][tok][h*384+dv] -> vt[bh][dv][tok(pad 656)] -------
__global__ __launch_bounds__(256)
void vtrans_kernel(const u16* __restrict__ v, u16* __restrict__ vt)
{
    __shared__ u16 tile[32][33];
    const int bh = blockIdx.z, b = bh >> 1, h = bh & 1;
    const int t0 = blockIdx.x * 32, d0 = blockIdx.y * 32;
    const int r = threadIdx.x >> 5, c = threadIdx.x & 31;
    #pragma unroll
    for (int i = 0; i < 4; i++) {
        const int tok = t0 + r + i * 8;
        tile[r + i * 8][c] = (tok < NTOK)
            ? v[(long)(b * NTOK + tok) * EMB + h * HD + d0 + c] : (u16)0;
    }
    __syncthreads();
    const int tok = t0 + c;
    if (tok < KPAD) {
        #pragma unroll
        for (int i = 0; i < 4; i++) {
            const int dv = d0 + r + i * 8;
            const u16 val = (tok < NTOK) ? tile[c][r + i * 8] : (u16)0;
            vt[(long)bh * HD * KPAD + (long)dv * KPAD + tok] = val;
        }
    }
}

// ---------------- dense MFMA GEMM v3: GLL dbuf + counted vmcnt + RAW barriers --------
#define DBK 64
#define DTILE_B (128 * DBK * 2)   // 16384 B per operand tile

template<bool OBF16, bool REMAP>
__global__ __launch_bounds__(256)
void dense_gemm(const u16* __restrict__ A, const u16* __restrict__ Bt,
                const float* __restrict__ b0, const float* __restrict__ b1,
                const float* __restrict__ b2,
                void* __restrict__ C0, void* __restrict__ C1, void* __restrict__ C2,
                int M, int nb)
{
    extern __shared__ char sm[];   // [2][A|B][128][64]u16 = 65536 B
    const int cpx = gridDim.x >> 3;
    const int wg = blockIdx.x;
    const int work = (wg & 7) * cpx + (wg >> 3);
    const int cb = work % nb;
    const int m0 = (work / nb) * 128;
    const int z  = cb / 6;
    const int n0 = (cb % 6) * 128;
    const u16* Btz = Bt + (size_t)z * EMB * EMB;
    const float* bias = (z == 0) ? b0 : (z == 1) ? b1 : b2;
    void* Cz = (z == 0) ? C0 : (z == 1) ? C1 : C2;

    const int tid = threadIdx.x;
    const int lane = tid & 63, w = tid >> 6, wr = w >> 1, wc = w & 1;
    const int l15 = lane & 15, g = lane >> 4;
    const int wbase = (tid & ~63);

    f32x4 acc[4][4] = {};

    auto stage = [&](int k0, int buf) {
        char* dst = sm + buf * 2 * DTILE_B;
        #pragma unroll
        for (int c = 0; c < 4; c++) {
            const int idx = c * 256 + tid;
            const int r = idx >> 3, s = idx & 7;
            const int gs = s ^ (r & 7);
            const int ar = min(m0 + r, M - 1);
            GLL(A + (long)ar * EMB + k0 + gs * 8, dst + (c * 256 + wbase) * 16);
        }
        #pragma unroll
        for (int c = 0; c < 4; c++) {
            const int idx = c * 256 + tid;
            const int r = idx >> 3, s = idx & 7;
            const int gs = s ^ (r & 7);
            GLL(Btz + (long)(n0 + r) * EMB + k0 + gs * 8,
                dst + DTILE_B + (c * 256 + wbase) * 16);
        }
    };

    stage(0, 0);
    for (int t = 0; t < 12; t++) {
        if (t < 11) {
            stage((t + 1) * DBK, (t + 1) & 1);
            asm volatile("s_waitcnt vmcnt(8)" ::: "memory");   // tile t landed; t+1 in flight
        } else {
            asm volatile("s_waitcnt vmcnt(0)" ::: "memory");
        }
        __builtin_amdgcn_s_barrier();          // all waves' tile-t loads landed
        __builtin_amdgcn_sched_barrier(0);
        const char* Asb = sm + (t & 1) * 2 * DTILE_B;
        const char* Bsb = Asb + DTILE_B;
        #pragma unroll
        for (int ks = 0; ks < 2; ks++) {
            BF8 af[4], bfr[4];
            #pragma unroll
            for (int mi = 0; mi < 4; mi++) {
                const int row = wr * 64 + mi * 16 + l15;
                const int slot = (ks * 4 + g) ^ (row & 7);
                af[mi].u4 = *(const uint4*)(Asb + row * 128 + slot * 16);
            }
            #pragma unroll
            for (int nj = 0; nj < 4; nj++) {
                const int row = wc * 64 + nj * 16 + l15;
                const int slot = (ks * 4 + g) ^ (row & 7);
                bfr[nj].u4 = *(const uint4*)(Bsb + row * 128 + slot * 16);
            }
            __builtin_amdgcn_s_setprio(1);
            #pragma unroll
            for (int mi = 0; mi < 4; mi++)
                #pragma unroll
                for (int nj = 0; nj < 4; nj++)
                    acc[mi][nj] = mfma16(af[mi].v, bfr[nj].v, acc[mi][nj]);
            __builtin_amdgcn_s_setprio(0);
        }
        __builtin_amdgcn_s_barrier();          // all waves done reading buf t&1
        __builtin_amdgcn_sched_barrier(0);
    }

    float bv[4];
    #pragma unroll
    for (int nj = 0; nj < 4; nj++) bv[nj] = bias[n0 + wc * 64 + nj * 16 + l15];
    #pragma unroll
    for (int mi = 0; mi < 4; mi++) {
        #pragma unroll
        for (int rr = 0; rr < 4; rr++) {
            const int r = m0 + wr * 64 + mi * 16 + 4 * g + rr;
            if (r >= M) continue;
            long orow = r;
            if (REMAP) orow = (long)(r / NPATCH) * NTOK + 1 + (r % NPATCH);
            #pragma unroll
            for (int nj = 0; nj < 4; nj++) {
                const int cc = n0 + wc * 64 + nj * 16 + l15;
                const float val = acc[mi][nj][rr] + bv[nj];
                if (OBF16) ((u16*)Cz)[orow * EMB + cc] = f2bf(val);
                else       ((float*)Cz)[orow * EMB + cc] = val;
            }
        }
    }
}

// ---------------- flash attention v10: barrier-free, L2-direct operands --------------
// 2624 independent wave-items (64 bh x 41 q-tiles of 16 rows); 656 blocks x 4 waves.
// K-frags and V^T-frags are direct global b128 loads (L2-resident: ~1MB/bh, 8bh/XCD,
// streaming window ~800KB << 4MB L2). No __syncthreads anywhere; Ps roundtrip is
// wave-private (lgkmcnt only). LDS = 5KB/block.
#define PSLD 40   // Ps row stride (u16)

__global__ __launch_bounds__(256)
void flash_mfma(const u16* __restrict__ q, const u16* __restrict__ k,
                const u16* __restrict__ vt, u16* __restrict__ o)
{
    __shared__ u16 Ps[4 * 16 * PSLD];   // per-wave private slices

    const int tid = threadIdx.x;
    const int lane = tid & 63, w = tid >> 6;
    const int l15 = lane & 15, g = lane >> 4;
    // XCD-bijective: 656 = 8 * 82; 4 waves of a block take consecutive work items
    const int wg = blockIdx.x;
    const int work = (wg & 7) * 82 + (wg >> 3);
    const int wid = work * 4 + w;
    const int bh = wid / 41, qt = wid % 41;
    const int b = bh >> 1, h = bh & 1;
    const int q0 = qt * 16;
    const long baseQ = (long)b * NTOK * EMB + h * HD;
    const long baseV = (long)bh * HD * KPAD;

    // Q fragments in registers: 12 d-steps of 32 (lane l15 = q-col of the B-operand)
    BF8 qf[12];
    {
        const int qrow = min(q0 + l15, NTOK - 1);
        const u16* src = q + baseQ + (long)qrow * EMB;
        #pragma unroll
        for (int ds = 0; ds < 12; ds++)
            qf[ds].u4 = *(const uint4*)(src + ds * 32 + g * 8);
    }

    float m_run = -3.0e38f, l_run = 0.f;
    f32x4 oacc[24] = {};

    for (int kt = 0; kt < 21; kt++) {
        const int kv0 = kt * 32;

        // ---- S^T = K @ Q^T : K-frags direct from global (L2) ----
        const u16* kp0 = k + baseQ + (long)min(kv0 + l15, NTOK - 1) * EMB;
        const u16* kp1 = k + baseQ + (long)min(kv0 + 16 + l15, NTOK - 1) * EMB;
        f32x4 sacc[2] = {};
        #pragma unroll
        for (int ds = 0; ds < 12; ds++) {
            BF8 ak0, ak1;
            ak0.u4 = *(const uint4*)(kp0 + ds * 32 + g * 8);
            ak1.u4 = *(const uint4*)(kp1 + ds * 32 + g * 8);
            sacc[0] = mfma16(ak0.v, qf[ds].v, sacc[0]);
            sacc[1] = mfma16(ak1.v, qf[ds].v, sacc[1]);
        }

        // ---- mask + online softmax (per q = l15) ----
        float pe[2][4];
        float mx = -3.0e38f;
        #pragma unroll
        for (int kb = 0; kb < 2; kb++)
            #pragma unroll
            for (int rr = 0; rr < 4; rr++) {
                float s = sacc[kb][rr];
                if (kv0 + kb * 16 + 4 * g + rr >= NTOK) s = -1e30f;
                pe[kb][rr] = s;
                mx = fmaxf(mx, s);
            }
        mx = fmaxf(mx, __shfl_xor(mx, 16, 64));
        mx = fmaxf(mx, __shfl_xor(mx, 32, 64));
        const float m_new = fmaxf(m_run, mx);
        const float corr = __expf(m_run - m_new);
        float psum = 0.f;
        #pragma unroll
        for (int kb = 0; kb < 2; kb++)
            #pragma unroll
            for (int rr = 0; rr < 4; rr++) {
                pe[kb][rr] = __expf(pe[kb][rr] - m_new);
                psum += pe[kb][rr];
            }
        psum += __shfl_xor(psum, 16, 64);
        psum += __shfl_xor(psum, 32, 64);
        l_run = l_run * corr + psum;
        m_run = m_new;

        // ---- canonicalize P via per-wave (private) LDS roundtrip ----
        {
            u32* pw = (u32*)(Ps + w * (16 * PSLD) + l15 * PSLD);
            pw[g * 2]         = pk2(pe[0][0], pe[0][1]);
            pw[g * 2 + 1]     = pk2(pe[0][2], pe[0][3]);
            pw[8 + g * 2]     = pk2(pe[1][0], pe[1][1]);
            pw[8 + g * 2 + 1] = pk2(pe[1][2], pe[1][3]);
        }
        asm volatile("s_waitcnt lgkmcnt(0)" ::: "memory");
        __builtin_amdgcn_sched_barrier(0);
        BF8 pa;
        pa.u4 = *(const uint4*)(Ps + w * (16 * PSLD) + l15 * PSLD + g * 8);

        float cb4[4];
        #pragma unroll
        for (int rr = 0; rr < 4; rr++) cb4[rr] = __shfl(corr, 4 * g + rr, 64);

        // ---- PV: O[q][dv] += P @ V ; V^T-frags direct from global (L2) ----
        const u16* vrow = vt + baseV + kv0 + g * 8;
        #pragma unroll
        for (int dc = 0; dc < 24; dc++) {
            #pragma unroll
            for (int rr = 0; rr < 4; rr++) oacc[dc][rr] *= cb4[rr];
            BF8 vb8;
            vb8.u4 = *(const uint4*)(vrow + (long)(dc * 16 + l15) * KPAD);
            oacc[dc] = mfma16(pa.v, vb8.v, oacc[dc]);
        }
    }

    // ---- store O (scaled by 1/(l*sqrt(768))) ----
    float linv[4];
    #pragma unroll
    for (int rr = 0; rr < 4; rr++)
        linv[rr] = INV_SQRT_EMB / __shfl(l_run, 4 * g + rr, 64);
    #pragma unroll
    for (int rr = 0; rr < 4; rr++) {
        const int row = q0 + 4 * g + rr;
        if (row < NTOK) {
            u16* dst = o + baseQ + (long)row * EMB;
            #pragma unroll
            for (int dc = 0; dc < 24; dc++)
                dst[dc * 16 + l15] = f2bf(oacc[dc][rr] * linv[rr]);
        }
    }
}

// ---------------- LN2 (bf16 in) then residual-add into t (bf16) ----------------
__global__ __launch_bounds__(256)
void ln_add_kernel(const u16* __restrict__ in, u16* __restrict__ t,
                   const float* __restrict__ g, const float* __restrict__ be)
{
    __shared__ float red[256];
    const int row = blockIdx.x, tid = threadIdx.x;
    const u16* x = in + (long)row * EMB;
    const float v0 = bf2f(x[tid]), v1 = bf2f(x[tid + 256]), v2 = bf2f(x[tid + 512]);
    const float mu = blk_sum(v0 + v1 + v2, red, tid) * (1.f / EMB);
    const float d0 = v0 - mu, d1 = v1 - mu, d2 = v2 - mu;
    const float var = blk_sum(d0 * d0 + d1 * d1 + d2 * d2, red, tid) * (1.f / EMB);
    const float rs = rsqrtf(var + LN_EPS);
    u16* o = t + (long)row * EMB;
    o[tid]       = f2bf(bf2f(o[tid])       + d0 * rs * g[tid]       + be[tid]);
    o[tid + 256] = f2bf(bf2f(o[tid + 256]) + d1 * rs * g[tid + 256] + be[tid + 256]);
    o[tid + 512] = f2bf(bf2f(o[tid + 512]) + d2 * rs * g[tid + 512] + be[tid + 512]);
}

// ---------------- mean over tokens ----------------
__global__ __launch_bounds__(128)
void meanpool_kernel(const u16* __restrict__ t, float* __restrict__ m)
{
    const int b = blockIdx.y;
    const int e = blockIdx.x * 128 + threadIdx.x;
    const u16* p = t + (long)b * NTOK * EMB + e;
    float s = 0.f;
    for (int j = 0; j < NTOK; j++) s += bf2f(p[(long)j * EMB]);
    m[b * EMB + e] = s * (1.f / NTOK);
}

// ---------------- LN3 + final Linear (fp32) ----------------
__global__ __launch_bounds__(256)
void final_kernel(const float* __restrict__ m, const float* __restrict__ g,
                  const float* __restrict__ be, const float* __restrict__ Wf,
                  const float* __restrict__ bf, float* __restrict__ out)
{
    __shared__ float red[256];
    __shared__ float mln[EMB];
    const int b = blockIdx.x, tid = threadIdx.x;
    const float* x = m + b * EMB;
    const float v0 = x[tid], v1 = x[tid + 256], v2 = x[tid + 512];
    const float mu = blk_sum(v0 + v1 + v2, red, tid) * (1.f / EMB);
    const float d0 = v0 - mu, d1 = v1 - mu, d2 = v2 - mu;
    const float var = blk_sum(d0 * d0 + d1 * d1 + d2 * d2, red, tid) * (1.f / EMB);
    const float rs = rsqrtf(var + LN_EPS);
    mln[tid]       = d0 * rs * g[tid]       + be[tid];
    mln[tid + 256] = d1 * rs * g[tid + 256] + be[tid + 256];
    mln[tid + 512] = d2 * rs * g[tid + 512] + be[tid + 512];
    __syncthreads();
    #pragma unroll
    for (int s = 0; s < 3; s++) {
        const int e = tid + s * 256;
        float acc = bf[e];
        #pragma unroll 8
        for (int kk = 0; kk < EMB; kk++) acc += mln[kk] * Wf[(long)kk * EMB + e];
        out[(long)b * EMB + e] = acc;
    }
}

extern "C" void kernel_launch(void* const* d_in, const int* in_sizes, int n_in,
                              void* d_out, int out_size, void* d_ws, size_t ws_size,
                              hipStream_t stream) {
    const float* x      = (const float*)d_in[0];
    const float* text   = (const float*)d_in[1];
    const float* Wpatch = (const float*)d_in[2];
    const float* bpatch = (const float*)d_in[3];
    const float* cls    = (const float*)d_in[4];
    const float* g1  = (const float*)d_in[5];
    const float* be1 = (const float*)d_in[6];
    const float* Wq  = (const float*)d_in[7];
    const float* bq  = (const float*)d_in[8];
    const float* Wk  = (const float*)d_in[9];
    const float* bk  = (const float*)d_in[10];
    const float* Wv  = (const float*)d_in[11];
    const float* bv  = (const float*)d_in[12];
    const float* Wp  = (const float*)d_in[13];
    const float* bp  = (const float*)d_in[14];
    const float* g2  = (const float*)d_in[15];
    const float* be2 = (const float*)d_in[16];
    const float* g3  = (const float*)d_in[17];
    const float* be3 = (const float*)d_in[18];
    const float* Wf  = (const float*)d_in[19];
    const float* bf  = (const float*)d_in[20];

    // ws layout (~167 MB):
    //  t=0 | qb=S2 | kbf=2S2 | vbf=3S2 | hb/vt2=4S2 (32.25MB slot) | wt | mp
    //  pat aliases qb (dead until QKV); vt2 overwrites hb (dead post-QKV);
    //  o2 (bf16) aliases vbf (dead post-vtrans).
    char* ws = (char*)d_ws;
    const size_t S2 = (size_t)MROWS * EMB * 2;           // 32,145,408
    const size_t VT2 = (size_t)64 * HD * KPAD * 2;       // 32,243,712
    u16*   t    = (u16*)ws;
    u16*   qb   = (u16*)(ws + S2);
    u16*   kbf  = (u16*)(ws + 2 * S2);
    u16*   vbf  = (u16*)(ws + 3 * S2);
    u16*   hb   = (u16*)(ws + 4 * S2);
    u16*   vt2  = hb;                                    // after QKV, hb is dead
    u16*   o2b  = vbf;                                   // after vtrans, vbf is dead
    u16*   wt   = (u16*)(ws + 4 * S2 + VT2);
    float* mp   = (float*)(ws + 4 * S2 + VT2 + (size_t)5 * EMB * EMB * 2);
    u16*   pat  = qb;
    const size_t WTS = (size_t)EMB * EMB;
    const int DLDS = 2 * 2 * DTILE_B;   // 65536

    // 1) weights -> bf16 transposed
    wt_kernel<<<dim3(24, 24, 5), 256, 0, stream>>>(Wpatch, Wq, Wk, Wv, Wp, wt);
    // 2) cls + text rows of t
    fill_rows_kernel<<<dim3(NTEXT + 1, NBATCH), 256, 0, stream>>>(cls, text, t);
    // 3) im2col -> patches (aliases q)
    im2col_kernel<<<dim3(512, 24), 384, 0, stream>>>(x, pat);
    // 4) patch embed: dense GEMM with row remap -> t   (864 = 8*108 blocks)
    dense_gemm<true, true><<<864, 256, DLDS, stream>>>(
        pat, wt, bpatch, bpatch, bpatch, t, t, t, NBATCH * NPATCH, 6);
    // 5) h = LN1(t)
    ln_h_kernel<<<MROWS, 256, 0, stream>>>(t, hb, g1, be1);
    // 6) fused QKV: nb=18, z selects Wq/Wk/Wv  (2952 = 8*369 blocks)
    dense_gemm<true, false><<<2952, 256, DLDS, stream>>>(
        hb, wt + WTS, bq, bk, bv, qb, kbf, vbf, MROWS, 18);
    // 7) V^T materialization (overwrites hb)
    vtrans_kernel<<<dim3(21, 12, 64), 256, 0, stream>>>(vbf, vt2);
    // 8) flash attention v10 (o over q), 656 = 8*82 blocks
    flash_mfma<<<656, 256, 0, stream>>>(qb, kbf, vt2, qb);
    // 9) proj -> o2 bf16 (aliases vbf)   (984 = 8*123 blocks)
    dense_gemm<true, false><<<984, 256, DLDS, stream>>>(
        qb, wt + 4 * WTS, bp, bp, bp, o2b, o2b, o2b, MROWS, 6);
    // 10) t += LN2(o2)
    ln_add_kernel<<<MROWS, 256, 0, stream>>>(o2b, t, g2, be2);
    // 11) mean pool
    meanpool_kernel<<<dim3(6, NBATCH), 128, 0, stream>>>(t, mp);
    // 12) LN3 + final linear
    final_kernel<<<NBATCH, 256, 0, stream>>>(mp, g3, be3, Wf, bf, (float*)d_out);
}

// Round 13
// 558.086 us; speedup vs baseline: 1.1791x; 1.1791x over previous
//
#include <hip/hip_runtime.h>
#include <hip/hip_bf16.h>
#include <math.h>

#define EMB 768
#define NTOK 654
#define NPATCH 576
#define NTEXT 77
#define NBATCH 32
#define HD 384
#define MROWS (NBATCH * NTOK)   // 20928
#define LN_EPS 1e-5f
#define INV_SQRT_EMB 0.03608439182435161f

typedef unsigned int u32;
typedef unsigned short u16;
typedef float f32x4 __attribute__((ext_vector_type(4)));
typedef __bf16 bf16x8 __attribute__((ext_vector_type(8)));

union BF8 { uint4 u4; u32 w[4]; bf16x8 v; };

// async global->LDS, 16B per lane; dest = wave-uniform base + lane*16
#define GLL(gsrc, ldst) __builtin_amdgcn_global_load_lds( \
    (const __attribute__((address_space(1))) unsigned int*)(gsrc), \
    (__attribute__((address_space(3))) unsigned int*)(ldst), 16, 0, 0)

// ---------------- helpers ----------------
__device__ __forceinline__ float bf2f(u16 u) {
    union { u32 i; float f; } x; x.i = ((u32)u) << 16; return x.f;
}
__device__ __forceinline__ u16 f2bf(float f) {  // RTNE
    union { float f; u32 i; } x; x.f = f;
    u32 r = x.i + 0x7fffu + ((x.i >> 16) & 1u);
    return (u16)(r >> 16);
}
__device__ __forceinline__ u32 pk2(float lo, float hi) {
    return (u32)f2bf(lo) | ((u32)f2bf(hi) << 16);
}
__device__ __forceinline__ float blk_sum(float v, float* red, int tid) {
    red[tid] = v; __syncthreads();
    #pragma unroll
    for (int s = 128; s > 0; s >>= 1) {
        if (tid < s) red[tid] += red[tid + s];
        __syncthreads();
    }
    float r = red[0]; __syncthreads();
    return r;
}
__device__ __forceinline__ float wave_sum(float v) {
    #pragma unroll
    for (int off = 1; off < 64; off <<= 1) v += __shfl_xor(v, off, 64);
    return v;
}
__device__ __forceinline__ f32x4 mfma16(bf16x8 a, bf16x8 b, f32x4 c) {
    return __builtin_amdgcn_mfma_f32_16x16x32_bf16(a, b, c, 0, 0, 0);
}

// ---------------- weight transpose + bf16: Wt[n][k] = bf16(W[k][n]) ----------------
__global__ __launch_bounds__(256)
void wt_kernel(const float* __restrict__ W0, const float* __restrict__ W1,
               const float* __restrict__ W2, const float* __restrict__ W3,
               const float* __restrict__ W4, u16* __restrict__ dst)
{
    __shared__ float tile[32][33];
    const int z = blockIdx.z;
    const float* W = (z == 0) ? W0 : (z == 1) ? W1 : (z == 2) ? W2 : (z == 3) ? W3 : W4;
    u16* o = dst + (size_t)z * EMB * EMB;
    const int bi = blockIdx.y, bj = blockIdx.x;
    const int r = threadIdx.x >> 5, c = threadIdx.x & 31;
    #pragma unroll
    for (int i = 0; i < 4; i++)
        tile[r + i * 8][c] = W[(long)(bi * 32 + r + i * 8) * EMB + bj * 32 + c];
    __syncthreads();
    #pragma unroll
    for (int i = 0; i < 4; i++) {
        const int rr = r + i * 8;
        o[(long)(bj * 32 + rr) * EMB + bi * 32 + c] = f2bf(tile[c][rr]);
    }
}

// ---------------- fill cls + text rows of t (bf16) ----------------
__global__ __launch_bounds__(256)
void fill_rows_kernel(const float* __restrict__ cls, const float* __restrict__ text,
                      u16* __restrict__ t)
{
    const int b = blockIdx.y, r = blockIdx.x;
    const int tid = threadIdx.x;
    const long trow = (long)b * NTOK + (r == 0 ? 0 : NPATCH + r);
    const float* src = (r == 0) ? cls : text + ((long)b * NTEXT + (r - 1)) * EMB;
    u16* dst = t + trow * EMB;
    #pragma unroll
    for (int s = 0; s < 3; s++) dst[tid + s * 256] = f2bf(src[tid + s * 256]);
}

// ---------------- im2col v2: coalesced uint4 writes ----------------
// Thread owns 8 consecutive output u16s of one patch row. col = 48*p1 + 3*p2 + c.
__global__ __launch_bounds__(384)
void im2col_kernel(const float* __restrict__ x, u16* __restrict__ patches)
{
    const int row = blockIdx.x * 4 + threadIdx.x / 96;   // 0..18431
    const int j = threadIdx.x % 96;
    const int bb = row / NPATCH, rem = row % NPATCH;
    const int hh = rem / 24, ww = rem % 24;
    union { u16 s[8]; uint4 v; } out;
    #pragma unroll
    for (int e = 0; e < 8; e++) {
        const int col = j * 8 + e;
        const int p1 = col / 48, r2 = col % 48, p2 = r2 / 3, c = r2 % 3;
        out.s[e] = f2bf(x[((long)(bb * 3 + c) * 384 + hh * 16 + p1) * 384 + ww * 16 + p2]);
    }
    *(uint4*)(patches + (long)row * EMB + j * 8) = out.v;
}

// ---------------- LN1 wave-per-row: t(bf16) -> h(bf16), no barriers ----------------
__global__ __launch_bounds__(256)
void ln_h_kernel(const u16* __restrict__ t, u16* __restrict__ h,
                 const float* __restrict__ g, const float* __restrict__ be)
{
    const int row = blockIdx.x * 4 + (threadIdx.x >> 6);
    const int lane = threadIdx.x & 63;
    const u16* xp = t + (long)row * EMB;
    float v[12];
    #pragma unroll
    for (int s = 0; s < 3; s++) {
        const uint2 u = *(const uint2*)(xp + lane * 4 + s * 256);
        const u16* e = (const u16*)&u;
        #pragma unroll
        for (int jj = 0; jj < 4; jj++) v[s * 4 + jj] = bf2f(e[jj]);
    }
    float sum = 0.f;
    #pragma unroll
    for (int i = 0; i < 12; i++) sum += v[i];
    const float mu = wave_sum(sum) * (1.f / EMB);
    float vs = 0.f;
    #pragma unroll
    for (int i = 0; i < 12; i++) { v[i] -= mu; vs += v[i] * v[i]; }
    const float rs = rsqrtf(wave_sum(vs) * (1.f / EMB) + LN_EPS);
    u16* o = h + (long)row * EMB;
    #pragma unroll
    for (int s = 0; s < 3; s++) {
        const int col = lane * 4 + s * 256;
        const float4 gv = *(const float4*)(g + col);
        const float4 bv = *(const float4*)(be + col);
        uint2 w;
        w.x = pk2(v[s * 4 + 0] * rs * gv.x + bv.x, v[s * 4 + 1] * rs * gv.y + bv.y);
        w.y = pk2(v[s * 4 + 2] * rs * gv.z + bv.z, v[s * 4 + 3] * rs * gv.w + bv.w);
        *(uint2*)(o + col) = w;
    }
}

// ---------------- dense MFMA GEMM v3: GLL dbuf + counted vmcnt + RAW barriers --------
#define DBK 64
#define DTILE_B (128 * DBK * 2)   // 16384 B per operand tile

template<bool OBF16, bool REMAP>
__global__ __launch_bounds__(256)
void dense_gemm(const u16* __restrict__ A, const u16* __restrict__ Bt,
                const float* __restrict__ b0, const float* __restrict__ b1,
                const float* __restrict__ b2,
                void* __restrict__ C0, void* __restrict__ C1, void* __restrict__ C2,
                int M, int nb)
{
    extern __shared__ char sm[];   // [2][A|B][128][64]u16 = 65536 B
    const int cpx = gridDim.x >> 3;
    const int wg = blockIdx.x;
    const int work = (wg & 7) * cpx + (wg >> 3);
    const int cb = work % nb;
    const int m0 = (work / nb) * 128;
    const int z  = cb / 6;
    const int n0 = (cb % 6) * 128;
    const u16* Btz = Bt + (size_t)z * EMB * EMB;
    const float* bias = (z == 0) ? b0 : (z == 1) ? b1 : b2;
    void* Cz = (z == 0) ? C0 : (z == 1) ? C1 : C2;

    const int tid = threadIdx.x;
    const int lane = tid & 63, w = tid >> 6, wr = w >> 1, wc = w & 1;
    const int l15 = lane & 15, g = lane >> 4;
    const int wbase = (tid & ~63);

    f32x4 acc[4][4] = {};

    auto stage = [&](int k0, int buf) {
        char* dst = sm + buf * 2 * DTILE_B;
        #pragma unroll
        for (int c = 0; c < 4; c++) {
            const int idx = c * 256 + tid;
            const int r = idx >> 3, s = idx & 7;
            const int gs = s ^ (r & 7);
            const int ar = min(m0 + r, M - 1);
            GLL(A + (long)ar * EMB + k0 + gs * 8, dst + (c * 256 + wbase) * 16);
        }
        #pragma unroll
        for (int c = 0; c < 4; c++) {
            const int idx = c * 256 + tid;
            const int r = idx >> 3, s = idx & 7;
            const int gs = s ^ (r & 7);
            GLL(Btz + (long)(n0 + r) * EMB + k0 + gs * 8,
                dst + DTILE_B + (c * 256 + wbase) * 16);
        }
    };

    stage(0, 0);
    for (int t = 0; t < 12; t++) {
        if (t < 11) {
            stage((t + 1) * DBK, (t + 1) & 1);
            asm volatile("s_waitcnt vmcnt(8)" ::: "memory");   // tile t landed; t+1 in flight
        } else {
            asm volatile("s_waitcnt vmcnt(0)" ::: "memory");
        }
        __builtin_amdgcn_s_barrier();          // all waves' tile-t loads landed
        __builtin_amdgcn_sched_barrier(0);
        const char* Asb = sm + (t & 1) * 2 * DTILE_B;
        const char* Bsb = Asb + DTILE_B;
        #pragma unroll
        for (int ks = 0; ks < 2; ks++) {
            BF8 af[4], bfr[4];
            #pragma unroll
            for (int mi = 0; mi < 4; mi++) {
                const int row = wr * 64 + mi * 16 + l15;
                const int slot = (ks * 4 + g) ^ (row & 7);
                af[mi].u4 = *(const uint4*)(Asb + row * 128 + slot * 16);
            }
            #pragma unroll
            for (int nj = 0; nj < 4; nj++) {
                const int row = wc * 64 + nj * 16 + l15;
                const int slot = (ks * 4 + g) ^ (row & 7);
                bfr[nj].u4 = *(const uint4*)(Bsb + row * 128 + slot * 16);
            }
            __builtin_amdgcn_s_setprio(1);
            #pragma unroll
            for (int mi = 0; mi < 4; mi++)
                #pragma unroll
                for (int nj = 0; nj < 4; nj++)
                    acc[mi][nj] = mfma16(af[mi].v, bfr[nj].v, acc[mi][nj]);
            __builtin_amdgcn_s_setprio(0);
        }
        __builtin_amdgcn_s_barrier();          // all waves done reading buf t&1
        __builtin_amdgcn_sched_barrier(0);
    }

    float bv[4];
    #pragma unroll
    for (int nj = 0; nj < 4; nj++) bv[nj] = bias[n0 + wc * 64 + nj * 16 + l15];
    #pragma unroll
    for (int mi = 0; mi < 4; mi++) {
        #pragma unroll
        for (int rr = 0; rr < 4; rr++) {
            const int r = m0 + wr * 64 + mi * 16 + 4 * g + rr;
            if (r >= M) continue;
            long orow = r;
            if (REMAP) orow = (long)(r / NPATCH) * NTOK + 1 + (r % NPATCH);
            #pragma unroll
            for (int nj = 0; nj < 4; nj++) {
                const int cc = n0 + wc * 64 + nj * 16 + l15;
                const float val = acc[mi][nj][rr] + bv[nj];
                if (OBF16) ((u16*)Cz)[orow * EMB + cc] = f2bf(val);
                else       ((float*)Cz)[orow * EMB + cc] = val;
            }
        }
    }
}

// ---------------- flash attention v7 (r9 best): GLL-K dbuf, true pipeline ------------
// 256 thr = 4 waves, 64 q/block, KV tiles of 32 keys.
//   top __syncthreads : drains vmem -> K(t) in LDS, V(t) in regs; WAR gate for Vt
//   writeV(t)         : regs -> Vt
//   mid __syncthreads : Vt/K visible (nothing in flight -> free drain)
//   stage_K(t+1) GLL + loadV(t+1)   : fly across the whole compute phase
//   compute(t)
#define KS_TILE_B 24576   // 32*384*2
#define VTLD 36           // Vt row stride (u16), 72 B (conflict-free; 40 regressed r10)
#define PSLD 40           // Ps row stride (u16)
#define FLASH_LDS (2 * KS_TILE_B + 384 * VTLD * 2 + 4 * 16 * PSLD * 2)  // 81920

__global__ __launch_bounds__(256)
void flash_mfma(const u16* __restrict__ q, const u16* __restrict__ k,
                const u16* __restrict__ v, u16* __restrict__ o)
{
    extern __shared__ char smem[];
    char* KsB = smem;                                   // [2][32][384] u16 (swizzled)
    u16* Vt = (u16*)(smem + 2 * KS_TILE_B);             // [384][VTLD]
    char* Ps = smem + 2 * KS_TILE_B + 384 * VTLD * 2;   // 4 waves x [16][PSLD]

    // XCD-bijective: 704 = 8 * 88; 11 consecutive works share one (b,h)
    const int wg = blockIdx.x;
    const int work = (wg & 7) * 88 + (wg >> 3);
    const int bh = work / 11, qblk = work % 11;
    const int b = bh >> 1, h = bh & 1;
    const int q0 = qblk * 64;
    const int tid = threadIdx.x;
    const int lane = tid & 63, w = tid >> 6;
    const int l15 = lane & 15, g = lane >> 4;
    const int wbase = (tid & ~63);
    const long base = (long)b * NTOK * EMB + h * HD;

    BF8 qf[12];
    {
        const int qrow = q0 + w * 16 + l15;
        if (qrow < NTOK) {
            const u16* src = q + base + (long)qrow * EMB;
            #pragma unroll
            for (int ds = 0; ds < 12; ds++)
                qf[ds].u4 = *(const uint4*)(src + ds * 32 + g * 8);
        } else {
            #pragma unroll
            for (int ds = 0; ds < 12; ds++) qf[ds].u4 = make_uint4(0, 0, 0, 0);
        }
    }

    auto stage_K = [&](int kv0, int buf) {
        #pragma unroll
        for (int c = 0; c < 6; c++) {
            const int idx = c * 256 + tid;
            const int r = idx / 48, gr = idx % 48;
            const int gsrc = (gr & ~7) | ((gr & 7) ^ (r & 7));
            const int kr = min(kv0 + r, NTOK - 1);
            GLL(k + base + (long)kr * EMB + gsrc * 8,
                KsB + buf * KS_TILE_B + (c * 256 + wbase) * 16);
        }
    };

    const int kp = tid & 15;
    uint4 va[3], vb[3];
    auto loadV = [&](int kv0) {
        const int kr0 = kv0 + 2 * kp;
        const u16* v0p = v + base + (long)min(kr0, NTOK - 1) * EMB;
        const u16* v1p = v + base + (long)min(kr0 + 1, NTOK - 1) * EMB;
        #pragma unroll
        for (int tt = 0; tt < 3; tt++) {
            const int dseg = (tid >> 4) + tt * 16;
            va[tt] = *(const uint4*)(v0p + dseg * 8);
            vb[tt] = *(const uint4*)(v1p + dseg * 8);
        }
    };
    auto writeV = [&](int kv0) {
        const int kr0 = kv0 + 2 * kp;
        const bool ok0 = kr0 < NTOK, ok1 = (kr0 + 1) < NTOK;
        #pragma unroll
        for (int tt = 0; tt < 3; tt++) {
            const int dseg = (tid >> 4) + tt * 16;
            const u16* ae = (const u16*)&va[tt];
            const u16* be = (const u16*)&vb[tt];
            #pragma unroll
            for (int e = 0; e < 8; e++) {
                const u32 lo = ok0 ? (u32)ae[e] : 0u;
                const u32 hi = ok1 ? (u32)be[e] : 0u;
                *(u32*)&Vt[(dseg * 8 + e) * VTLD + 2 * kp] = lo | (hi << 16);
            }
        }
    };

    float m_run = -3.0e38f, l_run = 0.f;
    f32x4 oacc[24] = {};

    stage_K(0, 0);
    loadV(0);

    for (int kt = 0; kt < 21; kt++) {
        const int kv0 = kt * 32;
        __syncthreads();   // implicit vmcnt(0): K(kt) in LDS, V(kt) in regs; WAR for Vt
        writeV(kv0);
        __syncthreads();   // Vt(kt)+K(kt) visible; nothing in flight -> free drain
        if (kt < 20) {
            stage_K(kv0 + 32, (kt + 1) & 1);   // async across compute(kt)
            loadV(kv0 + 32);
        }

        const char* kbuf = KsB + (kt & 1) * KS_TILE_B;
        f32x4 sacc[2] = {};
        #pragma unroll
        for (int ds = 0; ds < 12; ds++) {
            const int idx = ds * 4 + g;
            const int slot = (idx & ~7) | ((idx & 7) ^ (l15 & 7));
            BF8 ak0, ak1;
            ak0.u4 = *(const uint4*)(kbuf + l15 * 768 + slot * 16);
            ak1.u4 = *(const uint4*)(kbuf + (16 + l15) * 768 + slot * 16);
            sacc[0] = mfma16(ak0.v, qf[ds].v, sacc[0]);
            sacc[1] = mfma16(ak1.v, qf[ds].v, sacc[1]);
        }

        float pe[2][4];
        float mx = -3.0e38f;
        #pragma unroll
        for (int kb = 0; kb < 2; kb++)
            #pragma unroll
            for (int rr = 0; rr < 4; rr++) {
                float s = sacc[kb][rr];
                if (kv0 + kb * 16 + 4 * g + rr >= NTOK) s = -1e30f;
                pe[kb][rr] = s;
                mx = fmaxf(mx, s);
            }
        mx = fmaxf(mx, __shfl_xor(mx, 16, 64));
        mx = fmaxf(mx, __shfl_xor(mx, 32, 64));
        const float m_new = fmaxf(m_run, mx);
        const float corr = __expf(m_run - m_new);
        float psum = 0.f;
        #pragma unroll
        for (int kb = 0; kb < 2; kb++)
            #pragma unroll
            for (int rr = 0; rr < 4; rr++) {
                pe[kb][rr] = __expf(pe[kb][rr] - m_new);
                psum += pe[kb][rr];
            }
        psum += __shfl_xor(psum, 16, 64);
        psum += __shfl_xor(psum, 32, 64);
        l_run = l_run * corr + psum;
        m_run = m_new;

        {
            u32* pw = (u32*)(Ps + w * (16 * PSLD * 2) + l15 * (PSLD * 2));
            pw[g * 2]         = pk2(pe[0][0], pe[0][1]);
            pw[g * 2 + 1]     = pk2(pe[0][2], pe[0][3]);
            pw[8 + g * 2]     = pk2(pe[1][0], pe[1][1]);
            pw[8 + g * 2 + 1] = pk2(pe[1][2], pe[1][3]);
        }
        asm volatile("s_waitcnt lgkmcnt(0)" ::: "memory");
        __builtin_amdgcn_sched_barrier(0);
        BF8 pa;
        pa.u4 = *(const uint4*)(Ps + w * (16 * PSLD * 2) + l15 * (PSLD * 2) + g * 16);

        float cb4[4];
        #pragma unroll
        for (int rr = 0; rr < 4; rr++) cb4[rr] = __shfl(corr, 4 * g + rr, 64);

        #pragma unroll
        for (int dc = 0; dc < 24; dc++) {
            #pragma unroll
            for (int rr = 0; rr < 4; rr++) oacc[dc][rr] *= cb4[rr];
            const u16* vp = &Vt[(dc * 16 + l15) * VTLD + g * 8];
            const uint2 lo = *(const uint2*)vp;
            const uint2 hi = *(const uint2*)(vp + 4);
            BF8 vb8;
            vb8.w[0] = lo.x; vb8.w[1] = lo.y; vb8.w[2] = hi.x; vb8.w[3] = hi.y;
            oacc[dc] = mfma16(pa.v, vb8.v, oacc[dc]);
        }
    }

    float linv[4];
    #pragma unroll
    for (int rr = 0; rr < 4; rr++)
        linv[rr] = INV_SQRT_EMB / __shfl(l_run, 4 * g + rr, 64);
    #pragma unroll
    for (int rr = 0; rr < 4; rr++) {
        const int row = q0 + w * 16 + 4 * g + rr;
        if (row < NTOK) {
            u16* dst = o + base + (long)row * EMB;
            #pragma unroll
            for (int dc = 0; dc < 24; dc++)
                dst[dc * 16 + l15] = f2bf(oacc[dc][rr] * linv[rr]);
        }
    }
}

// ---------------- LN2 wave-per-row (bf16 in) + residual-add into t ----------------
__global__ __launch_bounds__(256)
void ln_add_kernel(const u16* __restrict__ in, u16* __restrict__ t,
                   const float* __restrict__ g, const float* __restrict__ be)
{
    const int row = blockIdx.x * 4 + (threadIdx.x >> 6);
    const int lane = threadIdx.x & 63;
    const u16* xp = in + (long)row * EMB;
    float v[12];
    #pragma unroll
    for (int s = 0; s < 3; s++) {
        const uint2 u = *(const uint2*)(xp + lane * 4 + s * 256);
        const u16* e = (const u16*)&u;
        #pragma unroll
        for (int jj = 0; jj < 4; jj++) v[s * 4 + jj] = bf2f(e[jj]);
    }
    float sum = 0.f;
    #pragma unroll
    for (int i = 0; i < 12; i++) sum += v[i];
    const float mu = wave_sum(sum) * (1.f / EMB);
    float vs = 0.f;
    #pragma unroll
    for (int i = 0; i < 12; i++) { v[i] -= mu; vs += v[i] * v[i]; }
    const float rs = rsqrtf(wave_sum(vs) * (1.f / EMB) + LN_EPS);
    u16* o = t + (long)row * EMB;
    #pragma unroll
    for (int s = 0; s < 3; s++) {
        const int col = lane * 4 + s * 256;
        const float4 gv = *(const float4*)(g + col);
        const float4 bv = *(const float4*)(be + col);
        const uint2 told = *(const uint2*)(o + col);
        const u16* te = (const u16*)&told;
        uint2 w;
        w.x = pk2(bf2f(te[0]) + v[s * 4 + 0] * rs * gv.x + bv.x,
                  bf2f(te[1]) + v[s * 4 + 1] * rs * gv.y + bv.y);
        w.y = pk2(bf2f(te[2]) + v[s * 4 + 2] * rs * gv.z + bv.z,
                  bf2f(te[3]) + v[s * 4 + 3] * rs * gv.w + bv.w);
        *(uint2*)(o + col) = w;
    }
}

// ---------------- mean over tokens ----------------
__global__ __launch_bounds__(128)
void meanpool_kernel(const u16* __restrict__ t, float* __restrict__ m)
{
    const int b = blockIdx.y;
    const int e = blockIdx.x * 128 + threadIdx.x;
    const u16* p = t + (long)b * NTOK * EMB + e;
    float s = 0.f;
    for (int j = 0; j < NTOK; j++) s += bf2f(p[(long)j * EMB]);
    m[b * EMB + e] = s * (1.f / NTOK);
}

// ---------------- LN3 + final Linear (fp32) ----------------
__global__ __launch_bounds__(256)
void final_kernel(const float* __restrict__ m, const float* __restrict__ g,
                  const float* __restrict__ be, const float* __restrict__ Wf,
                  const float* __restrict__ bf, float* __restrict__ out)
{
    __shared__ float red[256];
    __shared__ float mln[EMB];
    const int b = blockIdx.x, tid = threadIdx.x;
    const float* x = m + b * EMB;
    const float v0 = x[tid], v1 = x[tid + 256], v2 = x[tid + 512];
    const float mu = blk_sum(v0 + v1 + v2, red, tid) * (1.f / EMB);
    const float d0 = v0 - mu, d1 = v1 - mu, d2 = v2 - mu;
    const float var = blk_sum(d0 * d0 + d1 * d1 + d2 * d2, red, tid) * (1.f / EMB);
    const float rs = rsqrtf(var + LN_EPS);
    mln[tid]       = d0 * rs * g[tid]       + be[tid];
    mln[tid + 256] = d1 * rs * g[tid + 256] + be[tid + 256];
    mln[tid + 512] = d2 * rs * g[tid + 512] + be[tid + 512];
    __syncthreads();
    #pragma unroll
    for (int s = 0; s < 3; s++) {
        const int e = tid + s * 256;
        float acc = bf[e];
        #pragma unroll 8
        for (int kk = 0; kk < EMB; kk++) acc += mln[kk] * Wf[(long)kk * EMB + e];
        out[(long)b * EMB + e] = acc;
    }
}

extern "C" void kernel_launch(void* const* d_in, const int* in_sizes, int n_in,
                              void* d_out, int out_size, void* d_ws, size_t ws_size,
                              hipStream_t stream) {
    const float* x      = (const float*)d_in[0];
    const float* text   = (const float*)d_in[1];
    const float* Wpatch = (const float*)d_in[2];
    const float* bpatch = (const float*)d_in[3];
    const float* cls    = (const float*)d_in[4];
    const float* g1  = (const float*)d_in[5];
    const float* be1 = (const float*)d_in[6];
    const float* Wq  = (const float*)d_in[7];
    const float* bq  = (const float*)d_in[8];
    const float* Wk  = (const float*)d_in[9];
    const float* bk  = (const float*)d_in[10];
    const float* Wv  = (const float*)d_in[11];
    const float* bv  = (const float*)d_in[12];
    const float* Wp  = (const float*)d_in[13];
    const float* bp  = (const float*)d_in[14];
    const float* g2  = (const float*)d_in[15];
    const float* be2 = (const float*)d_in[16];
    const float* g3  = (const float*)d_in[17];
    const float* be3 = (const float*)d_in[18];
    const float* Wf  = (const float*)d_in[19];
    const float* bf  = (const float*)d_in[20];

    // ws layout (~167 MB): t | h | q | k | v (bf16, 5 x 32.1 MB)
    //  pat aliases qb (dead until QKV); o2 (bf16) aliases kbf (dead post-flash)
    //  Wt bf16 (5 x 1.18 MB) | mp fp32
    char* ws = (char*)d_ws;
    const size_t S2 = (size_t)MROWS * EMB * 2;   // 32,145,408
    u16*   t    = (u16*)ws;
    u16*   hb   = (u16*)(ws + S2);
    u16*   qb   = (u16*)(ws + 2 * S2);
    u16*   kbf  = (u16*)(ws + 3 * S2);
    u16*   vbf  = (u16*)(ws + 4 * S2);
    u16*   o2b  = kbf;   // after flash, k is dead
    u16*   wt   = (u16*)(ws + 5 * S2);
    float* mp   = (float*)(ws + 5 * S2 + (size_t)5 * EMB * EMB * 2);
    u16*   pat  = qb;    // im2col output aliases q
    const size_t WTS = (size_t)EMB * EMB;
    const int DLDS = 2 * 2 * DTILE_B;   // 65536

    // 1) weights -> bf16 transposed
    wt_kernel<<<dim3(24, 24, 5), 256, 0, stream>>>(Wpatch, Wq, Wk, Wv, Wp, wt);
    // 2) cls + text rows of t
    fill_rows_kernel<<<dim3(NTEXT + 1, NBATCH), 256, 0, stream>>>(cls, text, t);
    // 3) im2col v2 -> patches (aliases q), coalesced writes
    im2col_kernel<<<4608, 384, 0, stream>>>(x, pat);
    // 4) patch embed: dense GEMM with row remap -> t   (864 = 8*108 blocks)
    dense_gemm<true, true><<<864, 256, DLDS, stream>>>(
        pat, wt, bpatch, bpatch, bpatch, t, t, t, NBATCH * NPATCH, 6);
    // 5) h = LN1(t), wave-per-row
    ln_h_kernel<<<MROWS / 4, 256, 0, stream>>>(t, hb, g1, be1);
    // 6) fused QKV: nb=18, z selects Wq/Wk/Wv  (2952 = 8*369 blocks)
    dense_gemm<true, false><<<2952, 256, DLDS, stream>>>(
        hb, wt + WTS, bq, bk, bv, qb, kbf, vbf, MROWS, 18);
    // 7) flash attention v7/r9 (o over q)
    flash_mfma<<<704, 256, FLASH_LDS, stream>>>(qb, kbf, vbf, qb);
    // 8) proj -> o2 bf16 (aliases kbf)   (984 = 8*123 blocks)
    dense_gemm<true, false><<<984, 256, DLDS, stream>>>(
        qb, wt + 4 * WTS, bp, bp, bp, o2b, o2b, o2b, MROWS, 6);
    // 9) t += LN2(o2), wave-per-row
    ln_add_kernel<<<MROWS / 4, 256, 0, stream>>>(o2b, t, g2, be2);
    // 10) mean pool
    meanpool_kernel<<<dim3(6, NBATCH), 128, 0, stream>>>(t, mp);
    // 11) LN3 + final linear
    final_kernel<<<NBATCH, 256, 0, stream>>>(mp, g3, be3, Wf, bf, (float*)d_out);
}

// Round 14
// 490.997 us; speedup vs baseline: 1.3402x; 1.1366x over previous
//
#include <hip/hip_runtime.h>
#include <hip/hip_bf16.h>
#include <math.h>

#define EMB 768
#define NTOK 654
#define NPATCH 576
#define NTEXT 77
#define NBATCH 32
#define HD 384
#define MROWS (NBATCH * NTOK)   // 20928
#define LN_EPS 1e-5f
#define INV_SQRT_EMB 0.03608439182435161f

typedef unsigned int u32;
typedef unsigned short u16;
typedef float f32x4 __attribute__((ext_vector_type(4)));
typedef __bf16 bf16x8 __attribute__((ext_vector_type(8)));

union BF8 { uint4 u4; u32 w[4]; bf16x8 v; };

// async global->LDS, 16B per lane; dest = wave-uniform base + lane*16
#define GLL(gsrc, ldst) __builtin_amdgcn_global_load_lds( \
    (const __attribute__((address_space(1))) unsigned int*)(gsrc), \
    (__attribute__((address_space(3))) unsigned int*)(ldst), 16, 0, 0)

// ---------------- helpers ----------------
__device__ __forceinline__ float bf2f(u16 u) {
    union { u32 i; float f; } x; x.i = ((u32)u) << 16; return x.f;
}
__device__ __forceinline__ u16 f2bf(float f) {  // RTNE
    union { float f; u32 i; } x; x.f = f;
    u32 r = x.i + 0x7fffu + ((x.i >> 16) & 1u);
    return (u16)(r >> 16);
}
__device__ __forceinline__ u32 pk2(float lo, float hi) {
    return (u32)f2bf(lo) | ((u32)f2bf(hi) << 16);
}
__device__ __forceinline__ float blk_sum(float v, float* red, int tid) {
    red[tid] = v; __syncthreads();
    #pragma unroll
    for (int s = 128; s > 0; s >>= 1) {
        if (tid < s) red[tid] += red[tid + s];
        __syncthreads();
    }
    float r = red[0]; __syncthreads();
    return r;
}
__device__ __forceinline__ float wave_sum(float v) {
    #pragma unroll
    for (int off = 1; off < 64; off <<= 1) v += __shfl_xor(v, off, 64);
    return v;
}
__device__ __forceinline__ f32x4 mfma16(bf16x8 a, bf16x8 b, f32x4 c) {
    return __builtin_amdgcn_mfma_f32_16x16x32_bf16(a, b, c, 0, 0, 0);
}

// ---------------- weight transpose + bf16: Wt[n][k] = bf16(W[k][n]) ----------------
__global__ __launch_bounds__(256)
void wt_kernel(const float* __restrict__ W0, const float* __restrict__ W1,
               const float* __restrict__ W2, const float* __restrict__ W3,
               const float* __restrict__ W4, u16* __restrict__ dst)
{
    __shared__ float tile[32][33];
    const int z = blockIdx.z;
    const float* W = (z == 0) ? W0 : (z == 1) ? W1 : (z == 2) ? W2 : (z == 3) ? W3 : W4;
    u16* o = dst + (size_t)z * EMB * EMB;
    const int bi = blockIdx.y, bj = blockIdx.x;
    const int r = threadIdx.x >> 5, c = threadIdx.x & 31;
    #pragma unroll
    for (int i = 0; i < 4; i++)
        tile[r + i * 8][c] = W[(long)(bi * 32 + r + i * 8) * EMB + bj * 32 + c];
    __syncthreads();
    #pragma unroll
    for (int i = 0; i < 4; i++) {
        const int rr = r + i * 8;
        o[(long)(bj * 32 + rr) * EMB + bi * 32 + c] = f2bf(tile[c][rr]);
    }
}

// ---------------- fill cls + text rows of t (bf16) ----------------
__global__ __launch_bounds__(256)
void fill_rows_kernel(const float* __restrict__ cls, const float* __restrict__ text,
                      u16* __restrict__ t)
{
    const int b = blockIdx.y, r = blockIdx.x;
    const int tid = threadIdx.x;
    const long trow = (long)b * NTOK + (r == 0 ? 0 : NPATCH + r);
    const float* src = (r == 0) ? cls : text + ((long)b * NTEXT + (r - 1)) * EMB;
    u16* dst = t + trow * EMB;
    #pragma unroll
    for (int s = 0; s < 3; s++) dst[tid + s * 256] = f2bf(src[tid + s * 256]);
}

// ---------------- im2col v2: coalesced uint4 writes ----------------
__global__ __launch_bounds__(384)
void im2col_kernel(const float* __restrict__ x, u16* __restrict__ patches)
{
    const int row = blockIdx.x * 4 + threadIdx.x / 96;   // 0..18431
    const int j = threadIdx.x % 96;
    const int bb = row / NPATCH, rem = row % NPATCH;
    const int hh = rem / 24, ww = rem % 24;
    union { u16 s[8]; uint4 v; } out;
    #pragma unroll
    for (int e = 0; e < 8; e++) {
        const int col = j * 8 + e;
        const int p1 = col / 48, r2 = col % 48, p2 = r2 / 3, c = r2 % 3;
        out.s[e] = f2bf(x[((long)(bb * 3 + c) * 384 + hh * 16 + p1) * 384 + ww * 16 + p2]);
    }
    *(uint4*)(patches + (long)row * EMB + j * 8) = out.v;
}

// ---------------- LN1 wave-per-row: t(bf16) -> h(bf16), no barriers ----------------
__global__ __launch_bounds__(256)
void ln_h_kernel(const u16* __restrict__ t, u16* __restrict__ h,
                 const float* __restrict__ g, const float* __restrict__ be)
{
    const int row = blockIdx.x * 4 + (threadIdx.x >> 6);
    const int lane = threadIdx.x & 63;
    const u16* xp = t + (long)row * EMB;
    float v[12];
    #pragma unroll
    for (int s = 0; s < 3; s++) {
        const uint2 u = *(const uint2*)(xp + lane * 4 + s * 256);
        const u16* e = (const u16*)&u;
        #pragma unroll
        for (int jj = 0; jj < 4; jj++) v[s * 4 + jj] = bf2f(e[jj]);
    }
    float sum = 0.f;
    #pragma unroll
    for (int i = 0; i < 12; i++) sum += v[i];
    const float mu = wave_sum(sum) * (1.f / EMB);
    float vs = 0.f;
    #pragma unroll
    for (int i = 0; i < 12; i++) { v[i] -= mu; vs += v[i] * v[i]; }
    const float rs = rsqrtf(wave_sum(vs) * (1.f / EMB) + LN_EPS);
    u16* o = h + (long)row * EMB;
    #pragma unroll
    for (int s = 0; s < 3; s++) {
        const int col = lane * 4 + s * 256;
        const float4 gv = *(const float4*)(g + col);
        const float4 bv = *(const float4*)(be + col);
        uint2 w;
        w.x = pk2(v[s * 4 + 0] * rs * gv.x + bv.x, v[s * 4 + 1] * rs * gv.y + bv.y);
        w.y = pk2(v[s * 4 + 2] * rs * gv.z + bv.z, v[s * 4 + 3] * rs * gv.w + bv.w);
        *(uint2*)(o + col) = w;
    }
}

// ---------------- dense MFMA GEMM v3: GLL dbuf + counted vmcnt + RAW barriers --------
#define DBK 64
#define DTILE_B (128 * DBK * 2)   // 16384 B per operand tile

template<bool OBF16, bool REMAP>
__global__ __launch_bounds__(256)
void dense_gemm(const u16* __restrict__ A, const u16* __restrict__ Bt,
                const float* __restrict__ b0, const float* __restrict__ b1,
                const float* __restrict__ b2,
                void* __restrict__ C0, void* __restrict__ C1, void* __restrict__ C2,
                int M, int nb)
{
    extern __shared__ char sm[];   // [2][A|B][128][64]u16 = 65536 B
    const int cpx = gridDim.x >> 3;
    const int wg = blockIdx.x;
    const int work = (wg & 7) * cpx + (wg >> 3);
    const int cb = work % nb;
    const int m0 = (work / nb) * 128;
    const int z  = cb / 6;
    const int n0 = (cb % 6) * 128;
    const u16* Btz = Bt + (size_t)z * EMB * EMB;
    const float* bias = (z == 0) ? b0 : (z == 1) ? b1 : b2;
    void* Cz = (z == 0) ? C0 : (z == 1) ? C1 : C2;

    const int tid = threadIdx.x;
    const int lane = tid & 63, w = tid >> 6, wr = w >> 1, wc = w & 1;
    const int l15 = lane & 15, g = lane >> 4;
    const int wbase = (tid & ~63);

    f32x4 acc[4][4] = {};

    auto stage = [&](int k0, int buf) {
        char* dst = sm + buf * 2 * DTILE_B;
        #pragma unroll
        for (int c = 0; c < 4; c++) {
            const int idx = c * 256 + tid;
            const int r = idx >> 3, s = idx & 7;
            const int gs = s ^ (r & 7);
            const int ar = min(m0 + r, M - 1);
            GLL(A + (long)ar * EMB + k0 + gs * 8, dst + (c * 256 + wbase) * 16);
        }
        #pragma unroll
        for (int c = 0; c < 4; c++) {
            const int idx = c * 256 + tid;
            const int r = idx >> 3, s = idx & 7;
            const int gs = s ^ (r & 7);
            GLL(Btz + (long)(n0 + r) * EMB + k0 + gs * 8,
                dst + DTILE_B + (c * 256 + wbase) * 16);
        }
    };

    stage(0, 0);
    for (int t = 0; t < 12; t++) {
        if (t < 11) {
            stage((t + 1) * DBK, (t + 1) & 1);
            asm volatile("s_waitcnt vmcnt(8)" ::: "memory");   // tile t landed; t+1 in flight
        } else {
            asm volatile("s_waitcnt vmcnt(0)" ::: "memory");
        }
        __builtin_amdgcn_s_barrier();          // all waves' tile-t loads landed
        __builtin_amdgcn_sched_barrier(0);
        const char* Asb = sm + (t & 1) * 2 * DTILE_B;
        const char* Bsb = Asb + DTILE_B;
        #pragma unroll
        for (int ks = 0; ks < 2; ks++) {
            BF8 af[4], bfr[4];
            #pragma unroll
            for (int mi = 0; mi < 4; mi++) {
                const int row = wr * 64 + mi * 16 + l15;
                const int slot = (ks * 4 + g) ^ (row & 7);
                af[mi].u4 = *(const uint4*)(Asb + row * 128 + slot * 16);
            }
            #pragma unroll
            for (int nj = 0; nj < 4; nj++) {
                const int row = wc * 64 + nj * 16 + l15;
                const int slot = (ks * 4 + g) ^ (row & 7);
                bfr[nj].u4 = *(const uint4*)(Bsb + row * 128 + slot * 16);
            }
            __builtin_amdgcn_s_setprio(1);
            #pragma unroll
            for (int mi = 0; mi < 4; mi++)
                #pragma unroll
                for (int nj = 0; nj < 4; nj++)
                    acc[mi][nj] = mfma16(af[mi].v, bfr[nj].v, acc[mi][nj]);
            __builtin_amdgcn_s_setprio(0);
        }
        __builtin_amdgcn_s_barrier();          // all waves done reading buf t&1
        __builtin_amdgcn_sched_barrier(0);
    }

    float bv[4];
    #pragma unroll
    for (int nj = 0; nj < 4; nj++) bv[nj] = bias[n0 + wc * 64 + nj * 16 + l15];
    #pragma unroll
    for (int mi = 0; mi < 4; mi++) {
        #pragma unroll
        for (int rr = 0; rr < 4; rr++) {
            const int r = m0 + wr * 64 + mi * 16 + 4 * g + rr;
            if (r >= M) continue;
            long orow = r;
            if (REMAP) orow = (long)(r / NPATCH) * NTOK + 1 + (r % NPATCH);
            #pragma unroll
            for (int nj = 0; nj < 4; nj++) {
                const int cc = n0 + wc * 64 + nj * 16 + l15;
                const float val = acc[mi][nj][rr] + bv[nj];
                if (OBF16) ((u16*)Cz)[orow * EMB + cc] = f2bf(val);
                else       ((float*)Cz)[orow * EMB + cc] = val;
            }
        }
    }
}

// ---------------- flash attention v11: 8 waves (2/SIMD), r9 schedule, defer-max ------
// 512 thr = 8 waves, each wave 16 q-rows (128 q/block). KV tiles of 32 keys.
//   top __syncthreads : drains vmem -> K(t) in LDS, V(t) in regs; WAR gate for Vt
//   writeV(t)         : regs -> Vt
//   mid __syncthreads : Vt/K visible (nothing in flight -> free drain)
//   stage_K(t+1) GLL + loadV(t+1)   : fly across the whole compute phase
//   compute(t)        : QK^T, defer-max softmax, Ps roundtrip, PV
// LDS 87040 B -> 1 block/CU but 2 waves/SIMD (vs r9's 1/SIMD: the latency-hiding fix).
#define KS_TILE_B 24576   // 32*384*2
#define VTLD 36           // Vt row stride (u16), 72 B (conflict-free; 40 regressed r10)
#define PSLD 40           // Ps row stride (u16)
#define FLASH_LDS (2 * KS_TILE_B + 384 * VTLD * 2 + 8 * 16 * PSLD * 2)  // 87040

__global__ __launch_bounds__(512)
void flash_mfma(const u16* __restrict__ q, const u16* __restrict__ k,
                const u16* __restrict__ v, u16* __restrict__ o)
{
    extern __shared__ char smem[];
    char* KsB = smem;                                   // [2][32][384] u16 (swizzled)
    u16* Vt = (u16*)(smem + 2 * KS_TILE_B);             // [384][VTLD]
    char* Ps = smem + 2 * KS_TILE_B + 384 * VTLD * 2;   // 8 waves x [16][PSLD]

    // XCD-bijective: 384 = 8 * 48; 6 consecutive works share one (b,h)
    const int wg = blockIdx.x;
    const int work = (wg & 7) * 48 + (wg >> 3);
    const int bh = work / 6, qblk = work % 6;
    const int b = bh >> 1, h = bh & 1;
    const int q0 = qblk * 128;
    const int tid = threadIdx.x;
    const int lane = tid & 63, w = tid >> 6;
    const int l15 = lane & 15, g = lane >> 4;
    const int wbase = (tid & ~63);
    const long base = (long)b * NTOK * EMB + h * HD;

    BF8 qf[12];
    {
        const int qrow = q0 + w * 16 + l15;
        if (qrow < NTOK) {
            const u16* src = q + base + (long)qrow * EMB;
            #pragma unroll
            for (int ds = 0; ds < 12; ds++)
                qf[ds].u4 = *(const uint4*)(src + ds * 32 + g * 8);
        } else {
            #pragma unroll
            for (int ds = 0; ds < 12; ds++) qf[ds].u4 = make_uint4(0, 0, 0, 0);
        }
    }

    // K async stage via GLL: 1536 granules = 3 per thread (512 thr)
    auto stage_K = [&](int kv0, int buf) {
        #pragma unroll
        for (int c = 0; c < 3; c++) {
            const int idx = c * 512 + tid;
            const int r = idx / 48, gr = idx % 48;
            const int gsrc = (gr & ~7) | ((gr & 7) ^ (r & 7));
            const int kr = min(kv0 + r, NTOK - 1);
            GLL(k + base + (long)kr * EMB + gsrc * 8,
                KsB + buf * KS_TILE_B + (c * 512 + wbase) * 16);
        }
    };

    // V reg staging: 768 (kp,dseg) tasks over 512 threads; tid<256 handles 2 tasks
    const int kp = tid & 15;
    const int dsegA = tid >> 4;          // 0..31 (all threads)
    const int dsegB = 32 + (tid >> 4);   // 32..47 (threads < 256 only)
    uint4 vaA, vbA, vaB, vbB;
    auto loadV = [&](int kv0) {
        const int kr0 = kv0 + 2 * kp;
        const u16* v0p = v + base + (long)min(kr0, NTOK - 1) * EMB;
        const u16* v1p = v + base + (long)min(kr0 + 1, NTOK - 1) * EMB;
        vaA = *(const uint4*)(v0p + dsegA * 8);
        vbA = *(const uint4*)(v1p + dsegA * 8);
        if (tid < 256) {
            vaB = *(const uint4*)(v0p + dsegB * 8);
            vbB = *(const uint4*)(v1p + dsegB * 8);
        }
    };
    auto writeV = [&](int kv0) {
        const int kr0 = kv0 + 2 * kp;
        const bool ok0 = kr0 < NTOK, ok1 = (kr0 + 1) < NTOK;
        {
            const u16* ae = (const u16*)&vaA;
            const u16* be = (const u16*)&vbA;
            #pragma unroll
            for (int e = 0; e < 8; e++) {
                const u32 lo = ok0 ? (u32)ae[e] : 0u;
                const u32 hi = ok1 ? (u32)be[e] : 0u;
                *(u32*)&Vt[(dsegA * 8 + e) * VTLD + 2 * kp] = lo | (hi << 16);
            }
        }
        if (tid < 256) {
            const u16* ae = (const u16*)&vaB;
            const u16* be = (const u16*)&vbB;
            #pragma unroll
            for (int e = 0; e < 8; e++) {
                const u32 lo = ok0 ? (u32)ae[e] : 0u;
                const u32 hi = ok1 ? (u32)be[e] : 0u;
                *(u32*)&Vt[(dsegB * 8 + e) * VTLD + 2 * kp] = lo | (hi << 16);
            }
        }
    };

    float m_run = -3.0e38f, l_run = 0.f;
    f32x4 oacc[24] = {};

    stage_K(0, 0);
    loadV(0);

    for (int kt = 0; kt < 21; kt++) {
        const int kv0 = kt * 32;
        __syncthreads();   // implicit vmcnt(0): K(kt) in LDS, V(kt) in regs; WAR for Vt
        writeV(kv0);
        __syncthreads();   // Vt(kt)+K(kt) visible; nothing in flight -> free drain
        if (kt < 20) {
            stage_K(kv0 + 32, (kt + 1) & 1);   // async across compute(kt)
            loadV(kv0 + 32);
        }

        const char* kbuf = KsB + (kt & 1) * KS_TILE_B;
        f32x4 sacc[2] = {};
        #pragma unroll
        for (int ds = 0; ds < 12; ds++) {
            const int idx = ds * 4 + g;
            const int slot = (idx & ~7) | ((idx & 7) ^ (l15 & 7));
            BF8 ak0, ak1;
            ak0.u4 = *(const uint4*)(kbuf + l15 * 768 + slot * 16);
            ak1.u4 = *(const uint4*)(kbuf + (16 + l15) * 768 + slot * 16);
            sacc[0] = mfma16(ak0.v, qf[ds].v, sacc[0]);
            sacc[1] = mfma16(ak1.v, qf[ds].v, sacc[1]);
        }

        // ---- mask + online softmax with defer-max (T13, THR=8) ----
        float pe[2][4];
        float mx = -3.0e38f;
        #pragma unroll
        for (int kb = 0; kb < 2; kb++)
            #pragma unroll
            for (int rr = 0; rr < 4; rr++) {
                float s = sacc[kb][rr];
                if (kv0 + kb * 16 + 4 * g + rr >= NTOK) s = -1e30f;
                pe[kb][rr] = s;
                mx = fmaxf(mx, s);
            }
        mx = fmaxf(mx, __shfl_xor(mx, 16, 64));
        mx = fmaxf(mx, __shfl_xor(mx, 32, 64));
        const bool nores = (bool)__all(mx - m_run <= 8.f);
        float m_new = m_run, corr = 1.f;
        if (!nores) {
            m_new = fmaxf(m_run, mx);
            corr = __expf(m_run - m_new);
        }
        float psum = 0.f;
        #pragma unroll
        for (int kb = 0; kb < 2; kb++)
            #pragma unroll
            for (int rr = 0; rr < 4; rr++) {
                pe[kb][rr] = __expf(pe[kb][rr] - m_new);
                psum += pe[kb][rr];
            }
        psum += __shfl_xor(psum, 16, 64);
        psum += __shfl_xor(psum, 32, 64);
        l_run = (nores ? l_run : l_run * corr) + psum;
        m_run = m_new;

        {
            u32* pw = (u32*)(Ps + w * (16 * PSLD * 2) + l15 * (PSLD * 2));
            pw[g * 2]         = pk2(pe[0][0], pe[0][1]);
            pw[g * 2 + 1]     = pk2(pe[0][2], pe[0][3]);
            pw[8 + g * 2]     = pk2(pe[1][0], pe[1][1]);
            pw[8 + g * 2 + 1] = pk2(pe[1][2], pe[1][3]);
        }
        asm volatile("s_waitcnt lgkmcnt(0)" ::: "memory");
        __builtin_amdgcn_sched_barrier(0);
        BF8 pa;
        pa.u4 = *(const uint4*)(Ps + w * (16 * PSLD * 2) + l15 * (PSLD * 2) + g * 16);

        if (!nores) {
            float cb4[4];
            #pragma unroll
            for (int rr = 0; rr < 4; rr++) cb4[rr] = __shfl(corr, 4 * g + rr, 64);
            #pragma unroll
            for (int dc = 0; dc < 24; dc++)
                #pragma unroll
                for (int rr = 0; rr < 4; rr++) oacc[dc][rr] *= cb4[rr];
        }

        #pragma unroll
        for (int dc = 0; dc < 24; dc++) {
            const u16* vp = &Vt[(dc * 16 + l15) * VTLD + g * 8];
            const uint2 lo = *(const uint2*)vp;
            const uint2 hi = *(const uint2*)(vp + 4);
            BF8 vb8;
            vb8.w[0] = lo.x; vb8.w[1] = lo.y; vb8.w[2] = hi.x; vb8.w[3] = hi.y;
            oacc[dc] = mfma16(pa.v, vb8.v, oacc[dc]);
        }
    }

    float linv[4];
    #pragma unroll
    for (int rr = 0; rr < 4; rr++)
        linv[rr] = INV_SQRT_EMB / __shfl(l_run, 4 * g + rr, 64);
    #pragma unroll
    for (int rr = 0; rr < 4; rr++) {
        const int row = q0 + w * 16 + 4 * g + rr;
        if (row < NTOK) {
            u16* dst = o + base + (long)row * EMB;
            #pragma unroll
            for (int dc = 0; dc < 24; dc++)
                dst[dc * 16 + l15] = f2bf(oacc[dc][rr] * linv[rr]);
        }
    }
}

// ---------------- LN2 wave-per-row (bf16 in) + residual-add into t ----------------
__global__ __launch_bounds__(256)
void ln_add_kernel(const u16* __restrict__ in, u16* __restrict__ t,
                   const float* __restrict__ g, const float* __restrict__ be)
{
    const int row = blockIdx.x * 4 + (threadIdx.x >> 6);
    const int lane = threadIdx.x & 63;
    const u16* xp = in + (long)row * EMB;
    float v[12];
    #pragma unroll
    for (int s = 0; s < 3; s++) {
        const uint2 u = *(const uint2*)(xp + lane * 4 + s * 256);
        const u16* e = (const u16*)&u;
        #pragma unroll
        for (int jj = 0; jj < 4; jj++) v[s * 4 + jj] = bf2f(e[jj]);
    }
    float sum = 0.f;
    #pragma unroll
    for (int i = 0; i < 12; i++) sum += v[i];
    const float mu = wave_sum(sum) * (1.f / EMB);
    float vs = 0.f;
    #pragma unroll
    for (int i = 0; i < 12; i++) { v[i] -= mu; vs += v[i] * v[i]; }
    const float rs = rsqrtf(wave_sum(vs) * (1.f / EMB) + LN_EPS);
    u16* o = t + (long)row * EMB;
    #pragma unroll
    for (int s = 0; s < 3; s++) {
        const int col = lane * 4 + s * 256;
        const float4 gv = *(const float4*)(g + col);
        const float4 bv = *(const float4*)(be + col);
        const uint2 told = *(const uint2*)(o + col);
        const u16* te = (const u16*)&told;
        uint2 w;
        w.x = pk2(bf2f(te[0]) + v[s * 4 + 0] * rs * gv.x + bv.x,
                  bf2f(te[1]) + v[s * 4 + 1] * rs * gv.y + bv.y);
        w.y = pk2(bf2f(te[2]) + v[s * 4 + 2] * rs * gv.z + bv.z,
                  bf2f(te[3]) + v[s * 4 + 3] * rs * gv.w + bv.w);
        *(uint2*)(o + col) = w;
    }
}

// ---------------- mean over tokens ----------------
__global__ __launch_bounds__(128)
void meanpool_kernel(const u16* __restrict__ t, float* __restrict__ m)
{
    const int b = blockIdx.y;
    const int e = blockIdx.x * 128 + threadIdx.x;
    const u16* p = t + (long)b * NTOK * EMB + e;
    float s = 0.f;
    for (int j = 0; j < NTOK; j++) s += bf2f(p[(long)j * EMB]);
    m[b * EMB + e] = s * (1.f / NTOK);
}

// ---------------- LN3 + final Linear (fp32) ----------------
__global__ __launch_bounds__(256)
void final_kernel(const float* __restrict__ m, const float* __restrict__ g,
                  const float* __restrict__ be, const float* __restrict__ Wf,
                  const float* __restrict__ bf, float* __restrict__ out)
{
    __shared__ float red[256];
    __shared__ float mln[EMB];
    const int b = blockIdx.x, tid = threadIdx.x;
    const float* x = m + b * EMB;
    const float v0 = x[tid], v1 = x[tid + 256], v2 = x[tid + 512];
    const float mu = blk_sum(v0 + v1 + v2, red, tid) * (1.f / EMB);
    const float d0 = v0 - mu, d1 = v1 - mu, d2 = v2 - mu;
    const float var = blk_sum(d0 * d0 + d1 * d1 + d2 * d2, red, tid) * (1.f / EMB);
    const float rs = rsqrtf(var + LN_EPS);
    mln[tid]       = d0 * rs * g[tid]       + be[tid];
    mln[tid + 256] = d1 * rs * g[tid + 256] + be[tid + 256];
    mln[tid + 512] = d2 * rs * g[tid + 512] + be[tid + 512];
    __syncthreads();
    #pragma unroll
    for (int s = 0; s < 3; s++) {
        const int e = tid + s * 256;
        float acc = bf[e];
        #pragma unroll 8
        for (int kk = 0; kk < EMB; kk++) acc += mln[kk] * Wf[(long)kk * EMB + e];
        out[(long)b * EMB + e] = acc;
    }
}

extern "C" void kernel_launch(void* const* d_in, const int* in_sizes, int n_in,
                              void* d_out, int out_size, void* d_ws, size_t ws_size,
                              hipStream_t stream) {
    const float* x      = (const float*)d_in[0];
    const float* text   = (const float*)d_in[1];
    const float* Wpatch = (const float*)d_in[2];
    const float* bpatch = (const float*)d_in[3];
    const float* cls    = (const float*)d_in[4];
    const float* g1  = (const float*)d_in[5];
    const float* be1 = (const float*)d_in[6];
    const float* Wq  = (const float*)d_in[7];
    const float* bq  = (const float*)d_in[8];
    const float* Wk  = (const float*)d_in[9];
    const float* bk  = (const float*)d_in[10];
    const float* Wv  = (const float*)d_in[11];
    const float* bv  = (const float*)d_in[12];
    const float* Wp  = (const float*)d_in[13];
    const float* bp  = (const float*)d_in[14];
    const float* g2  = (const float*)d_in[15];
    const float* be2 = (const float*)d_in[16];
    const float* g3  = (const float*)d_in[17];
    const float* be3 = (const float*)d_in[18];
    const float* Wf  = (const float*)d_in[19];
    const float* bf  = (const float*)d_in[20];

    // ws layout (~167 MB): t | h | q | k | v (bf16, 5 x 32.1 MB)
    //  pat aliases qb (dead until QKV); o2 (bf16) aliases kbf (dead post-flash)
    //  Wt bf16 (5 x 1.18 MB) | mp fp32
    char* ws = (char*)d_ws;
    const size_t S2 = (size_t)MROWS * EMB * 2;   // 32,145,408
    u16*   t    = (u16*)ws;
    u16*   hb   = (u16*)(ws + S2);
    u16*   qb   = (u16*)(ws + 2 * S2);
    u16*   kbf  = (u16*)(ws + 3 * S2);
    u16*   vbf  = (u16*)(ws + 4 * S2);
    u16*   o2b  = kbf;   // after flash, k is dead
    u16*   wt   = (u16*)(ws + 5 * S2);
    float* mp   = (float*)(ws + 5 * S2 + (size_t)5 * EMB * EMB * 2);
    u16*   pat  = qb;    // im2col output aliases q
    const size_t WTS = (size_t)EMB * EMB;
    const int DLDS = 2 * 2 * DTILE_B;   // 65536

    // 1) weights -> bf16 transposed
    wt_kernel<<<dim3(24, 24, 5), 256, 0, stream>>>(Wpatch, Wq, Wk, Wv, Wp, wt);
    // 2) cls + text rows of t
    fill_rows_kernel<<<dim3(NTEXT + 1, NBATCH), 256, 0, stream>>>(cls, text, t);
    // 3) im2col v2 -> patches (aliases q), coalesced writes
    im2col_kernel<<<4608, 384, 0, stream>>>(x, pat);
    // 4) patch embed: dense GEMM with row remap -> t   (864 = 8*108 blocks)
    dense_gemm<true, true><<<864, 256, DLDS, stream>>>(
        pat, wt, bpatch, bpatch, bpatch, t, t, t, NBATCH * NPATCH, 6);
    // 5) h = LN1(t), wave-per-row
    ln_h_kernel<<<MROWS / 4, 256, 0, stream>>>(t, hb, g1, be1);
    // 6) fused QKV: nb=18, z selects Wq/Wk/Wv  (2952 = 8*369 blocks)
    dense_gemm<true, false><<<2952, 256, DLDS, stream>>>(
        hb, wt + WTS, bq, bk, bv, qb, kbf, vbf, MROWS, 18);
    // 7) flash attention v11 (o over q), 384 = 8*48 blocks, 512 thr
    flash_mfma<<<384, 512, FLASH_LDS, stream>>>(qb, kbf, vbf, qb);
    // 8) proj -> o2 bf16 (aliases kbf)   (984 = 8*123 blocks)
    dense_gemm<true, false><<<984, 256, DLDS, stream>>>(
        qb, wt + 4 * WTS, bp, bp, bp, o2b, o2b, o2b, MROWS, 6);
    // 9) t += LN2(o2), wave-per-row
    ln_add_kernel<<<MROWS / 4, 256, 0, stream>>>(o2b, t, g2, be2);
    // 10) mean pool
    meanpool_kernel<<<dim3(6, NBATCH), 128, 0, stream>>>(t, mp);
    // 11) LN3 + final linear
    final_kernel<<<NBATCH, 256, 0, stream>>>(mp, g3, be3, Wf, bf, (float*)d_out);
}

// Round 15
// 394.668 us; speedup vs baseline: 1.6673x; 1.2441x over previous
//
#include <hip/hip_runtime.h>
#include <hip/hip_bf16.h>
#include <math.h>

#define EMB 768
#define NTOK 654
#define NPATCH 576
#define NTEXT 77
#define NBATCH 32
#define HD 384
#define MROWS (NBATCH * NTOK)   // 20928
#define LN_EPS 1e-5f
#define INV_SQRT_EMB 0.03608439182435161f

typedef unsigned int u32;
typedef unsigned short u16;
typedef float f32x4 __attribute__((ext_vector_type(4)));
typedef __bf16 bf16x8 __attribute__((ext_vector_type(8)));

union BF8 { uint4 u4; u32 w[4]; bf16x8 v; };

// async global->LDS, 16B per lane; dest = wave-uniform base + lane*16
#define GLL(gsrc, ldst) __builtin_amdgcn_global_load_lds( \
    (const __attribute__((address_space(1))) unsigned int*)(gsrc), \
    (__attribute__((address_space(3))) unsigned int*)(ldst), 16, 0, 0)

// ---------------- helpers ----------------
__device__ __forceinline__ float bf2f(u16 u) {
    union { u32 i; float f; } x; x.i = ((u32)u) << 16; return x.f;
}
__device__ __forceinline__ u16 f2bf(float f) {  // RTNE
    union { float f; u32 i; } x; x.f = f;
    u32 r = x.i + 0x7fffu + ((x.i >> 16) & 1u);
    return (u16)(r >> 16);
}
__device__ __forceinline__ u32 pk2(float lo, float hi) {
    return (u32)f2bf(lo) | ((u32)f2bf(hi) << 16);
}
__device__ __forceinline__ float blk_sum(float v, float* red, int tid) {
    red[tid] = v; __syncthreads();
    #pragma unroll
    for (int s = 128; s > 0; s >>= 1) {
        if (tid < s) red[tid] += red[tid + s];
        __syncthreads();
    }
    float r = red[0]; __syncthreads();
    return r;
}
__device__ __forceinline__ float wave_sum(float v) {
    #pragma unroll
    for (int off = 1; off < 64; off <<= 1) v += __shfl_xor(v, off, 64);
    return v;
}
__device__ __forceinline__ f32x4 mfma16(bf16x8 a, bf16x8 b, f32x4 c) {
    return __builtin_amdgcn_mfma_f32_16x16x32_bf16(a, b, c, 0, 0, 0);
}

// ---------------- weight transpose + bf16: Wt[n][k] = bf16(W[k][n]) ----------------
__global__ __launch_bounds__(256)
void wt_kernel(const float* __restrict__ W0, const float* __restrict__ W1,
               const float* __restrict__ W2, const float* __restrict__ W3,
               const float* __restrict__ W4, u16* __restrict__ dst)
{
    __shared__ float tile[32][33];
    const int z = blockIdx.z;
    const float* W = (z == 0) ? W0 : (z == 1) ? W1 : (z == 2) ? W2 : (z == 3) ? W3 : W4;
    u16* o = dst + (size_t)z * EMB * EMB;
    const int bi = blockIdx.y, bj = blockIdx.x;
    const int r = threadIdx.x >> 5, c = threadIdx.x & 31;
    #pragma unroll
    for (int i = 0; i < 4; i++)
        tile[r + i * 8][c] = W[(long)(bi * 32 + r + i * 8) * EMB + bj * 32 + c];
    __syncthreads();
    #pragma unroll
    for (int i = 0; i < 4; i++) {
        const int rr = r + i * 8;
        o[(long)(bj * 32 + rr) * EMB + bi * 32 + c] = f2bf(tile[c][rr]);
    }
}

// ---------------- fill cls + text rows of t (bf16) ----------------
__global__ __launch_bounds__(256)
void fill_rows_kernel(const float* __restrict__ cls, const float* __restrict__ text,
                      u16* __restrict__ t)
{
    const int b = blockIdx.y, r = blockIdx.x;
    const int tid = threadIdx.x;
    const long trow = (long)b * NTOK + (r == 0 ? 0 : NPATCH + r);
    const float* src = (r == 0) ? cls : text + ((long)b * NTEXT + (r - 1)) * EMB;
    u16* dst = t + trow * EMB;
    #pragma unroll
    for (int s = 0; s < 3; s++) dst[tid + s * 256] = f2bf(src[tid + s * 256]);
}

// ---------------- im2col v2: coalesced uint4 writes ----------------
__global__ __launch_bounds__(384)
void im2col_kernel(const float* __restrict__ x, u16* __restrict__ patches)
{
    const int row = blockIdx.x * 4 + threadIdx.x / 96;   // 0..18431
    const int j = threadIdx.x % 96;
    const int bb = row / NPATCH, rem = row % NPATCH;
    const int hh = rem / 24, ww = rem % 24;
    union { u16 s[8]; uint4 v; } out;
    #pragma unroll
    for (int e = 0; e < 8; e++) {
        const int col = j * 8 + e;
        const int p1 = col / 48, r2 = col % 48, p2 = r2 / 3, c = r2 % 3;
        out.s[e] = f2bf(x[((long)(bb * 3 + c) * 384 + hh * 16 + p1) * 384 + ww * 16 + p2]);
    }
    *(uint4*)(patches + (long)row * EMB + j * 8) = out.v;
}

// ---------------- LN1 wave-per-row: t(bf16) -> h(bf16), no barriers ----------------
__global__ __launch_bounds__(256)
void ln_h_kernel(const u16* __restrict__ t, u16* __restrict__ h,
                 const float* __restrict__ g, const float* __restrict__ be)
{
    const int row = blockIdx.x * 4 + (threadIdx.x >> 6);
    const int lane = threadIdx.x & 63;
    const u16* xp = t + (long)row * EMB;
    float v[12];
    #pragma unroll
    for (int s = 0; s < 3; s++) {
        const uint2 u = *(const uint2*)(xp + lane * 4 + s * 256);
        const u16* e = (const u16*)&u;
        #pragma unroll
        for (int jj = 0; jj < 4; jj++) v[s * 4 + jj] = bf2f(e[jj]);
    }
    float sum = 0.f;
    #pragma unroll
    for (int i = 0; i < 12; i++) sum += v[i];
    const float mu = wave_sum(sum) * (1.f / EMB);
    float vs = 0.f;
    #pragma unroll
    for (int i = 0; i < 12; i++) { v[i] -= mu; vs += v[i] * v[i]; }
    const float rs = rsqrtf(wave_sum(vs) * (1.f / EMB) + LN_EPS);
    u16* o = h + (long)row * EMB;
    #pragma unroll
    for (int s = 0; s < 3; s++) {
        const int col = lane * 4 + s * 256;
        const float4 gv = *(const float4*)(g + col);
        const float4 bv = *(const float4*)(be + col);
        uint2 w;
        w.x = pk2(v[s * 4 + 0] * rs * gv.x + bv.x, v[s * 4 + 1] * rs * gv.y + bv.y);
        w.y = pk2(v[s * 4 + 2] * rs * gv.z + bv.z, v[s * 4 + 3] * rs * gv.w + bv.w);
        *(uint2*)(o + col) = w;
    }
}

// ---------------- dense MFMA GEMM v3: GLL dbuf + counted vmcnt + RAW barriers --------
#define DBK 64
#define DTILE_B (128 * DBK * 2)   // 16384 B per operand tile

template<bool OBF16, bool REMAP>
__global__ __launch_bounds__(256)
void dense_gemm(const u16* __restrict__ A, const u16* __restrict__ Bt,
                const float* __restrict__ b0, const float* __restrict__ b1,
                const float* __restrict__ b2,
                void* __restrict__ C0, void* __restrict__ C1, void* __restrict__ C2,
                int M, int nb)
{
    extern __shared__ char sm[];   // [2][A|B][128][64]u16 = 65536 B
    const int cpx = gridDim.x >> 3;
    const int wg = blockIdx.x;
    const int work = (wg & 7) * cpx + (wg >> 3);
    const int cb = work % nb;
    const int m0 = (work / nb) * 128;
    const int z  = cb / 6;
    const int n0 = (cb % 6) * 128;
    const u16* Btz = Bt + (size_t)z * EMB * EMB;
    const float* bias = (z == 0) ? b0 : (z == 1) ? b1 : b2;
    void* Cz = (z == 0) ? C0 : (z == 1) ? C1 : C2;

    const int tid = threadIdx.x;
    const int lane = tid & 63, w = tid >> 6, wr = w >> 1, wc = w & 1;
    const int l15 = lane & 15, g = lane >> 4;
    const int wbase = (tid & ~63);

    f32x4 acc[4][4] = {};

    auto stage = [&](int k0, int buf) {
        char* dst = sm + buf * 2 * DTILE_B;
        #pragma unroll
        for (int c = 0; c < 4; c++) {
            const int idx = c * 256 + tid;
            const int r = idx >> 3, s = idx & 7;
            const int gs = s ^ (r & 7);
            const int ar = min(m0 + r, M - 1);
            GLL(A + (long)ar * EMB + k0 + gs * 8, dst + (c * 256 + wbase) * 16);
        }
        #pragma unroll
        for (int c = 0; c < 4; c++) {
            const int idx = c * 256 + tid;
            const int r = idx >> 3, s = idx & 7;
            const int gs = s ^ (r & 7);
            GLL(Btz + (long)(n0 + r) * EMB + k0 + gs * 8,
                dst + DTILE_B + (c * 256 + wbase) * 16);
        }
    };

    stage(0, 0);
    for (int t = 0; t < 12; t++) {
        if (t < 11) {
            stage((t + 1) * DBK, (t + 1) & 1);
            asm volatile("s_waitcnt vmcnt(8)" ::: "memory");   // tile t landed; t+1 in flight
        } else {
            asm volatile("s_waitcnt vmcnt(0)" ::: "memory");
        }
        __builtin_amdgcn_s_barrier();          // all waves' tile-t loads landed
        __builtin_amdgcn_sched_barrier(0);
        const char* Asb = sm + (t & 1) * 2 * DTILE_B;
        const char* Bsb = Asb + DTILE_B;
        #pragma unroll
        for (int ks = 0; ks < 2; ks++) {
            BF8 af[4], bfr[4];
            #pragma unroll
            for (int mi = 0; mi < 4; mi++) {
                const int row = wr * 64 + mi * 16 + l15;
                const int slot = (ks * 4 + g) ^ (row & 7);
                af[mi].u4 = *(const uint4*)(Asb + row * 128 + slot * 16);
            }
            #pragma unroll
            for (int nj = 0; nj < 4; nj++) {
                const int row = wc * 64 + nj * 16 + l15;
                const int slot = (ks * 4 + g) ^ (row & 7);
                bfr[nj].u4 = *(const uint4*)(Bsb + row * 128 + slot * 16);
            }
            __builtin_amdgcn_s_setprio(1);
            #pragma unroll
            for (int mi = 0; mi < 4; mi++)
                #pragma unroll
                for (int nj = 0; nj < 4; nj++)
                    acc[mi][nj] = mfma16(af[mi].v, bfr[nj].v, acc[mi][nj]);
            __builtin_amdgcn_s_setprio(0);
        }
        __builtin_amdgcn_s_barrier();          // all waves done reading buf t&1
        __builtin_amdgcn_sched_barrier(0);
    }

    float bv[4];
    #pragma unroll
    for (int nj = 0; nj < 4; nj++) bv[nj] = bias[n0 + wc * 64 + nj * 16 + l15];
    #pragma unroll
    for (int mi = 0; mi < 4; mi++) {
        #pragma unroll
        for (int rr = 0; rr < 4; rr++) {
            const int r = m0 + wr * 64 + mi * 16 + 4 * g + rr;
            if (r >= M) continue;
            long orow = r;
            if (REMAP) orow = (long)(r / NPATCH) * NTOK + 1 + (r % NPATCH);
            #pragma unroll
            for (int nj = 0; nj < 4; nj++) {
                const int cc = n0 + wc * 64 + nj * 16 + l15;
                const float val = acc[mi][nj][rr] + bv[nj];
                if (OBF16) ((u16*)Cz)[orow * EMB + cc] = f2bf(val);
                else       ((float*)Cz)[orow * EMB + cc] = val;
            }
        }
    }
}

// ---------------- flash attention v11: 8 waves (2/SIMD), r9 schedule, defer-max ------
#define KS_TILE_B 24576   // 32*384*2
#define VTLD 36           // Vt row stride (u16), 72 B (conflict-free; 40 regressed r10)
#define PSLD 40           // Ps row stride (u16)
#define FLASH_LDS (2 * KS_TILE_B + 384 * VTLD * 2 + 8 * 16 * PSLD * 2)  // 87040

__global__ __launch_bounds__(512)
void flash_mfma(const u16* __restrict__ q, const u16* __restrict__ k,
                const u16* __restrict__ v, u16* __restrict__ o)
{
    extern __shared__ char smem[];
    char* KsB = smem;                                   // [2][32][384] u16 (swizzled)
    u16* Vt = (u16*)(smem + 2 * KS_TILE_B);             // [384][VTLD]
    char* Ps = smem + 2 * KS_TILE_B + 384 * VTLD * 2;   // 8 waves x [16][PSLD]

    // XCD-bijective: 384 = 8 * 48; 6 consecutive works share one (b,h)
    const int wg = blockIdx.x;
    const int work = (wg & 7) * 48 + (wg >> 3);
    const int bh = work / 6, qblk = work % 6;
    const int b = bh >> 1, h = bh & 1;
    const int q0 = qblk * 128;
    const int tid = threadIdx.x;
    const int lane = tid & 63, w = tid >> 6;
    const int l15 = lane & 15, g = lane >> 4;
    const int wbase = (tid & ~63);
    const long base = (long)b * NTOK * EMB + h * HD;

    BF8 qf[12];
    {
        const int qrow = q0 + w * 16 + l15;
        if (qrow < NTOK) {
            const u16* src = q + base + (long)qrow * EMB;
            #pragma unroll
            for (int ds = 0; ds < 12; ds++)
                qf[ds].u4 = *(const uint4*)(src + ds * 32 + g * 8);
        } else {
            #pragma unroll
            for (int ds = 0; ds < 12; ds++) qf[ds].u4 = make_uint4(0, 0, 0, 0);
        }
    }

    // K async stage via GLL: 1536 granules = 3 per thread (512 thr)
    auto stage_K = [&](int kv0, int buf) {
        #pragma unroll
        for (int c = 0; c < 3; c++) {
            const int idx = c * 512 + tid;
            const int r = idx / 48, gr = idx % 48;
            const int gsrc = (gr & ~7) | ((gr & 7) ^ (r & 7));
            const int kr = min(kv0 + r, NTOK - 1);
            GLL(k + base + (long)kr * EMB + gsrc * 8,
                KsB + buf * KS_TILE_B + (c * 512 + wbase) * 16);
        }
    };

    // V reg staging: 768 (kp,dseg) tasks over 512 threads; tid<256 handles 2 tasks
    const int kp = tid & 15;
    const int dsegA = tid >> 4;          // 0..31 (all threads)
    const int dsegB = 32 + (tid >> 4);   // 32..47 (threads < 256 only)
    uint4 vaA, vbA, vaB, vbB;
    auto loadV = [&](int kv0) {
        const int kr0 = kv0 + 2 * kp;
        const u16* v0p = v + base + (long)min(kr0, NTOK - 1) * EMB;
        const u16* v1p = v + base + (long)min(kr0 + 1, NTOK - 1) * EMB;
        vaA = *(const uint4*)(v0p + dsegA * 8);
        vbA = *(const uint4*)(v1p + dsegA * 8);
        if (tid < 256) {
            vaB = *(const uint4*)(v0p + dsegB * 8);
            vbB = *(const uint4*)(v1p + dsegB * 8);
        }
    };
    auto writeV = [&](int kv0) {
        const int kr0 = kv0 + 2 * kp;
        const bool ok0 = kr0 < NTOK, ok1 = (kr0 + 1) < NTOK;
        {
            const u16* ae = (const u16*)&vaA;
            const u16* be = (const u16*)&vbA;
            #pragma unroll
            for (int e = 0; e < 8; e++) {
                const u32 lo = ok0 ? (u32)ae[e] : 0u;
                const u32 hi = ok1 ? (u32)be[e] : 0u;
                *(u32*)&Vt[(dsegA * 8 + e) * VTLD + 2 * kp] = lo | (hi << 16);
            }
        }
        if (tid < 256) {
            const u16* ae = (const u16*)&vaB;
            const u16* be = (const u16*)&vbB;
            #pragma unroll
            for (int e = 0; e < 8; e++) {
                const u32 lo = ok0 ? (u32)ae[e] : 0u;
                const u32 hi = ok1 ? (u32)be[e] : 0u;
                *(u32*)&Vt[(dsegB * 8 + e) * VTLD + 2 * kp] = lo | (hi << 16);
            }
        }
    };

    float m_run = -3.0e38f, l_run = 0.f;
    f32x4 oacc[24] = {};

    stage_K(0, 0);
    loadV(0);

    for (int kt = 0; kt < 21; kt++) {
        const int kv0 = kt * 32;
        __syncthreads();   // implicit vmcnt(0): K(kt) in LDS, V(kt) in regs; WAR for Vt
        writeV(kv0);
        __syncthreads();   // Vt(kt)+K(kt) visible; nothing in flight -> free drain
        if (kt < 20) {
            stage_K(kv0 + 32, (kt + 1) & 1);   // async across compute(kt)
            loadV(kv0 + 32);
        }

        const char* kbuf = KsB + (kt & 1) * KS_TILE_B;
        f32x4 sacc[2] = {};
        #pragma unroll
        for (int ds = 0; ds < 12; ds++) {
            const int idx = ds * 4 + g;
            const int slot = (idx & ~7) | ((idx & 7) ^ (l15 & 7));
            BF8 ak0, ak1;
            ak0.u4 = *(const uint4*)(kbuf + l15 * 768 + slot * 16);
            ak1.u4 = *(const uint4*)(kbuf + (16 + l15) * 768 + slot * 16);
            sacc[0] = mfma16(ak0.v, qf[ds].v, sacc[0]);
            sacc[1] = mfma16(ak1.v, qf[ds].v, sacc[1]);
        }

        // ---- mask + online softmax with defer-max (T13, THR=8) ----
        float pe[2][4];
        float mx = -3.0e38f;
        #pragma unroll
        for (int kb = 0; kb < 2; kb++)
            #pragma unroll
            for (int rr = 0; rr < 4; rr++) {
                float s = sacc[kb][rr];
                if (kv0 + kb * 16 + 4 * g + rr >= NTOK) s = -1e30f;
                pe[kb][rr] = s;
                mx = fmaxf(mx, s);
            }
        mx = fmaxf(mx, __shfl_xor(mx, 16, 64));
        mx = fmaxf(mx, __shfl_xor(mx, 32, 64));
        const bool nores = (bool)__all(mx - m_run <= 8.f);
        float m_new = m_run, corr = 1.f;
        if (!nores) {
            m_new = fmaxf(m_run, mx);
            corr = __expf(m_run - m_new);
        }
        float psum = 0.f;
        #pragma unroll
        for (int kb = 0; kb < 2; kb++)
            #pragma unroll
            for (int rr = 0; rr < 4; rr++) {
                pe[kb][rr] = __expf(pe[kb][rr] - m_new);
                psum += pe[kb][rr];
            }
        psum += __shfl_xor(psum, 16, 64);
        psum += __shfl_xor(psum, 32, 64);
        l_run = (nores ? l_run : l_run * corr) + psum;
        m_run = m_new;

        {
            u32* pw = (u32*)(Ps + w * (16 * PSLD * 2) + l15 * (PSLD * 2));
            pw[g * 2]         = pk2(pe[0][0], pe[0][1]);
            pw[g * 2 + 1]     = pk2(pe[0][2], pe[0][3]);
            pw[8 + g * 2]     = pk2(pe[1][0], pe[1][1]);
            pw[8 + g * 2 + 1] = pk2(pe[1][2], pe[1][3]);
        }
        asm volatile("s_waitcnt lgkmcnt(0)" ::: "memory");
        __builtin_amdgcn_sched_barrier(0);
        BF8 pa;
        pa.u4 = *(const uint4*)(Ps + w * (16 * PSLD * 2) + l15 * (PSLD * 2) + g * 16);

        if (!nores) {
            float cb4[4];
            #pragma unroll
            for (int rr = 0; rr < 4; rr++) cb4[rr] = __shfl(corr, 4 * g + rr, 64);
            #pragma unroll
            for (int dc = 0; dc < 24; dc++)
                #pragma unroll
                for (int rr = 0; rr < 4; rr++) oacc[dc][rr] *= cb4[rr];
        }

        #pragma unroll
        for (int dc = 0; dc < 24; dc++) {
            const u16* vp = &Vt[(dc * 16 + l15) * VTLD + g * 8];
            const uint2 lo = *(const uint2*)vp;
            const uint2 hi = *(const uint2*)(vp + 4);
            BF8 vb8;
            vb8.w[0] = lo.x; vb8.w[1] = lo.y; vb8.w[2] = hi.x; vb8.w[3] = hi.y;
            oacc[dc] = mfma16(pa.v, vb8.v, oacc[dc]);
        }
    }

    float linv[4];
    #pragma unroll
    for (int rr = 0; rr < 4; rr++)
        linv[rr] = INV_SQRT_EMB / __shfl(l_run, 4 * g + rr, 64);
    #pragma unroll
    for (int rr = 0; rr < 4; rr++) {
        const int row = q0 + w * 16 + 4 * g + rr;
        if (row < NTOK) {
            u16* dst = o + base + (long)row * EMB;
            #pragma unroll
            for (int dc = 0; dc < 24; dc++)
                dst[dc * 16 + l15] = f2bf(oacc[dc][rr] * linv[rr]);
        }
    }
}

// ---------------- LN2 wave-per-row (bf16 in) + residual-add into t ----------------
__global__ __launch_bounds__(256)
void ln_add_kernel(const u16* __restrict__ in, u16* __restrict__ t,
                   const float* __restrict__ g, const float* __restrict__ be)
{
    const int row = blockIdx.x * 4 + (threadIdx.x >> 6);
    const int lane = threadIdx.x & 63;
    const u16* xp = in + (long)row * EMB;
    float v[12];
    #pragma unroll
    for (int s = 0; s < 3; s++) {
        const uint2 u = *(const uint2*)(xp + lane * 4 + s * 256);
        const u16* e = (const u16*)&u;
        #pragma unroll
        for (int jj = 0; jj < 4; jj++) v[s * 4 + jj] = bf2f(e[jj]);
    }
    float sum = 0.f;
    #pragma unroll
    for (int i = 0; i < 12; i++) sum += v[i];
    const float mu = wave_sum(sum) * (1.f / EMB);
    float vs = 0.f;
    #pragma unroll
    for (int i = 0; i < 12; i++) { v[i] -= mu; vs += v[i] * v[i]; }
    const float rs = rsqrtf(wave_sum(vs) * (1.f / EMB) + LN_EPS);
    u16* o = t + (long)row * EMB;
    #pragma unroll
    for (int s = 0; s < 3; s++) {
        const int col = lane * 4 + s * 256;
        const float4 gv = *(const float4*)(g + col);
        const float4 bv = *(const float4*)(be + col);
        const uint2 told = *(const uint2*)(o + col);
        const u16* te = (const u16*)&told;
        uint2 w;
        w.x = pk2(bf2f(te[0]) + v[s * 4 + 0] * rs * gv.x + bv.x,
                  bf2f(te[1]) + v[s * 4 + 1] * rs * gv.y + bv.y);
        w.y = pk2(bf2f(te[2]) + v[s * 4 + 2] * rs * gv.z + bv.z,
                  bf2f(te[3]) + v[s * 4 + 3] * rs * gv.w + bv.w);
        *(uint2*)(o + col) = w;
    }
}

// ---------------- mean over tokens ----------------
__global__ __launch_bounds__(128)
void meanpool_kernel(const u16* __restrict__ t, float* __restrict__ m)
{
    const int b = blockIdx.y;
    const int e = blockIdx.x * 128 + threadIdx.x;
    const u16* p = t + (long)b * NTOK * EMB + e;
    float s = 0.f;
    for (int j = 0; j < NTOK; j++) s += bf2f(p[(long)j * EMB]);
    m[b * EMB + e] = s * (1.f / NTOK);
}

// ---------------- LN3: m[32][768] -> mln fp32 ----------------
__global__ __launch_bounds__(256)
void ln3_kernel(const float* __restrict__ m, const float* __restrict__ g,
                const float* __restrict__ be, float* __restrict__ mln)
{
    __shared__ float red[256];
    const int b = blockIdx.x, tid = threadIdx.x;
    const float* x = m + b * EMB;
    const float v0 = x[tid], v1 = x[tid + 256], v2 = x[tid + 512];
    const float mu = blk_sum(v0 + v1 + v2, red, tid) * (1.f / EMB);
    const float d0 = v0 - mu, d1 = v1 - mu, d2 = v2 - mu;
    const float var = blk_sum(d0 * d0 + d1 * d1 + d2 * d2, red, tid) * (1.f / EMB);
    const float rs = rsqrtf(var + LN_EPS);
    float* o = mln + (long)b * EMB;
    o[tid]       = d0 * rs * g[tid]       + be[tid];
    o[tid + 256] = d1 * rs * g[tid + 256] + be[tid + 256];
    o[tid + 512] = d2 * rs * g[tid + 512] + be[tid + 512];
}

// ---------------- final GEMM: out[32][768] = mln @ Wf + bf, 768 blocks ----------------
// block (e-chunk of 32, batch b); 8 k-groups x 32 cols; LDS tree-reduce.
__global__ __launch_bounds__(256)
void final_gemm(const float* __restrict__ mln, const float* __restrict__ Wf,
                const float* __restrict__ bfv, float* __restrict__ out)
{
    __shared__ float sml[EMB];
    __shared__ float red[8][32];
    const int b = blockIdx.y, e0 = blockIdx.x * 32;
    const int tid = threadIdx.x;
    for (int i = tid; i < EMB; i += 256) sml[i] = mln[(long)b * EMB + i];
    __syncthreads();
    const int kg = tid >> 5, col = tid & 31, e = e0 + col;
    float acc = 0.f;
    const float* wp = Wf + (long)(kg * 96) * EMB + e;
    const float* mp = sml + kg * 96;
    #pragma unroll 8
    for (int kk = 0; kk < 96; kk++) acc += mp[kk] * wp[(long)kk * EMB];
    red[kg][col] = acc;
    __syncthreads();
    if (kg == 0) {
        float s = bfv[e];
        #pragma unroll
        for (int i = 0; i < 8; i++) s += red[i][col];
        out[(long)b * EMB + e] = s;
    }
}

extern "C" void kernel_launch(void* const* d_in, const int* in_sizes, int n_in,
                              void* d_out, int out_size, void* d_ws, size_t ws_size,
                              hipStream_t stream) {
    const float* x      = (const float*)d_in[0];
    const float* text   = (const float*)d_in[1];
    const float* Wpatch = (const float*)d_in[2];
    const float* bpatch = (const float*)d_in[3];
    const float* cls    = (const float*)d_in[4];
    const float* g1  = (const float*)d_in[5];
    const float* be1 = (const float*)d_in[6];
    const float* Wq  = (const float*)d_in[7];
    const float* bq  = (const float*)d_in[8];
    const float* Wk  = (const float*)d_in[9];
    const float* bk  = (const float*)d_in[10];
    const float* Wv  = (const float*)d_in[11];
    const float* bv  = (const float*)d_in[12];
    const float* Wp  = (const float*)d_in[13];
    const float* bp  = (const float*)d_in[14];
    const float* g2  = (const float*)d_in[15];
    const float* be2 = (const float*)d_in[16];
    const float* g3  = (const float*)d_in[17];
    const float* be3 = (const float*)d_in[18];
    const float* Wf  = (const float*)d_in[19];
    const float* bf  = (const float*)d_in[20];

    // ws layout (~167 MB): t | h | q | k | v (bf16, 5 x 32.1 MB)
    //  pat aliases qb (dead until QKV); o2 (bf16) aliases kbf (dead post-flash)
    //  Wt bf16 (5 x 1.18 MB) | mp fp32 | mln fp32
    char* ws = (char*)d_ws;
    const size_t S2 = (size_t)MROWS * EMB * 2;   // 32,145,408
    u16*   t    = (u16*)ws;
    u16*   hb   = (u16*)(ws + S2);
    u16*   qb   = (u16*)(ws + 2 * S2);
    u16*   kbf  = (u16*)(ws + 3 * S2);
    u16*   vbf  = (u16*)(ws + 4 * S2);
    u16*   o2b  = kbf;   // after flash, k is dead
    u16*   wt   = (u16*)(ws + 5 * S2);
    float* mp   = (float*)(ws + 5 * S2 + (size_t)5 * EMB * EMB * 2);
    float* mln  = mp + (size_t)NBATCH * EMB;
    u16*   pat  = qb;    // im2col output aliases q
    const size_t WTS = (size_t)EMB * EMB;
    const int DLDS = 2 * 2 * DTILE_B;   // 65536

    // 1) weights -> bf16 transposed
    wt_kernel<<<dim3(24, 24, 5), 256, 0, stream>>>(Wpatch, Wq, Wk, Wv, Wp, wt);
    // 2) cls + text rows of t
    fill_rows_kernel<<<dim3(NTEXT + 1, NBATCH), 256, 0, stream>>>(cls, text, t);
    // 3) im2col v2 -> patches (aliases q), coalesced writes
    im2col_kernel<<<4608, 384, 0, stream>>>(x, pat);
    // 4) patch embed: dense GEMM with row remap -> t   (864 = 8*108 blocks)
    dense_gemm<true, true><<<864, 256, DLDS, stream>>>(
        pat, wt, bpatch, bpatch, bpatch, t, t, t, NBATCH * NPATCH, 6);
    // 5) h = LN1(t), wave-per-row
    ln_h_kernel<<<MROWS / 4, 256, 0, stream>>>(t, hb, g1, be1);
    // 6) fused QKV: nb=18, z selects Wq/Wk/Wv  (2952 = 8*369 blocks)
    dense_gemm<true, false><<<2952, 256, DLDS, stream>>>(
        hb, wt + WTS, bq, bk, bv, qb, kbf, vbf, MROWS, 18);
    // 7) flash attention v11 (o over q), 384 = 8*48 blocks, 512 thr
    flash_mfma<<<384, 512, FLASH_LDS, stream>>>(qb, kbf, vbf, qb);
    // 8) proj -> o2 bf16 (aliases kbf)   (984 = 8*123 blocks)
    dense_gemm<true, false><<<984, 256, DLDS, stream>>>(
        qb, wt + 4 * WTS, bp, bp, bp, o2b, o2b, o2b, MROWS, 6);
    // 9) t += LN2(o2), wave-per-row
    ln_add_kernel<<<MROWS / 4, 256, 0, stream>>>(o2b, t, g2, be2);
    // 10) mean pool
    meanpool_kernel<<<dim3(6, NBATCH), 128, 0, stream>>>(t, mp);
    // 11) LN3 -> mln
    ln3_kernel<<<NBATCH, 256, 0, stream>>>(mp, g3, be3, mln);
    // 12) final GEMM, 768 blocks
    final_gemm<<<dim3(24, NBATCH), 256, 0, stream>>>(mln, Wf, bf, (float*)d_out);
}

// Round 16
// 356.887 us; speedup vs baseline: 1.8438x; 1.1059x over previous
//
#include <hip/hip_runtime.h>
#include <hip/hip_bf16.h>
#include <math.h>

#define EMB 768
#define NTOK 654
#define NPATCH 576
#define NTEXT 77
#define NBATCH 32
#define HD 384
#define MROWS (NBATCH * NTOK)   // 20928
#define LN_EPS 1e-5f
#define INV_SQRT_EMB 0.03608439182435161f

typedef unsigned int u32;
typedef unsigned short u16;
typedef float f32x4 __attribute__((ext_vector_type(4)));
typedef __bf16 bf16x8 __attribute__((ext_vector_type(8)));

union BF8 { uint4 u4; u32 w[4]; bf16x8 v; };

// async global->LDS, 16B per lane; dest = wave-uniform base + lane*16
#define GLL(gsrc, ldst) __builtin_amdgcn_global_load_lds( \
    (const __attribute__((address_space(1))) unsigned int*)(gsrc), \
    (__attribute__((address_space(3))) unsigned int*)(ldst), 16, 0, 0)

// ---------------- helpers ----------------
__device__ __forceinline__ float bf2f(u16 u) {
    union { u32 i; float f; } x; x.i = ((u32)u) << 16; return x.f;
}
__device__ __forceinline__ u16 f2bf(float f) {  // RTNE
    union { float f; u32 i; } x; x.f = f;
    u32 r = x.i + 0x7fffu + ((x.i >> 16) & 1u);
    return (u16)(r >> 16);
}
__device__ __forceinline__ u32 pk2(float lo, float hi) {
    return (u32)f2bf(lo) | ((u32)f2bf(hi) << 16);
}
__device__ __forceinline__ float blk_sum(float v, float* red, int tid) {
    red[tid] = v; __syncthreads();
    #pragma unroll
    for (int s = 128; s > 0; s >>= 1) {
        if (tid < s) red[tid] += red[tid + s];
        __syncthreads();
    }
    float r = red[0]; __syncthreads();
    return r;
}
__device__ __forceinline__ float wave_sum(float v) {
    #pragma unroll
    for (int off = 1; off < 64; off <<= 1) v += __shfl_xor(v, off, 64);
    return v;
}
__device__ __forceinline__ f32x4 mfma16(bf16x8 a, bf16x8 b, f32x4 c) {
    return __builtin_amdgcn_mfma_f32_16x16x32_bf16(a, b, c, 0, 0, 0);
}

// ---------------- weight transpose + bf16: Wt[n][k] = bf16(W[k][n]) ----------------
__global__ __launch_bounds__(256)
void wt_kernel(const float* __restrict__ W0, const float* __restrict__ W1,
               const float* __restrict__ W2, const float* __restrict__ W3,
               const float* __restrict__ W4, u16* __restrict__ dst)
{
    __shared__ float tile[32][33];
    const int z = blockIdx.z;
    const float* W = (z == 0) ? W0 : (z == 1) ? W1 : (z == 2) ? W2 : (z == 3) ? W3 : W4;
    u16* o = dst + (size_t)z * EMB * EMB;
    const int bi = blockIdx.y, bj = blockIdx.x;
    const int r = threadIdx.x >> 5, c = threadIdx.x & 31;
    #pragma unroll
    for (int i = 0; i < 4; i++)
        tile[r + i * 8][c] = W[(long)(bi * 32 + r + i * 8) * EMB + bj * 32 + c];
    __syncthreads();
    #pragma unroll
    for (int i = 0; i < 4; i++) {
        const int rr = r + i * 8;
        o[(long)(bj * 32 + rr) * EMB + bi * 32 + c] = f2bf(tile[c][rr]);
    }
}

// ---------------- fill cls + text rows of t (bf16) ----------------
__global__ __launch_bounds__(256)
void fill_rows_kernel(const float* __restrict__ cls, const float* __restrict__ text,
                      u16* __restrict__ t)
{
    const int b = blockIdx.y, r = blockIdx.x;
    const int tid = threadIdx.x;
    const long trow = (long)b * NTOK + (r == 0 ? 0 : NPATCH + r);
    const float* src = (r == 0) ? cls : text + ((long)b * NTEXT + (r - 1)) * EMB;
    u16* dst = t + trow * EMB;
    #pragma unroll
    for (int s = 0; s < 3; s++) dst[tid + s * 256] = f2bf(src[tid + s * 256]);
}

// ---------------- im2col v2: coalesced uint4 writes ----------------
__global__ __launch_bounds__(384)
void im2col_kernel(const float* __restrict__ x, u16* __restrict__ patches)
{
    const int row = blockIdx.x * 4 + threadIdx.x / 96;   // 0..18431
    const int j = threadIdx.x % 96;
    const int bb = row / NPATCH, rem = row % NPATCH;
    const int hh = rem / 24, ww = rem % 24;
    union { u16 s[8]; uint4 v; } out;
    #pragma unroll
    for (int e = 0; e < 8; e++) {
        const int col = j * 8 + e;
        const int p1 = col / 48, r2 = col % 48, p2 = r2 / 3, c = r2 % 3;
        out.s[e] = f2bf(x[((long)(bb * 3 + c) * 384 + hh * 16 + p1) * 384 + ww * 16 + p2]);
    }
    *(uint4*)(patches + (long)row * EMB + j * 8) = out.v;
}

// ---------------- LN1 wave-per-row: t(bf16) -> h(bf16), no barriers ----------------
__global__ __launch_bounds__(256)
void ln_h_kernel(const u16* __restrict__ t, u16* __restrict__ h,
                 const float* __restrict__ g, const float* __restrict__ be)
{
    const int row = blockIdx.x * 4 + (threadIdx.x >> 6);
    const int lane = threadIdx.x & 63;
    const u16* xp = t + (long)row * EMB;
    float v[12];
    #pragma unroll
    for (int s = 0; s < 3; s++) {
        const uint2 u = *(const uint2*)(xp + lane * 4 + s * 256);
        const u16* e = (const u16*)&u;
        #pragma unroll
        for (int jj = 0; jj < 4; jj++) v[s * 4 + jj] = bf2f(e[jj]);
    }
    float sum = 0.f;
    #pragma unroll
    for (int i = 0; i < 12; i++) sum += v[i];
    const float mu = wave_sum(sum) * (1.f / EMB);
    float vs = 0.f;
    #pragma unroll
    for (int i = 0; i < 12; i++) { v[i] -= mu; vs += v[i] * v[i]; }
    const float rs = rsqrtf(wave_sum(vs) * (1.f / EMB) + LN_EPS);
    u16* o = h + (long)row * EMB;
    #pragma unroll
    for (int s = 0; s < 3; s++) {
        const int col = lane * 4 + s * 256;
        const float4 gv = *(const float4*)(g + col);
        const float4 bv = *(const float4*)(be + col);
        uint2 w;
        w.x = pk2(v[s * 4 + 0] * rs * gv.x + bv.x, v[s * 4 + 1] * rs * gv.y + bv.y);
        w.y = pk2(v[s * 4 + 2] * rs * gv.z + bv.z, v[s * 4 + 3] * rs * gv.w + bv.w);
        *(uint2*)(o + col) = w;
    }
}

// ---------------- dense MFMA GEMM v3: GLL dbuf + counted vmcnt + RAW barriers --------
#define DBK 64
#define DTILE_B (128 * DBK * 2)   // 16384 B per operand tile

template<bool OBF16, bool REMAP>
__global__ __launch_bounds__(256)
void dense_gemm(const u16* __restrict__ A, const u16* __restrict__ Bt,
                const float* __restrict__ b0, const float* __restrict__ b1,
                const float* __restrict__ b2,
                void* __restrict__ C0, void* __restrict__ C1, void* __restrict__ C2,
                int M, int nb)
{
    extern __shared__ char sm[];   // [2][A|B][128][64]u16 = 65536 B
    const int cpx = gridDim.x >> 3;
    const int wg = blockIdx.x;
    const int work = (wg & 7) * cpx + (wg >> 3);
    const int cb = work % nb;
    const int m0 = (work / nb) * 128;
    const int z  = cb / 6;
    const int n0 = (cb % 6) * 128;
    const u16* Btz = Bt + (size_t)z * EMB * EMB;
    const float* bias = (z == 0) ? b0 : (z == 1) ? b1 : b2;
    void* Cz = (z == 0) ? C0 : (z == 1) ? C1 : C2;

    const int tid = threadIdx.x;
    const int lane = tid & 63, w = tid >> 6, wr = w >> 1, wc = w & 1;
    const int l15 = lane & 15, g = lane >> 4;
    const int wbase = (tid & ~63);

    f32x4 acc[4][4] = {};

    auto stage = [&](int k0, int buf) {
        char* dst = sm + buf * 2 * DTILE_B;
        #pragma unroll
        for (int c = 0; c < 4; c++) {
            const int idx = c * 256 + tid;
            const int r = idx >> 3, s = idx & 7;
            const int gs = s ^ (r & 7);
            const int ar = min(m0 + r, M - 1);
            GLL(A + (long)ar * EMB + k0 + gs * 8, dst + (c * 256 + wbase) * 16);
        }
        #pragma unroll
        for (int c = 0; c < 4; c++) {
            const int idx = c * 256 + tid;
            const int r = idx >> 3, s = idx & 7;
            const int gs = s ^ (r & 7);
            GLL(Btz + (long)(n0 + r) * EMB + k0 + gs * 8,
                dst + DTILE_B + (c * 256 + wbase) * 16);
        }
    };

    stage(0, 0);
    for (int t = 0; t < 12; t++) {
        if (t < 11) {
            stage((t + 1) * DBK, (t + 1) & 1);
            asm volatile("s_waitcnt vmcnt(8)" ::: "memory");   // tile t landed; t+1 in flight
        } else {
            asm volatile("s_waitcnt vmcnt(0)" ::: "memory");
        }
        __builtin_amdgcn_s_barrier();          // all waves' tile-t loads landed
        __builtin_amdgcn_sched_barrier(0);
        const char* Asb = sm + (t & 1) * 2 * DTILE_B;
        const char* Bsb = Asb + DTILE_B;
        #pragma unroll
        for (int ks = 0; ks < 2; ks++) {
            BF8 af[4], bfr[4];
            #pragma unroll
            for (int mi = 0; mi < 4; mi++) {
                const int row = wr * 64 + mi * 16 + l15;
                const int slot = (ks * 4 + g) ^ (row & 7);
                af[mi].u4 = *(const uint4*)(Asb + row * 128 + slot * 16);
            }
            #pragma unroll
            for (int nj = 0; nj < 4; nj++) {
                const int row = wc * 64 + nj * 16 + l15;
                const int slot = (ks * 4 + g) ^ (row & 7);
                bfr[nj].u4 = *(const uint4*)(Bsb + row * 128 + slot * 16);
            }
            __builtin_amdgcn_s_setprio(1);
            #pragma unroll
            for (int mi = 0; mi < 4; mi++)
                #pragma unroll
                for (int nj = 0; nj < 4; nj++)
                    acc[mi][nj] = mfma16(af[mi].v, bfr[nj].v, acc[mi][nj]);
            __builtin_amdgcn_s_setprio(0);
        }
        __builtin_amdgcn_s_barrier();          // all waves done reading buf t&1
        __builtin_amdgcn_sched_barrier(0);
    }

    float bv[4];
    #pragma unroll
    for (int nj = 0; nj < 4; nj++) bv[nj] = bias[n0 + wc * 64 + nj * 16 + l15];
    #pragma unroll
    for (int mi = 0; mi < 4; mi++) {
        #pragma unroll
        for (int rr = 0; rr < 4; rr++) {
            const int r = m0 + wr * 64 + mi * 16 + 4 * g + rr;
            if (r >= M) continue;
            long orow = r;
            if (REMAP) orow = (long)(r / NPATCH) * NTOK + 1 + (r % NPATCH);
            #pragma unroll
            for (int nj = 0; nj < 4; nj++) {
                const int cc = n0 + wc * 64 + nj * 16 + l15;
                const float val = acc[mi][nj][rr] + bv[nj];
                if (OBF16) ((u16*)Cz)[orow * EMB + cc] = f2bf(val);
                else       ((float*)Cz)[orow * EMB + cc] = val;
            }
        }
    }
}

// ---------------- flash attention v12: 6 waves, 448 blocks (tail fix), defer-max -----
// 384 thr = 6 waves, each wave 16 q-rows (96 q/block); 7 qblocks/bh -> 448 blocks.
// Schedule = r9 (proven): top sync (drain), writeV, mid sync, prefetch K(t+1)+V(t+1),
// compute. LDS 84480 -> 1 block/CU; 448 blocks = ~2 rounds of 0.75x block time
// (vs r15: 384 blocks x 8 waves = 2 rounds of 1.0x, half-idle second round).
#define KS_TILE_B 24576   // 32*384*2
#define VTLD 36           // Vt row stride (u16), 72 B (conflict-free; 40 regressed r10)
#define PSLD 40           // Ps row stride (u16)
#define FL_WAVES 6
#define FLASH_LDS (2 * KS_TILE_B + 384 * VTLD * 2 + FL_WAVES * 16 * PSLD * 2)  // 84480

__global__ __launch_bounds__(384)
void flash_mfma(const u16* __restrict__ q, const u16* __restrict__ k,
                const u16* __restrict__ v, u16* __restrict__ o)
{
    extern __shared__ char smem[];
    char* KsB = smem;                                   // [2][32][384] u16 (swizzled)
    u16* Vt = (u16*)(smem + 2 * KS_TILE_B);             // [384][VTLD]
    char* Ps = smem + 2 * KS_TILE_B + 384 * VTLD * 2;   // 6 waves x [16][PSLD]

    // XCD-bijective: 448 = 8 * 56; 7 consecutive works share one (b,h)
    const int wg = blockIdx.x;
    const int work = (wg & 7) * 56 + (wg >> 3);
    const int bh = work / 7, qblk = work % 7;
    const int b = bh >> 1, h = bh & 1;
    const int q0 = qblk * 96;
    const int tid = threadIdx.x;
    const int lane = tid & 63, w = tid >> 6;
    const int l15 = lane & 15, g = lane >> 4;
    const int wbase = (tid & ~63);
    const long base = (long)b * NTOK * EMB + h * HD;

    BF8 qf[12];
    {
        const int qrow = q0 + w * 16 + l15;
        if (qrow < NTOK) {
            const u16* src = q + base + (long)qrow * EMB;
            #pragma unroll
            for (int ds = 0; ds < 12; ds++)
                qf[ds].u4 = *(const uint4*)(src + ds * 32 + g * 8);
        } else {
            #pragma unroll
            for (int ds = 0; ds < 12; ds++) qf[ds].u4 = make_uint4(0, 0, 0, 0);
        }
    }

    // K async stage via GLL: 1536 granules = 4 per thread (384 thr)
    auto stage_K = [&](int kv0, int buf) {
        #pragma unroll
        for (int c = 0; c < 4; c++) {
            const int idx = c * 384 + tid;
            const int r = idx / 48, gr = idx % 48;
            const int gsrc = (gr & ~7) | ((gr & 7) ^ (r & 7));
            const int kr = min(kv0 + r, NTOK - 1);
            GLL(k + base + (long)kr * EMB + gsrc * 8,
                KsB + buf * KS_TILE_B + (c * 384 + wbase) * 16);
        }
    };

    // V reg staging: 768 (kp,dseg) tasks = 2 per thread
    const int kp = tid & 15;
    const int dsegA = tid >> 4;          // 0..23
    const int dsegB = 24 + (tid >> 4);   // 24..47
    uint4 vaA, vbA, vaB, vbB;
    auto loadV = [&](int kv0) {
        const int kr0 = kv0 + 2 * kp;
        const u16* v0p = v + base + (long)min(kr0, NTOK - 1) * EMB;
        const u16* v1p = v + base + (long)min(kr0 + 1, NTOK - 1) * EMB;
        vaA = *(const uint4*)(v0p + dsegA * 8);
        vbA = *(const uint4*)(v1p + dsegA * 8);
        vaB = *(const uint4*)(v0p + dsegB * 8);
        vbB = *(const uint4*)(v1p + dsegB * 8);
    };
    auto writeV = [&](int kv0) {
        const int kr0 = kv0 + 2 * kp;
        const bool ok0 = kr0 < NTOK, ok1 = (kr0 + 1) < NTOK;
        {
            const u16* ae = (const u16*)&vaA;
            const u16* be = (const u16*)&vbA;
            #pragma unroll
            for (int e = 0; e < 8; e++) {
                const u32 lo = ok0 ? (u32)ae[e] : 0u;
                const u32 hi = ok1 ? (u32)be[e] : 0u;
                *(u32*)&Vt[(dsegA * 8 + e) * VTLD + 2 * kp] = lo | (hi << 16);
            }
        }
        {
            const u16* ae = (const u16*)&vaB;
            const u16* be = (const u16*)&vbB;
            #pragma unroll
            for (int e = 0; e < 8; e++) {
                const u32 lo = ok0 ? (u32)ae[e] : 0u;
                const u32 hi = ok1 ? (u32)be[e] : 0u;
                *(u32*)&Vt[(dsegB * 8 + e) * VTLD + 2 * kp] = lo | (hi << 16);
            }
        }
    };

    float m_run = -3.0e38f, l_run = 0.f;
    f32x4 oacc[24] = {};

    stage_K(0, 0);
    loadV(0);

    for (int kt = 0; kt < 21; kt++) {
        const int kv0 = kt * 32;
        __syncthreads();   // implicit vmcnt(0): K(kt) in LDS, V(kt) in regs; WAR for Vt
        writeV(kv0);
        __syncthreads();   // Vt(kt)+K(kt) visible; nothing in flight -> free drain
        if (kt < 20) {
            stage_K(kv0 + 32, (kt + 1) & 1);   // async across compute(kt)
            loadV(kv0 + 32);
        }

        const char* kbuf = KsB + (kt & 1) * KS_TILE_B;
        f32x4 sacc[2] = {};
        #pragma unroll
        for (int ds = 0; ds < 12; ds++) {
            const int idx = ds * 4 + g;
            const int slot = (idx & ~7) | ((idx & 7) ^ (l15 & 7));
            BF8 ak0, ak1;
            ak0.u4 = *(const uint4*)(kbuf + l15 * 768 + slot * 16);
            ak1.u4 = *(const uint4*)(kbuf + (16 + l15) * 768 + slot * 16);
            sacc[0] = mfma16(ak0.v, qf[ds].v, sacc[0]);
            sacc[1] = mfma16(ak1.v, qf[ds].v, sacc[1]);
        }

        // ---- mask + online softmax with defer-max (T13, THR=8) ----
        float pe[2][4];
        float mx = -3.0e38f;
        #pragma unroll
        for (int kb = 0; kb < 2; kb++)
            #pragma unroll
            for (int rr = 0; rr < 4; rr++) {
                float s = sacc[kb][rr];
                if (kv0 + kb * 16 + 4 * g + rr >= NTOK) s = -1e30f;
                pe[kb][rr] = s;
                mx = fmaxf(mx, s);
            }
        mx = fmaxf(mx, __shfl_xor(mx, 16, 64));
        mx = fmaxf(mx, __shfl_xor(mx, 32, 64));
        const bool nores = (bool)__all(mx - m_run <= 8.f);
        float m_new = m_run, corr = 1.f;
        if (!nores) {
            m_new = fmaxf(m_run, mx);
            corr = __expf(m_run - m_new);
        }
        float psum = 0.f;
        #pragma unroll
        for (int kb = 0; kb < 2; kb++)
            #pragma unroll
            for (int rr = 0; rr < 4; rr++) {
                pe[kb][rr] = __expf(pe[kb][rr] - m_new);
                psum += pe[kb][rr];
            }
        psum += __shfl_xor(psum, 16, 64);
        psum += __shfl_xor(psum, 32, 64);
        l_run = (nores ? l_run : l_run * corr) + psum;
        m_run = m_new;

        {
            u32* pw = (u32*)(Ps + w * (16 * PSLD * 2) + l15 * (PSLD * 2));
            pw[g * 2]         = pk2(pe[0][0], pe[0][1]);
            pw[g * 2 + 1]     = pk2(pe[0][2], pe[0][3]);
            pw[8 + g * 2]     = pk2(pe[1][0], pe[1][1]);
            pw[8 + g * 2 + 1] = pk2(pe[1][2], pe[1][3]);
        }
        asm volatile("s_waitcnt lgkmcnt(0)" ::: "memory");
        __builtin_amdgcn_sched_barrier(0);
        BF8 pa;
        pa.u4 = *(const uint4*)(Ps + w * (16 * PSLD * 2) + l15 * (PSLD * 2) + g * 16);

        if (!nores) {
            float cb4[4];
            #pragma unroll
            for (int rr = 0; rr < 4; rr++) cb4[rr] = __shfl(corr, 4 * g + rr, 64);
            #pragma unroll
            for (int dc = 0; dc < 24; dc++)
                #pragma unroll
                for (int rr = 0; rr < 4; rr++) oacc[dc][rr] *= cb4[rr];
        }

        #pragma unroll
        for (int dc = 0; dc < 24; dc++) {
            const u16* vp = &Vt[(dc * 16 + l15) * VTLD + g * 8];
            const uint2 lo = *(const uint2*)vp;
            const uint2 hi = *(const uint2*)(vp + 4);
            BF8 vb8;
            vb8.w[0] = lo.x; vb8.w[1] = lo.y; vb8.w[2] = hi.x; vb8.w[3] = hi.y;
            oacc[dc] = mfma16(pa.v, vb8.v, oacc[dc]);
        }
    }

    float linv[4];
    #pragma unroll
    for (int rr = 0; rr < 4; rr++)
        linv[rr] = INV_SQRT_EMB / __shfl(l_run, 4 * g + rr, 64);
    #pragma unroll
    for (int rr = 0; rr < 4; rr++) {
        const int row = q0 + w * 16 + 4 * g + rr;
        if (row < NTOK) {
            u16* dst = o + base + (long)row * EMB;
            #pragma unroll
            for (int dc = 0; dc < 24; dc++)
                dst[dc * 16 + l15] = f2bf(oacc[dc][rr] * linv[rr]);
        }
    }
}

// ---------------- LN2 wave-per-row (bf16 in) + residual-add into t ----------------
__global__ __launch_bounds__(256)
void ln_add_kernel(const u16* __restrict__ in, u16* __restrict__ t,
                   const float* __restrict__ g, const float* __restrict__ be)
{
    const int row = blockIdx.x * 4 + (threadIdx.x >> 6);
    const int lane = threadIdx.x & 63;
    const u16* xp = in + (long)row * EMB;
    float v[12];
    #pragma unroll
    for (int s = 0; s < 3; s++) {
        const uint2 u = *(const uint2*)(xp + lane * 4 + s * 256);
        const u16* e = (const u16*)&u;
        #pragma unroll
        for (int jj = 0; jj < 4; jj++) v[s * 4 + jj] = bf2f(e[jj]);
    }
    float sum = 0.f;
    #pragma unroll
    for (int i = 0; i < 12; i++) sum += v[i];
    const float mu = wave_sum(sum) * (1.f / EMB);
    float vs = 0.f;
    #pragma unroll
    for (int i = 0; i < 12; i++) { v[i] -= mu; vs += v[i] * v[i]; }
    const float rs = rsqrtf(wave_sum(vs) * (1.f / EMB) + LN_EPS);
    u16* o = t + (long)row * EMB;
    #pragma unroll
    for (int s = 0; s < 3; s++) {
        const int col = lane * 4 + s * 256;
        const float4 gv = *(const float4*)(g + col);
        const float4 bv = *(const float4*)(be + col);
        const uint2 told = *(const uint2*)(o + col);
        const u16* te = (const u16*)&told;
        uint2 w;
        w.x = pk2(bf2f(te[0]) + v[s * 4 + 0] * rs * gv.x + bv.x,
                  bf2f(te[1]) + v[s * 4 + 1] * rs * gv.y + bv.y);
        w.y = pk2(bf2f(te[2]) + v[s * 4 + 2] * rs * gv.z + bv.z,
                  bf2f(te[3]) + v[s * 4 + 3] * rs * gv.w + bv.w);
        *(uint2*)(o + col) = w;
    }
}

// ---------------- mean over tokens v2: 8 token-groups x 32 cols ----------------
__global__ __launch_bounds__(256)
void meanpool_kernel(const u16* __restrict__ t, float* __restrict__ m)
{
    __shared__ float red[8][32];
    const int b = blockIdx.y, e0 = blockIdx.x * 32;
    const int tg = threadIdx.x >> 5, col = threadIdx.x & 31;
    const u16* p = t + (long)b * NTOK * EMB + e0 + col;
    float s = 0.f;
    for (int j = tg; j < NTOK; j += 8) s += bf2f(p[(long)j * EMB]);
    red[tg][col] = s;
    __syncthreads();
    if (tg == 0) {
        float a = s;
        #pragma unroll
        for (int i = 1; i < 8; i++) a += red[i][col];
        m[(long)b * EMB + e0 + col] = a * (1.f / NTOK);
    }
}

// ---------------- LN3: m[32][768] -> mln fp32 ----------------
__global__ __launch_bounds__(256)
void ln3_kernel(const float* __restrict__ m, const float* __restrict__ g,
                const float* __restrict__ be, float* __restrict__ mln)
{
    __shared__ float red[256];
    const int b = blockIdx.x, tid = threadIdx.x;
    const float* x = m + b * EMB;
    const float v0 = x[tid], v1 = x[tid + 256], v2 = x[tid + 512];
    const float mu = blk_sum(v0 + v1 + v2, red, tid) * (1.f / EMB);
    const float d0 = v0 - mu, d1 = v1 - mu, d2 = v2 - mu;
    const float var = blk_sum(d0 * d0 + d1 * d1 + d2 * d2, red, tid) * (1.f / EMB);
    const float rs = rsqrtf(var + LN_EPS);
    float* o = mln + (long)b * EMB;
    o[tid]       = d0 * rs * g[tid]       + be[tid];
    o[tid + 256] = d1 * rs * g[tid + 256] + be[tid + 256];
    o[tid + 512] = d2 * rs * g[tid + 512] + be[tid + 512];
}

// ---------------- final GEMM: out[32][768] = mln @ Wf + bf, 768 blocks ----------------
__global__ __launch_bounds__(256)
void final_gemm(const float* __restrict__ mln, const float* __restrict__ Wf,
                const float* __restrict__ bfv, float* __restrict__ out)
{
    __shared__ float sml[EMB];
    __shared__ float red[8][32];
    const int b = blockIdx.y, e0 = blockIdx.x * 32;
    const int tid = threadIdx.x;
    for (int i = tid; i < EMB; i += 256) sml[i] = mln[(long)b * EMB + i];
    __syncthreads();
    const int kg = tid >> 5, col = tid & 31, e = e0 + col;
    float acc = 0.f;
    const float* wp = Wf + (long)(kg * 96) * EMB + e;
    const float* mp = sml + kg * 96;
    #pragma unroll 8
    for (int kk = 0; kk < 96; kk++) acc += mp[kk] * wp[(long)kk * EMB];
    red[kg][col] = acc;
    __syncthreads();
    if (kg == 0) {
        float s = bfv[e];
        #pragma unroll
        for (int i = 0; i < 8; i++) s += red[i][col];
        out[(long)b * EMB + e] = s;
    }
}

extern "C" void kernel_launch(void* const* d_in, const int* in_sizes, int n_in,
                              void* d_out, int out_size, void* d_ws, size_t ws_size,
                              hipStream_t stream) {
    const float* x      = (const float*)d_in[0];
    const float* text   = (const float*)d_in[1];
    const float* Wpatch = (const float*)d_in[2];
    const float* bpatch = (const float*)d_in[3];
    const float* cls    = (const float*)d_in[4];
    const float* g1  = (const float*)d_in[5];
    const float* be1 = (const float*)d_in[6];
    const float* Wq  = (const float*)d_in[7];
    const float* bq  = (const float*)d_in[8];
    const float* Wk  = (const float*)d_in[9];
    const float* bk  = (const float*)d_in[10];
    const float* Wv  = (const float*)d_in[11];
    const float* bv  = (const float*)d_in[12];
    const float* Wp  = (const float*)d_in[13];
    const float* bp  = (const float*)d_in[14];
    const float* g2  = (const float*)d_in[15];
    const float* be2 = (const float*)d_in[16];
    const float* g3  = (const float*)d_in[17];
    const float* be3 = (const float*)d_in[18];
    const float* Wf  = (const float*)d_in[19];
    const float* bf  = (const float*)d_in[20];

    // ws layout (~167 MB): t | h | q | k | v (bf16, 5 x 32.1 MB)
    //  pat aliases qb (dead until QKV); o2 (bf16) aliases kbf (dead post-flash)
    //  Wt bf16 (5 x 1.18 MB) | mp fp32 | mln fp32
    char* ws = (char*)d_ws;
    const size_t S2 = (size_t)MROWS * EMB * 2;   // 32,145,408
    u16*   t    = (u16*)ws;
    u16*   hb   = (u16*)(ws + S2);
    u16*   qb   = (u16*)(ws + 2 * S2);
    u16*   kbf  = (u16*)(ws + 3 * S2);
    u16*   vbf  = (u16*)(ws + 4 * S2);
    u16*   o2b  = kbf;   // after flash, k is dead
    u16*   wt   = (u16*)(ws + 5 * S2);
    float* mp   = (float*)(ws + 5 * S2 + (size_t)5 * EMB * EMB * 2);
    float* mln  = mp + (size_t)NBATCH * EMB;
    u16*   pat  = qb;    // im2col output aliases q
    const size_t WTS = (size_t)EMB * EMB;
    const int DLDS = 2 * 2 * DTILE_B;   // 65536

    // 1) weights -> bf16 transposed
    wt_kernel<<<dim3(24, 24, 5), 256, 0, stream>>>(Wpatch, Wq, Wk, Wv, Wp, wt);
    // 2) cls + text rows of t
    fill_rows_kernel<<<dim3(NTEXT + 1, NBATCH), 256, 0, stream>>>(cls, text, t);
    // 3) im2col v2 -> patches (aliases q), coalesced writes
    im2col_kernel<<<4608, 384, 0, stream>>>(x, pat);
    // 4) patch embed: dense GEMM with row remap -> t   (864 = 8*108 blocks)
    dense_gemm<true, true><<<864, 256, DLDS, stream>>>(
        pat, wt, bpatch, bpatch, bpatch, t, t, t, NBATCH * NPATCH, 6);
    // 5) h = LN1(t), wave-per-row
    ln_h_kernel<<<MROWS / 4, 256, 0, stream>>>(t, hb, g1, be1);
    // 6) fused QKV: nb=18, z selects Wq/Wk/Wv  (2952 = 8*369 blocks)
    dense_gemm<true, false><<<2952, 256, DLDS, stream>>>(
        hb, wt + WTS, bq, bk, bv, qb, kbf, vbf, MROWS, 18);
    // 7) flash attention v12 (o over q), 448 = 8*56 blocks, 384 thr
    flash_mfma<<<448, 384, FLASH_LDS, stream>>>(qb, kbf, vbf, qb);
    // 8) proj -> o2 bf16 (aliases kbf)   (984 = 8*123 blocks)
    dense_gemm<true, false><<<984, 256, DLDS, stream>>>(
        qb, wt + 4 * WTS, bp, bp, bp, o2b, o2b, o2b, MROWS, 6);
    // 9) t += LN2(o2), wave-per-row
    ln_add_kernel<<<MROWS / 4, 256, 0, stream>>>(o2b, t, g2, be2);
    // 10) mean pool v2
    meanpool_kernel<<<dim3(24, NBATCH), 256, 0, stream>>>(t, mp);
    // 11) LN3 -> mln
    ln3_kernel<<<NBATCH, 256, 0, stream>>>(mp, g3, be3, mln);
    // 12) final GEMM, 768 blocks
    final_gemm<<<dim3(24, NBATCH), 256, 0, stream>>>(mln, Wf, bf, (float*)d_out);
}

// Round 17
// 349.016 us; speedup vs baseline: 1.8854x; 1.0226x over previous
//
#include <hip/hip_runtime.h>
#include <hip/hip_bf16.h>
#include <math.h>

#define EMB 768
#define NTOK 654
#define NPATCH 576
#define NTEXT 77
#define NBATCH 32
#define HD 384
#define MROWS (NBATCH * NTOK)   // 20928
#define LN_EPS 1e-5f
#define INV_SQRT_EMB 0.03608439182435161f

typedef unsigned int u32;
typedef unsigned short u16;
typedef float f32x4 __attribute__((ext_vector_type(4)));
typedef __bf16 bf16x8 __attribute__((ext_vector_type(8)));

union BF8 { uint4 u4; u32 w[4]; bf16x8 v; };

// async global->LDS, 16B per lane; dest = wave-uniform base + lane*16
#define GLL(gsrc, ldst) __builtin_amdgcn_global_load_lds( \
    (const __attribute__((address_space(1))) unsigned int*)(gsrc), \
    (__attribute__((address_space(3))) unsigned int*)(ldst), 16, 0, 0)

// ---------------- helpers ----------------
__device__ __forceinline__ float bf2f(u16 u) {
    union { u32 i; float f; } x; x.i = ((u32)u) << 16; return x.f;
}
__device__ __forceinline__ u16 f2bf(float f) {  // RTNE
    union { float f; u32 i; } x; x.f = f;
    u32 r = x.i + 0x7fffu + ((x.i >> 16) & 1u);
    return (u16)(r >> 16);
}
__device__ __forceinline__ u32 pk2(float lo, float hi) {
    return (u32)f2bf(lo) | ((u32)f2bf(hi) << 16);
}
__device__ __forceinline__ float blk_sum(float v, float* red, int tid) {
    red[tid] = v; __syncthreads();
    #pragma unroll
    for (int s = 128; s > 0; s >>= 1) {
        if (tid < s) red[tid] += red[tid + s];
        __syncthreads();
    }
    float r = red[0]; __syncthreads();
    return r;
}
__device__ __forceinline__ float wave_sum(float v) {
    #pragma unroll
    for (int off = 1; off < 64; off <<= 1) v += __shfl_xor(v, off, 64);
    return v;
}
__device__ __forceinline__ f32x4 mfma16(bf16x8 a, bf16x8 b, f32x4 c) {
    return __builtin_amdgcn_mfma_f32_16x16x32_bf16(a, b, c, 0, 0, 0);
}

// ---------------- prep kernel: wt transpose | cls+text fill | im2col ----------------
// blocks [0,2880): Wt[n][k]=bf16(W[k][n]) 32x32 tiles (5 weights x 576 tiles)
// blocks [2880,5376): cls+text rows of t (78 rows x 32 batches)
// blocks [5376,7680): im2col, 8 patch-rows per block, coalesced uint4 writes
__global__ __launch_bounds__(256)
void prep_kernel(const float* __restrict__ W0, const float* __restrict__ W1,
                 const float* __restrict__ W2, const float* __restrict__ W3,
                 const float* __restrict__ W4, u16* __restrict__ wt,
                 const float* __restrict__ cls, const float* __restrict__ text,
                 u16* __restrict__ t,
                 const float* __restrict__ x, u16* __restrict__ patches)
{
    const int id = blockIdx.x;
    const int tid = threadIdx.x;
    if (id < 2880) {
        __shared__ float tile[32][33];
        const int z = id / 576, rem = id % 576;
        const int bi = rem / 24, bj = rem % 24;
        const float* W = (z == 0) ? W0 : (z == 1) ? W1 : (z == 2) ? W2 : (z == 3) ? W3 : W4;
        u16* o = wt + (size_t)z * EMB * EMB;
        const int r = tid >> 5, c = tid & 31;
        #pragma unroll
        for (int i = 0; i < 4; i++)
            tile[r + i * 8][c] = W[(long)(bi * 32 + r + i * 8) * EMB + bj * 32 + c];
        __syncthreads();
        #pragma unroll
        for (int i = 0; i < 4; i++) {
            const int rr = r + i * 8;
            o[(long)(bj * 32 + rr) * EMB + bi * 32 + c] = f2bf(tile[c][rr]);
        }
    } else if (id < 5376) {
        const int id2 = id - 2880;
        const int b = id2 / 78, r = id2 % 78;
        const long trow = (long)b * NTOK + (r == 0 ? 0 : NPATCH + r);
        const float* src = (r == 0) ? cls : text + ((long)b * NTEXT + (r - 1)) * EMB;
        u16* dst = t + trow * EMB;
        #pragma unroll
        for (int s = 0; s < 3; s++) dst[tid + s * 256] = f2bf(src[tid + s * 256]);
    } else {
        const int id3 = id - 5376;
        #pragma unroll
        for (int cc = 0; cc < 3; cc++) {
            const int task = tid + cc * 256;           // 768 tasks = 8 rows x 96 j
            const int row = id3 * 8 + task / 96;
            const int j = task % 96;
            const int bb = row / NPATCH, rem = row % NPATCH;
            const int hh = rem / 24, ww = rem % 24;
            union { u16 s[8]; uint4 v; } out;
            #pragma unroll
            for (int e = 0; e < 8; e++) {
                const int col = j * 8 + e;
                const int p1 = col / 48, r2 = col % 48, p2 = r2 / 3, c = r2 % 3;
                out.s[e] = f2bf(x[((long)(bb * 3 + c) * 384 + hh * 16 + p1) * 384 + ww * 16 + p2]);
            }
            *(uint4*)(patches + (long)row * EMB + j * 8) = out.v;
        }
    }
}

// ---------------- LN1 wave-per-row: t(bf16) -> h(bf16), no barriers ----------------
__global__ __launch_bounds__(256)
void ln_h_kernel(const u16* __restrict__ t, u16* __restrict__ h,
                 const float* __restrict__ g, const float* __restrict__ be)
{
    const int row = blockIdx.x * 4 + (threadIdx.x >> 6);
    const int lane = threadIdx.x & 63;
    const u16* xp = t + (long)row * EMB;
    float v[12];
    #pragma unroll
    for (int s = 0; s < 3; s++) {
        const uint2 u = *(const uint2*)(xp + lane * 4 + s * 256);
        const u16* e = (const u16*)&u;
        #pragma unroll
        for (int jj = 0; jj < 4; jj++) v[s * 4 + jj] = bf2f(e[jj]);
    }
    float sum = 0.f;
    #pragma unroll
    for (int i = 0; i < 12; i++) sum += v[i];
    const float mu = wave_sum(sum) * (1.f / EMB);
    float vs = 0.f;
    #pragma unroll
    for (int i = 0; i < 12; i++) { v[i] -= mu; vs += v[i] * v[i]; }
    const float rs = rsqrtf(wave_sum(vs) * (1.f / EMB) + LN_EPS);
    u16* o = h + (long)row * EMB;
    #pragma unroll
    for (int s = 0; s < 3; s++) {
        const int col = lane * 4 + s * 256;
        const float4 gv = *(const float4*)(g + col);
        const float4 bv = *(const float4*)(be + col);
        uint2 w;
        w.x = pk2(v[s * 4 + 0] * rs * gv.x + bv.x, v[s * 4 + 1] * rs * gv.y + bv.y);
        w.y = pk2(v[s * 4 + 2] * rs * gv.z + bv.z, v[s * 4 + 3] * rs * gv.w + bv.w);
        *(uint2*)(o + col) = w;
    }
}

// ---------------- dense MFMA GEMM v3: GLL dbuf + counted vmcnt + RAW barriers --------
#define DBK 64
#define DTILE_B (128 * DBK * 2)   // 16384 B per operand tile

template<bool OBF16, bool REMAP>
__global__ __launch_bounds__(256)
void dense_gemm(const u16* __restrict__ A, const u16* __restrict__ Bt,
                const float* __restrict__ b0, const float* __restrict__ b1,
                const float* __restrict__ b2,
                void* __restrict__ C0, void* __restrict__ C1, void* __restrict__ C2,
                int M, int nb)
{
    extern __shared__ char sm[];   // [2][A|B][128][64]u16 = 65536 B
    const int cpx = gridDim.x >> 3;
    const int wg = blockIdx.x;
    const int work = (wg & 7) * cpx + (wg >> 3);
    const int cb = work % nb;
    const int m0 = (work / nb) * 128;
    const int z  = cb / 6;
    const int n0 = (cb % 6) * 128;
    const u16* Btz = Bt + (size_t)z * EMB * EMB;
    const float* bias = (z == 0) ? b0 : (z == 1) ? b1 : b2;
    void* Cz = (z == 0) ? C0 : (z == 1) ? C1 : C2;

    const int tid = threadIdx.x;
    const int lane = tid & 63, w = tid >> 6, wr = w >> 1, wc = w & 1;
    const int l15 = lane & 15, g = lane >> 4;
    const int wbase = (tid & ~63);

    f32x4 acc[4][4] = {};

    auto stage = [&](int k0, int buf) {
        char* dst = sm + buf * 2 * DTILE_B;
        #pragma unroll
        for (int c = 0; c < 4; c++) {
            const int idx = c * 256 + tid;
            const int r = idx >> 3, s = idx & 7;
            const int gs = s ^ (r & 7);
            const int ar = min(m0 + r, M - 1);
            GLL(A + (long)ar * EMB + k0 + gs * 8, dst + (c * 256 + wbase) * 16);
        }
        #pragma unroll
        for (int c = 0; c < 4; c++) {
            const int idx = c * 256 + tid;
            const int r = idx >> 3, s = idx & 7;
            const int gs = s ^ (r & 7);
            GLL(Btz + (long)(n0 + r) * EMB + k0 + gs * 8,
                dst + DTILE_B + (c * 256 + wbase) * 16);
        }
    };

    stage(0, 0);
    for (int t = 0; t < 12; t++) {
        if (t < 11) {
            stage((t + 1) * DBK, (t + 1) & 1);
            asm volatile("s_waitcnt vmcnt(8)" ::: "memory");   // tile t landed; t+1 in flight
        } else {
            asm volatile("s_waitcnt vmcnt(0)" ::: "memory");
        }
        __builtin_amdgcn_s_barrier();          // all waves' tile-t loads landed
        __builtin_amdgcn_sched_barrier(0);
        const char* Asb = sm + (t & 1) * 2 * DTILE_B;
        const char* Bsb = Asb + DTILE_B;
        #pragma unroll
        for (int ks = 0; ks < 2; ks++) {
            BF8 af[4], bfr[4];
            #pragma unroll
            for (int mi = 0; mi < 4; mi++) {
                const int row = wr * 64 + mi * 16 + l15;
                const int slot = (ks * 4 + g) ^ (row & 7);
                af[mi].u4 = *(const uint4*)(Asb + row * 128 + slot * 16);
            }
            #pragma unroll
            for (int nj = 0; nj < 4; nj++) {
                const int row = wc * 64 + nj * 16 + l15;
                const int slot = (ks * 4 + g) ^ (row & 7);
                bfr[nj].u4 = *(const uint4*)(Bsb + row * 128 + slot * 16);
            }
            __builtin_amdgcn_s_setprio(1);
            #pragma unroll
            for (int mi = 0; mi < 4; mi++)
                #pragma unroll
                for (int nj = 0; nj < 4; nj++)
                    acc[mi][nj] = mfma16(af[mi].v, bfr[nj].v, acc[mi][nj]);
            __builtin_amdgcn_s_setprio(0);
        }
        __builtin_amdgcn_s_barrier();          // all waves done reading buf t&1
        __builtin_amdgcn_sched_barrier(0);
    }

    float bv[4];
    #pragma unroll
    for (int nj = 0; nj < 4; nj++) bv[nj] = bias[n0 + wc * 64 + nj * 16 + l15];
    #pragma unroll
    for (int mi = 0; mi < 4; mi++) {
        #pragma unroll
        for (int rr = 0; rr < 4; rr++) {
            const int r = m0 + wr * 64 + mi * 16 + 4 * g + rr;
            if (r >= M) continue;
            long orow = r;
            if (REMAP) orow = (long)(r / NPATCH) * NTOK + 1 + (r % NPATCH);
            #pragma unroll
            for (int nj = 0; nj < 4; nj++) {
                const int cc = n0 + wc * 64 + nj * 16 + l15;
                const float val = acc[mi][nj][rr] + bv[nj];
                if (OBF16) ((u16*)Cz)[orow * EMB + cc] = f2bf(val);
                else       ((float*)Cz)[orow * EMB + cc] = val;
            }
        }
    }
}

// ---------------- flash attention v12: 6 waves, 448 blocks, defer-max (r16 best) -----
#define KS_TILE_B 24576   // 32*384*2
#define VTLD 36           // Vt row stride (u16), 72 B (conflict-free; 40 regressed r10)
#define PSLD 40           // Ps row stride (u16)
#define FL_WAVES 6
#define FLASH_LDS (2 * KS_TILE_B + 384 * VTLD * 2 + FL_WAVES * 16 * PSLD * 2)  // 84480

__global__ __launch_bounds__(384)
void flash_mfma(const u16* __restrict__ q, const u16* __restrict__ k,
                const u16* __restrict__ v, u16* __restrict__ o)
{
    extern __shared__ char smem[];
    char* KsB = smem;                                   // [2][32][384] u16 (swizzled)
    u16* Vt = (u16*)(smem + 2 * KS_TILE_B);             // [384][VTLD]
    char* Ps = smem + 2 * KS_TILE_B + 384 * VTLD * 2;   // 6 waves x [16][PSLD]

    // XCD-bijective: 448 = 8 * 56; 7 consecutive works share one (b,h)
    const int wg = blockIdx.x;
    const int work = (wg & 7) * 56 + (wg >> 3);
    const int bh = work / 7, qblk = work % 7;
    const int b = bh >> 1, h = bh & 1;
    const int q0 = qblk * 96;
    const int tid = threadIdx.x;
    const int lane = tid & 63, w = tid >> 6;
    const int l15 = lane & 15, g = lane >> 4;
    const int wbase = (tid & ~63);
    const long base = (long)b * NTOK * EMB + h * HD;

    BF8 qf[12];
    {
        const int qrow = q0 + w * 16 + l15;
        if (qrow < NTOK) {
            const u16* src = q + base + (long)qrow * EMB;
            #pragma unroll
            for (int ds = 0; ds < 12; ds++)
                qf[ds].u4 = *(const uint4*)(src + ds * 32 + g * 8);
        } else {
            #pragma unroll
            for (int ds = 0; ds < 12; ds++) qf[ds].u4 = make_uint4(0, 0, 0, 0);
        }
    }

    auto stage_K = [&](int kv0, int buf) {
        #pragma unroll
        for (int c = 0; c < 4; c++) {
            const int idx = c * 384 + tid;
            const int r = idx / 48, gr = idx % 48;
            const int gsrc = (gr & ~7) | ((gr & 7) ^ (r & 7));
            const int kr = min(kv0 + r, NTOK - 1);
            GLL(k + base + (long)kr * EMB + gsrc * 8,
                KsB + buf * KS_TILE_B + (c * 384 + wbase) * 16);
        }
    };

    const int kp = tid & 15;
    const int dsegA = tid >> 4;          // 0..23
    const int dsegB = 24 + (tid >> 4);   // 24..47
    uint4 vaA, vbA, vaB, vbB;
    auto loadV = [&](int kv0) {
        const int kr0 = kv0 + 2 * kp;
        const u16* v0p = v + base + (long)min(kr0, NTOK - 1) * EMB;
        const u16* v1p = v + base + (long)min(kr0 + 1, NTOK - 1) * EMB;
        vaA = *(const uint4*)(v0p + dsegA * 8);
        vbA = *(const uint4*)(v1p + dsegA * 8);
        vaB = *(const uint4*)(v0p + dsegB * 8);
        vbB = *(const uint4*)(v1p + dsegB * 8);
    };
    auto writeV = [&](int kv0) {
        const int kr0 = kv0 + 2 * kp;
        const bool ok0 = kr0 < NTOK, ok1 = (kr0 + 1) < NTOK;
        {
            const u16* ae = (const u16*)&vaA;
            const u16* be = (const u16*)&vbA;
            #pragma unroll
            for (int e = 0; e < 8; e++) {
                const u32 lo = ok0 ? (u32)ae[e] : 0u;
                const u32 hi = ok1 ? (u32)be[e] : 0u;
                *(u32*)&Vt[(dsegA * 8 + e) * VTLD + 2 * kp] = lo | (hi << 16);
            }
        }
        {
            const u16* ae = (const u16*)&vaB;
            const u16* be = (const u16*)&vbB;
            #pragma unroll
            for (int e = 0; e < 8; e++) {
                const u32 lo = ok0 ? (u32)ae[e] : 0u;
                const u32 hi = ok1 ? (u32)be[e] : 0u;
                *(u32*)&Vt[(dsegB * 8 + e) * VTLD + 2 * kp] = lo | (hi << 16);
            }
        }
    };

    float m_run = -3.0e38f, l_run = 0.f;
    f32x4 oacc[24] = {};

    stage_K(0, 0);
    loadV(0);

    for (int kt = 0; kt < 21; kt++) {
        const int kv0 = kt * 32;
        __syncthreads();   // implicit vmcnt(0): K(kt) in LDS, V(kt) in regs; WAR for Vt
        writeV(kv0);
        __syncthreads();   // Vt(kt)+K(kt) visible; nothing in flight -> free drain
        if (kt < 20) {
            stage_K(kv0 + 32, (kt + 1) & 1);   // async across compute(kt)
            loadV(kv0 + 32);
        }

        const char* kbuf = KsB + (kt & 1) * KS_TILE_B;
        f32x4 sacc[2] = {};
        #pragma unroll
        for (int ds = 0; ds < 12; ds++) {
            const int idx = ds * 4 + g;
            const int slot = (idx & ~7) | ((idx & 7) ^ (l15 & 7));
            BF8 ak0, ak1;
            ak0.u4 = *(const uint4*)(kbuf + l15 * 768 + slot * 16);
            ak1.u4 = *(const uint4*)(kbuf + (16 + l15) * 768 + slot * 16);
            sacc[0] = mfma16(ak0.v, qf[ds].v, sacc[0]);
            sacc[1] = mfma16(ak1.v, qf[ds].v, sacc[1]);
        }

        // ---- mask + online softmax with defer-max (T13, THR=8) ----
        float pe[2][4];
        float mx = -3.0e38f;
        #pragma unroll
        for (int kb = 0; kb < 2; kb++)
            #pragma unroll
            for (int rr = 0; rr < 4; rr++) {
                float s = sacc[kb][rr];
                if (kv0 + kb * 16 + 4 * g + rr >= NTOK) s = -1e30f;
                pe[kb][rr] = s;
                mx = fmaxf(mx, s);
            }
        mx = fmaxf(mx, __shfl_xor(mx, 16, 64));
        mx = fmaxf(mx, __shfl_xor(mx, 32, 64));
        const bool nores = (bool)__all(mx - m_run <= 8.f);
        float m_new = m_run, corr = 1.f;
        if (!nores) {
            m_new = fmaxf(m_run, mx);
            corr = __expf(m_run - m_new);
        }
        float psum = 0.f;
        #pragma unroll
        for (int kb = 0; kb < 2; kb++)
            #pragma unroll
            for (int rr = 0; rr < 4; rr++) {
                pe[kb][rr] = __expf(pe[kb][rr] - m_new);
                psum += pe[kb][rr];
            }
        psum += __shfl_xor(psum, 16, 64);
        psum += __shfl_xor(psum, 32, 64);
        l_run = (nores ? l_run : l_run * corr) + psum;
        m_run = m_new;

        {
            u32* pw = (u32*)(Ps + w * (16 * PSLD * 2) + l15 * (PSLD * 2));
            pw[g * 2]         = pk2(pe[0][0], pe[0][1]);
            pw[g * 2 + 1]     = pk2(pe[0][2], pe[0][3]);
            pw[8 + g * 2]     = pk2(pe[1][0], pe[1][1]);
            pw[8 + g * 2 + 1] = pk2(pe[1][2], pe[1][3]);
        }
        asm volatile("s_waitcnt lgkmcnt(0)" ::: "memory");
        __builtin_amdgcn_sched_barrier(0);
        BF8 pa;
        pa.u4 = *(const uint4*)(Ps + w * (16 * PSLD * 2) + l15 * (PSLD * 2) + g * 16);

        if (!nores) {
            float cb4[4];
            #pragma unroll
            for (int rr = 0; rr < 4; rr++) cb4[rr] = __shfl(corr, 4 * g + rr, 64);
            #pragma unroll
            for (int dc = 0; dc < 24; dc++)
                #pragma unroll
                for (int rr = 0; rr < 4; rr++) oacc[dc][rr] *= cb4[rr];
        }

        #pragma unroll
        for (int dc = 0; dc < 24; dc++) {
            const u16* vp = &Vt[(dc * 16 + l15) * VTLD + g * 8];
            const uint2 lo = *(const uint2*)vp;
            const uint2 hi = *(const uint2*)(vp + 4);
            BF8 vb8;
            vb8.w[0] = lo.x; vb8.w[1] = lo.y; vb8.w[2] = hi.x; vb8.w[3] = hi.y;
            oacc[dc] = mfma16(pa.v, vb8.v, oacc[dc]);
        }
    }

    float linv[4];
    #pragma unroll
    for (int rr = 0; rr < 4; rr++)
        linv[rr] = INV_SQRT_EMB / __shfl(l_run, 4 * g + rr, 64);
    #pragma unroll
    for (int rr = 0; rr < 4; rr++) {
        const int row = q0 + w * 16 + 4 * g + rr;
        if (row < NTOK) {
            u16* dst = o + base + (long)row * EMB;
            #pragma unroll
            for (int dc = 0; dc < 24; dc++)
                dst[dc * 16 + l15] = f2bf(oacc[dc][rr] * linv[rr]);
        }
    }
}

// ---------------- LN2 wave-per-row (bf16 in) + residual-add into t ----------------
__global__ __launch_bounds__(256)
void ln_add_kernel(const u16* __restrict__ in, u16* __restrict__ t,
                   const float* __restrict__ g, const float* __restrict__ be)
{
    const int row = blockIdx.x * 4 + (threadIdx.x >> 6);
    const int lane = threadIdx.x & 63;
    const u16* xp = in + (long)row * EMB;
    float v[12];
    #pragma unroll
    for (int s = 0; s < 3; s++) {
        const uint2 u = *(const uint2*)(xp + lane * 4 + s * 256);
        const u16* e = (const u16*)&u;
        #pragma unroll
        for (int jj = 0; jj < 4; jj++) v[s * 4 + jj] = bf2f(e[jj]);
    }
    float sum = 0.f;
    #pragma unroll
    for (int i = 0; i < 12; i++) sum += v[i];
    const float mu = wave_sum(sum) * (1.f / EMB);
    float vs = 0.f;
    #pragma unroll
    for (int i = 0; i < 12; i++) { v[i] -= mu; vs += v[i] * v[i]; }
    const float rs = rsqrtf(wave_sum(vs) * (1.f / EMB) + LN_EPS);
    u16* o = t + (long)row * EMB;
    #pragma unroll
    for (int s = 0; s < 3; s++) {
        const int col = lane * 4 + s * 256;
        const float4 gv = *(const float4*)(g + col);
        const float4 bv = *(const float4*)(be + col);
        const uint2 told = *(const uint2*)(o + col);
        const u16* te = (const u16*)&told;
        uint2 w;
        w.x = pk2(bf2f(te[0]) + v[s * 4 + 0] * rs * gv.x + bv.x,
                  bf2f(te[1]) + v[s * 4 + 1] * rs * gv.y + bv.y);
        w.y = pk2(bf2f(te[2]) + v[s * 4 + 2] * rs * gv.z + bv.z,
                  bf2f(te[3]) + v[s * 4 + 3] * rs * gv.w + bv.w);
        *(uint2*)(o + col) = w;
    }
}

// ---------------- mean over tokens v2: 8 token-groups x 32 cols ----------------
__global__ __launch_bounds__(256)
void meanpool_kernel(const u16* __restrict__ t, float* __restrict__ m)
{
    __shared__ float red[8][32];
    const int b = blockIdx.y, e0 = blockIdx.x * 32;
    const int tg = threadIdx.x >> 5, col = threadIdx.x & 31;
    const u16* p = t + (long)b * NTOK * EMB + e0 + col;
    float s = 0.f;
    for (int j = tg; j < NTOK; j += 8) s += bf2f(p[(long)j * EMB]);
    red[tg][col] = s;
    __syncthreads();
    if (tg == 0) {
        float a = s;
        #pragma unroll
        for (int i = 1; i < 8; i++) a += red[i][col];
        m[(long)b * EMB + e0 + col] = a * (1.f / NTOK);
    }
}

// ---------------- final GEMM with fused LN3: out = LN3(mp) @ Wf + bf ----------------
// 768 blocks (24 e-chunks x 32 batches); each block recomputes row stats (cheap).
__global__ __launch_bounds__(256)
void final_gemm(const float* __restrict__ mp, const float* __restrict__ g3,
                const float* __restrict__ be3, const float* __restrict__ Wf,
                const float* __restrict__ bfv, float* __restrict__ out)
{
    __shared__ float sml[EMB];
    __shared__ float redb[256];
    __shared__ float red[8][32];
    const int b = blockIdx.y, e0 = blockIdx.x * 32;
    const int tid = threadIdx.x;
    const float* xr = mp + (long)b * EMB;
    const float v0 = xr[tid], v1 = xr[tid + 256], v2 = xr[tid + 512];
    const float mu = blk_sum(v0 + v1 + v2, redb, tid) * (1.f / EMB);
    const float d0 = v0 - mu, d1 = v1 - mu, d2 = v2 - mu;
    const float var = blk_sum(d0 * d0 + d1 * d1 + d2 * d2, redb, tid) * (1.f / EMB);
    const float rs = rsqrtf(var + LN_EPS);
    sml[tid]       = d0 * rs * g3[tid]       + be3[tid];
    sml[tid + 256] = d1 * rs * g3[tid + 256] + be3[tid + 256];
    sml[tid + 512] = d2 * rs * g3[tid + 512] + be3[tid + 512];
    __syncthreads();
    const int kg = tid >> 5, col = tid & 31, e = e0 + col;
    float acc = 0.f;
    const float* wp = Wf + (long)(kg * 96) * EMB + e;
    const float* mpp = sml + kg * 96;
    #pragma unroll 8
    for (int kk = 0; kk < 96; kk++) acc += mpp[kk] * wp[(long)kk * EMB];
    red[kg][col] = acc;
    __syncthreads();
    if (kg == 0) {
        float s = bfv[e];
        #pragma unroll
        for (int i = 0; i < 8; i++) s += red[i][col];
        out[(long)b * EMB + e] = s;
    }
}

extern "C" void kernel_launch(void* const* d_in, const int* in_sizes, int n_in,
                              void* d_out, int out_size, void* d_ws, size_t ws_size,
                              hipStream_t stream) {
    const float* x      = (const float*)d_in[0];
    const float* text   = (const float*)d_in[1];
    const float* Wpatch = (const float*)d_in[2];
    const float* bpatch = (const float*)d_in[3];
    const float* cls    = (const float*)d_in[4];
    const float* g1  = (const float*)d_in[5];
    const float* be1 = (const float*)d_in[6];
    const float* Wq  = (const float*)d_in[7];
    const float* bq  = (const float*)d_in[8];
    const float* Wk  = (const float*)d_in[9];
    const float* bk  = (const float*)d_in[10];
    const float* Wv  = (const float*)d_in[11];
    const float* bv  = (const float*)d_in[12];
    const float* Wp  = (const float*)d_in[13];
    const float* bp  = (const float*)d_in[14];
    const float* g2  = (const float*)d_in[15];
    const float* be2 = (const float*)d_in[16];
    const float* g3  = (const float*)d_in[17];
    const float* be3 = (const float*)d_in[18];
    const float* Wf  = (const float*)d_in[19];
    const float* bf  = (const float*)d_in[20];

    // ws layout (~167 MB): t | h | q | k | v (bf16, 5 x 32.1 MB)
    //  pat aliases qb (dead until QKV); o2 (bf16) aliases kbf (dead post-flash)
    //  Wt bf16 (5 x 1.18 MB) | mp fp32
    char* ws = (char*)d_ws;
    const size_t S2 = (size_t)MROWS * EMB * 2;   // 32,145,408
    u16*   t    = (u16*)ws;
    u16*   hb   = (u16*)(ws + S2);
    u16*   qb   = (u16*)(ws + 2 * S2);
    u16*   kbf  = (u16*)(ws + 3 * S2);
    u16*   vbf  = (u16*)(ws + 4 * S2);
    u16*   o2b  = kbf;   // after flash, k is dead
    u16*   wt   = (u16*)(ws + 5 * S2);
    float* mp   = (float*)(ws + 5 * S2 + (size_t)5 * EMB * EMB * 2);
    u16*   pat  = qb;    // im2col output aliases q
    const size_t WTS = (size_t)EMB * EMB;
    const int DLDS = 2 * 2 * DTILE_B;   // 65536

    // 1) prep: wt transpose + cls/text fill + im2col (one dispatch, 7680 blocks)
    prep_kernel<<<7680, 256, 0, stream>>>(Wpatch, Wq, Wk, Wv, Wp, wt,
                                          cls, text, t, x, pat);
    // 2) patch embed: dense GEMM with row remap -> t   (864 = 8*108 blocks)
    dense_gemm<true, true><<<864, 256, DLDS, stream>>>(
        pat, wt, bpatch, bpatch, bpatch, t, t, t, NBATCH * NPATCH, 6);
    // 3) h = LN1(t), wave-per-row
    ln_h_kernel<<<MROWS / 4, 256, 0, stream>>>(t, hb, g1, be1);
    // 4) fused QKV: nb=18, z selects Wq/Wk/Wv  (2952 = 8*369 blocks)
    dense_gemm<true, false><<<2952, 256, DLDS, stream>>>(
        hb, wt + WTS, bq, bk, bv, qb, kbf, vbf, MROWS, 18);
    // 5) flash attention v12 (o over q), 448 = 8*56 blocks, 384 thr
    flash_mfma<<<448, 384, FLASH_LDS, stream>>>(qb, kbf, vbf, qb);
    // 6) proj -> o2 bf16 (aliases kbf)   (984 = 8*123 blocks)
    dense_gemm<true, false><<<984, 256, DLDS, stream>>>(
        qb, wt + 4 * WTS, bp, bp, bp, o2b, o2b, o2b, MROWS, 6);
    // 7) t += LN2(o2), wave-per-row
    ln_add_kernel<<<MROWS / 4, 256, 0, stream>>>(o2b, t, g2, be2);
    // 8) mean pool v2
    meanpool_kernel<<<dim3(24, NBATCH), 256, 0, stream>>>(t, mp);
    // 9) final GEMM with fused LN3, 768 blocks
    final_gemm<<<dim3(24, NBATCH), 256, 0, stream>>>(mp, g3, be3, Wf, bf, (float*)d_out);
}

// Round 18
// 347.512 us; speedup vs baseline: 1.8935x; 1.0043x over previous
//
#include <hip/hip_runtime.h>
#include <hip/hip_bf16.h>
#include <math.h>

#define EMB 768
#define NTOK 654
#define NPATCH 576
#define NTEXT 77
#define NBATCH 32
#define HD 384
#define MROWS (NBATCH * NTOK)   // 20928
#define LN_EPS 1e-5f
#define INV_SQRT_EMB 0.03608439182435161f

typedef unsigned int u32;
typedef unsigned short u16;
typedef float f32x4 __attribute__((ext_vector_type(4)));
typedef __bf16 bf16x8 __attribute__((ext_vector_type(8)));

union BF8 { uint4 u4; u32 w[4]; bf16x8 v; };

// async global->LDS, 16B per lane; dest = wave-uniform base + lane*16
#define GLL(gsrc, ldst) __builtin_amdgcn_global_load_lds( \
    (const __attribute__((address_space(1))) unsigned int*)(gsrc), \
    (__attribute__((address_space(3))) unsigned int*)(ldst), 16, 0, 0)

// ---------------- helpers ----------------
__device__ __forceinline__ float bf2f(u16 u) {
    union { u32 i; float f; } x; x.i = ((u32)u) << 16; return x.f;
}
__device__ __forceinline__ u16 f2bf(float f) {  // RTNE
    union { float f; u32 i; } x; x.f = f;
    u32 r = x.i + 0x7fffu + ((x.i >> 16) & 1u);
    return (u16)(r >> 16);
}
__device__ __forceinline__ u32 pk2(float lo, float hi) {
    return (u32)f2bf(lo) | ((u32)f2bf(hi) << 16);
}
__device__ __forceinline__ float blk_sum(float v, float* red, int tid) {
    red[tid] = v; __syncthreads();
    #pragma unroll
    for (int s = 128; s > 0; s >>= 1) {
        if (tid < s) red[tid] += red[tid + s];
        __syncthreads();
    }
    float r = red[0]; __syncthreads();
    return r;
}
__device__ __forceinline__ float wave_sum(float v) {
    #pragma unroll
    for (int off = 1; off < 64; off <<= 1) v += __shfl_xor(v, off, 64);
    return v;
}
__device__ __forceinline__ f32x4 mfma16(bf16x8 a, bf16x8 b, f32x4 c) {
    return __builtin_amdgcn_mfma_f32_16x16x32_bf16(a, b, c, 0, 0, 0);
}

// ---------------- prep kernel: wt transpose | cls+text fill | im2col ----------------
__global__ __launch_bounds__(256)
void prep_kernel(const float* __restrict__ W0, const float* __restrict__ W1,
                 const float* __restrict__ W2, const float* __restrict__ W3,
                 const float* __restrict__ W4, u16* __restrict__ wt,
                 const float* __restrict__ cls, const float* __restrict__ text,
                 u16* __restrict__ t,
                 const float* __restrict__ x, u16* __restrict__ patches)
{
    const int id = blockIdx.x;
    const int tid = threadIdx.x;
    if (id < 2880) {
        __shared__ float tile[32][33];
        const int z = id / 576, rem = id % 576;
        const int bi = rem / 24, bj = rem % 24;
        const float* W = (z == 0) ? W0 : (z == 1) ? W1 : (z == 2) ? W2 : (z == 3) ? W3 : W4;
        u16* o = wt + (size_t)z * EMB * EMB;
        const int r = tid >> 5, c = tid & 31;
        #pragma unroll
        for (int i = 0; i < 4; i++)
            tile[r + i * 8][c] = W[(long)(bi * 32 + r + i * 8) * EMB + bj * 32 + c];
        __syncthreads();
        #pragma unroll
        for (int i = 0; i < 4; i++) {
            const int rr = r + i * 8;
            o[(long)(bj * 32 + rr) * EMB + bi * 32 + c] = f2bf(tile[c][rr]);
        }
    } else if (id < 5376) {
        const int id2 = id - 2880;
        const int b = id2 / 78, r = id2 % 78;
        const long trow = (long)b * NTOK + (r == 0 ? 0 : NPATCH + r);
        const float* src = (r == 0) ? cls : text + ((long)b * NTEXT + (r - 1)) * EMB;
        u16* dst = t + trow * EMB;
        #pragma unroll
        for (int s = 0; s < 3; s++) dst[tid + s * 256] = f2bf(src[tid + s * 256]);
    } else {
        const int id3 = id - 5376;
        #pragma unroll
        for (int cc = 0; cc < 3; cc++) {
            const int task = tid + cc * 256;           // 768 tasks = 8 rows x 96 j
            const int row = id3 * 8 + task / 96;
            const int j = task % 96;
            const int bb = row / NPATCH, rem = row % NPATCH;
            const int hh = rem / 24, ww = rem % 24;
            union { u16 s[8]; uint4 v; } out;
            #pragma unroll
            for (int e = 0; e < 8; e++) {
                const int col = j * 8 + e;
                const int p1 = col / 48, r2 = col % 48, p2 = r2 / 3, c = r2 % 3;
                out.s[e] = f2bf(x[((long)(bb * 3 + c) * 384 + hh * 16 + p1) * 384 + ww * 16 + p2]);
            }
            *(uint4*)(patches + (long)row * EMB + j * 8) = out.v;
        }
    }
}

// ---------------- LN1 wave-per-row: t(bf16) -> h(bf16), no barriers ----------------
__global__ __launch_bounds__(256)
void ln_h_kernel(const u16* __restrict__ t, u16* __restrict__ h,
                 const float* __restrict__ g, const float* __restrict__ be)
{
    const int row = blockIdx.x * 4 + (threadIdx.x >> 6);
    const int lane = threadIdx.x & 63;
    const u16* xp = t + (long)row * EMB;
    float v[12];
    #pragma unroll
    for (int s = 0; s < 3; s++) {
        const uint2 u = *(const uint2*)(xp + lane * 4 + s * 256);
        const u16* e = (const u16*)&u;
        #pragma unroll
        for (int jj = 0; jj < 4; jj++) v[s * 4 + jj] = bf2f(e[jj]);
    }
    float sum = 0.f;
    #pragma unroll
    for (int i = 0; i < 12; i++) sum += v[i];
    const float mu = wave_sum(sum) * (1.f / EMB);
    float vs = 0.f;
    #pragma unroll
    for (int i = 0; i < 12; i++) { v[i] -= mu; vs += v[i] * v[i]; }
    const float rs = rsqrtf(wave_sum(vs) * (1.f / EMB) + LN_EPS);
    u16* o = h + (long)row * EMB;
    #pragma unroll
    for (int s = 0; s < 3; s++) {
        const int col = lane * 4 + s * 256;
        const float4 gv = *(const float4*)(g + col);
        const float4 bv = *(const float4*)(be + col);
        uint2 w;
        w.x = pk2(v[s * 4 + 0] * rs * gv.x + bv.x, v[s * 4 + 1] * rs * gv.y + bv.y);
        w.y = pk2(v[s * 4 + 2] * rs * gv.z + bv.z, v[s * 4 + 3] * rs * gv.w + bv.w);
        *(uint2*)(o + col) = w;
    }
}

// ---------------- dense MFMA GEMM v4: GLL dbuf + counted vmcnt; setprio removed ------
// (m190: s_setprio on lockstep barrier-synced GEMM waves measured negative.)
#define DBK 64
#define DTILE_B (128 * DBK * 2)   // 16384 B per operand tile

template<bool OBF16, bool REMAP>
__global__ __launch_bounds__(256)
void dense_gemm(const u16* __restrict__ A, const u16* __restrict__ Bt,
                const float* __restrict__ b0, const float* __restrict__ b1,
                const float* __restrict__ b2,
                void* __restrict__ C0, void* __restrict__ C1, void* __restrict__ C2,
                int M, int nb)
{
    extern __shared__ char sm[];   // [2][A|B][128][64]u16 = 65536 B
    const int cpx = gridDim.x >> 3;
    const int wg = blockIdx.x;
    const int work = (wg & 7) * cpx + (wg >> 3);
    const int cb = work % nb;
    const int m0 = (work / nb) * 128;
    const int z  = cb / 6;
    const int n0 = (cb % 6) * 128;
    const u16* Btz = Bt + (size_t)z * EMB * EMB;
    const float* bias = (z == 0) ? b0 : (z == 1) ? b1 : b2;
    void* Cz = (z == 0) ? C0 : (z == 1) ? C1 : C2;

    const int tid = threadIdx.x;
    const int lane = tid & 63, w = tid >> 6, wr = w >> 1, wc = w & 1;
    const int l15 = lane & 15, g = lane >> 4;
    const int wbase = (tid & ~63);

    f32x4 acc[4][4] = {};

    auto stage = [&](int k0, int buf) {
        char* dst = sm + buf * 2 * DTILE_B;
        #pragma unroll
        for (int c = 0; c < 4; c++) {
            const int idx = c * 256 + tid;
            const int r = idx >> 3, s = idx & 7;
            const int gs = s ^ (r & 7);
            const int ar = min(m0 + r, M - 1);
            GLL(A + (long)ar * EMB + k0 + gs * 8, dst + (c * 256 + wbase) * 16);
        }
        #pragma unroll
        for (int c = 0; c < 4; c++) {
            const int idx = c * 256 + tid;
            const int r = idx >> 3, s = idx & 7;
            const int gs = s ^ (r & 7);
            GLL(Btz + (long)(n0 + r) * EMB + k0 + gs * 8,
                dst + DTILE_B + (c * 256 + wbase) * 16);
        }
    };

    stage(0, 0);
    for (int t = 0; t < 12; t++) {
        if (t < 11) {
            stage((t + 1) * DBK, (t + 1) & 1);
            asm volatile("s_waitcnt vmcnt(8)" ::: "memory");   // tile t landed; t+1 in flight
        } else {
            asm volatile("s_waitcnt vmcnt(0)" ::: "memory");
        }
        __builtin_amdgcn_s_barrier();          // all waves' tile-t loads landed
        __builtin_amdgcn_sched_barrier(0);
        const char* Asb = sm + (t & 1) * 2 * DTILE_B;
        const char* Bsb = Asb + DTILE_B;
        #pragma unroll
        for (int ks = 0; ks < 2; ks++) {
            BF8 af[4], bfr[4];
            #pragma unroll
            for (int mi = 0; mi < 4; mi++) {
                const int row = wr * 64 + mi * 16 + l15;
                const int slot = (ks * 4 + g) ^ (row & 7);
                af[mi].u4 = *(const uint4*)(Asb + row * 128 + slot * 16);
            }
            #pragma unroll
            for (int nj = 0; nj < 4; nj++) {
                const int row = wc * 64 + nj * 16 + l15;
                const int slot = (ks * 4 + g) ^ (row & 7);
                bfr[nj].u4 = *(const uint4*)(Bsb + row * 128 + slot * 16);
            }
            #pragma unroll
            for (int mi = 0; mi < 4; mi++)
                #pragma unroll
                for (int nj = 0; nj < 4; nj++)
                    acc[mi][nj] = mfma16(af[mi].v, bfr[nj].v, acc[mi][nj]);
        }
        __builtin_amdgcn_s_barrier();          // all waves done reading buf t&1
        __builtin_amdgcn_sched_barrier(0);
    }

    float bv[4];
    #pragma unroll
    for (int nj = 0; nj < 4; nj++) bv[nj] = bias[n0 + wc * 64 + nj * 16 + l15];
    #pragma unroll
    for (int mi = 0; mi < 4; mi++) {
        #pragma unroll
        for (int rr = 0; rr < 4; rr++) {
            const int r = m0 + wr * 64 + mi * 16 + 4 * g + rr;
            if (r >= M) continue;
            long orow = r;
            if (REMAP) orow = (long)(r / NPATCH) * NTOK + 1 + (r % NPATCH);
            #pragma unroll
            for (int nj = 0; nj < 4; nj++) {
                const int cc = n0 + wc * 64 + nj * 16 + l15;
                const float val = acc[mi][nj][rr] + bv[nj];
                if (OBF16) ((u16*)Cz)[orow * EMB + cc] = f2bf(val);
                else       ((float*)Cz)[orow * EMB + cc] = val;
            }
        }
    }
}

// ---------------- flash attention v12: 6 waves, 448 blocks, defer-max (r16 best) -----
#define KS_TILE_B 24576   // 32*384*2
#define VTLD 36           // Vt row stride (u16), 72 B (conflict-free; 40 regressed r10)
#define PSLD 40           // Ps row stride (u16)
#define FL_WAVES 6
#define FLASH_LDS (2 * KS_TILE_B + 384 * VTLD * 2 + FL_WAVES * 16 * PSLD * 2)  // 84480

__global__ __launch_bounds__(384)
void flash_mfma(const u16* __restrict__ q, const u16* __restrict__ k,
                const u16* __restrict__ v, u16* __restrict__ o)
{
    extern __shared__ char smem[];
    char* KsB = smem;                                   // [2][32][384] u16 (swizzled)
    u16* Vt = (u16*)(smem + 2 * KS_TILE_B);             // [384][VTLD]
    char* Ps = smem + 2 * KS_TILE_B + 384 * VTLD * 2;   // 6 waves x [16][PSLD]

    // XCD-bijective: 448 = 8 * 56; 7 consecutive works share one (b,h)
    const int wg = blockIdx.x;
    const int work = (wg & 7) * 56 + (wg >> 3);
    const int bh = work / 7, qblk = work % 7;
    const int b = bh >> 1, h = bh & 1;
    const int q0 = qblk * 96;
    const int tid = threadIdx.x;
    const int lane = tid & 63, w = tid >> 6;
    const int l15 = lane & 15, g = lane >> 4;
    const int wbase = (tid & ~63);
    const long base = (long)b * NTOK * EMB + h * HD;

    BF8 qf[12];
    {
        const int qrow = q0 + w * 16 + l15;
        if (qrow < NTOK) {
            const u16* src = q + base + (long)qrow * EMB;
            #pragma unroll
            for (int ds = 0; ds < 12; ds++)
                qf[ds].u4 = *(const uint4*)(src + ds * 32 + g * 8);
        } else {
            #pragma unroll
            for (int ds = 0; ds < 12; ds++) qf[ds].u4 = make_uint4(0, 0, 0, 0);
        }
    }

    auto stage_K = [&](int kv0, int buf) {
        #pragma unroll
        for (int c = 0; c < 4; c++) {
            const int idx = c * 384 + tid;
            const int r = idx / 48, gr = idx % 48;
            const int gsrc = (gr & ~7) | ((gr & 7) ^ (r & 7));
            const int kr = min(kv0 + r, NTOK - 1);
            GLL(k + base + (long)kr * EMB + gsrc * 8,
                KsB + buf * KS_TILE_B + (c * 384 + wbase) * 16);
        }
    };

    const int kp = tid & 15;
    const int dsegA = tid >> 4;          // 0..23
    const int dsegB = 24 + (tid >> 4);   // 24..47
    uint4 vaA, vbA, vaB, vbB;
    auto loadV = [&](int kv0) {
        const int kr0 = kv0 + 2 * kp;
        const u16* v0p = v + base + (long)min(kr0, NTOK - 1) * EMB;
        const u16* v1p = v + base + (long)min(kr0 + 1, NTOK - 1) * EMB;
        vaA = *(const uint4*)(v0p + dsegA * 8);
        vbA = *(const uint4*)(v1p + dsegA * 8);
        vaB = *(const uint4*)(v0p + dsegB * 8);
        vbB = *(const uint4*)(v1p + dsegB * 8);
    };
    auto writeV = [&](int kv0) {
        const int kr0 = kv0 + 2 * kp;
        const bool ok0 = kr0 < NTOK, ok1 = (kr0 + 1) < NTOK;
        {
            const u16* ae = (const u16*)&vaA;
            const u16* be = (const u16*)&vbA;
            #pragma unroll
            for (int e = 0; e < 8; e++) {
                const u32 lo = ok0 ? (u32)ae[e] : 0u;
                const u32 hi = ok1 ? (u32)be[e] : 0u;
                *(u32*)&Vt[(dsegA * 8 + e) * VTLD + 2 * kp] = lo | (hi << 16);
            }
        }
        {
            const u16* ae = (const u16*)&vaB;
            const u16* be = (const u16*)&vbB;
            #pragma unroll
            for (int e = 0; e < 8; e++) {
                const u32 lo = ok0 ? (u32)ae[e] : 0u;
                const u32 hi = ok1 ? (u32)be[e] : 0u;
                *(u32*)&Vt[(dsegB * 8 + e) * VTLD + 2 * kp] = lo | (hi << 16);
            }
        }
    };

    float m_run = -3.0e38f, l_run = 0.f;
    f32x4 oacc[24] = {};

    stage_K(0, 0);
    loadV(0);

    for (int kt = 0; kt < 21; kt++) {
        const int kv0 = kt * 32;
        __syncthreads();   // implicit vmcnt(0): K(kt) in LDS, V(kt) in regs; WAR for Vt
        writeV(kv0);
        __syncthreads();   // Vt(kt)+K(kt) visible; nothing in flight -> free drain
        if (kt < 20) {
            stage_K(kv0 + 32, (kt + 1) & 1);   // async across compute(kt)
            loadV(kv0 + 32);
        }

        const char* kbuf = KsB + (kt & 1) * KS_TILE_B;
        f32x4 sacc[2] = {};
        #pragma unroll
        for (int ds = 0; ds < 12; ds++) {
            const int idx = ds * 4 + g;
            const int slot = (idx & ~7) | ((idx & 7) ^ (l15 & 7));
            BF8 ak0, ak1;
            ak0.u4 = *(const uint4*)(kbuf + l15 * 768 + slot * 16);
            ak1.u4 = *(const uint4*)(kbuf + (16 + l15) * 768 + slot * 16);
            sacc[0] = mfma16(ak0.v, qf[ds].v, sacc[0]);
            sacc[1] = mfma16(ak1.v, qf[ds].v, sacc[1]);
        }

        // ---- mask + online softmax with defer-max (T13, THR=8) ----
        float pe[2][4];
        float mx = -3.0e38f;
        #pragma unroll
        for (int kb = 0; kb < 2; kb++)
            #pragma unroll
            for (int rr = 0; rr < 4; rr++) {
                float s = sacc[kb][rr];
                if (kv0 + kb * 16 + 4 * g + rr >= NTOK) s = -1e30f;
                pe[kb][rr] = s;
                mx = fmaxf(mx, s);
            }
        mx = fmaxf(mx, __shfl_xor(mx, 16, 64));
        mx = fmaxf(mx, __shfl_xor(mx, 32, 64));
        const bool nores = (bool)__all(mx - m_run <= 8.f);
        float m_new = m_run, corr = 1.f;
        if (!nores) {
            m_new = fmaxf(m_run, mx);
            corr = __expf(m_run - m_new);
        }
        float psum = 0.f;
        #pragma unroll
        for (int kb = 0; kb < 2; kb++)
            #pragma unroll
            for (int rr = 0; rr < 4; rr++) {
                pe[kb][rr] = __expf(pe[kb][rr] - m_new);
                psum += pe[kb][rr];
            }
        psum += __shfl_xor(psum, 16, 64);
        psum += __shfl_xor(psum, 32, 64);
        l_run = (nores ? l_run : l_run * corr) + psum;
        m_run = m_new;

        {
            u32* pw = (u32*)(Ps + w * (16 * PSLD * 2) + l15 * (PSLD * 2));
            pw[g * 2]         = pk2(pe[0][0], pe[0][1]);
            pw[g * 2 + 1]     = pk2(pe[0][2], pe[0][3]);
            pw[8 + g * 2]     = pk2(pe[1][0], pe[1][1]);
            pw[8 + g * 2 + 1] = pk2(pe[1][2], pe[1][3]);
        }
        asm volatile("s_waitcnt lgkmcnt(0)" ::: "memory");
        __builtin_amdgcn_sched_barrier(0);
        BF8 pa;
        pa.u4 = *(const uint4*)(Ps + w * (16 * PSLD * 2) + l15 * (PSLD * 2) + g * 16);

        if (!nores) {
            float cb4[4];
            #pragma unroll
            for (int rr = 0; rr < 4; rr++) cb4[rr] = __shfl(corr, 4 * g + rr, 64);
            #pragma unroll
            for (int dc = 0; dc < 24; dc++)
                #pragma unroll
                for (int rr = 0; rr < 4; rr++) oacc[dc][rr] *= cb4[rr];
        }

        #pragma unroll
        for (int dc = 0; dc < 24; dc++) {
            const u16* vp = &Vt[(dc * 16 + l15) * VTLD + g * 8];
            const uint2 lo = *(const uint2*)vp;
            const uint2 hi = *(const uint2*)(vp + 4);
            BF8 vb8;
            vb8.w[0] = lo.x; vb8.w[1] = lo.y; vb8.w[2] = hi.x; vb8.w[3] = hi.y;
            oacc[dc] = mfma16(pa.v, vb8.v, oacc[dc]);
        }
    }

    float linv[4];
    #pragma unroll
    for (int rr = 0; rr < 4; rr++)
        linv[rr] = INV_SQRT_EMB / __shfl(l_run, 4 * g + rr, 64);
    #pragma unroll
    for (int rr = 0; rr < 4; rr++) {
        const int row = q0 + w * 16 + 4 * g + rr;
        if (row < NTOK) {
            u16* dst = o + base + (long)row * EMB;
            #pragma unroll
            for (int dc = 0; dc < 24; dc++)
                dst[dc * 16 + l15] = f2bf(oacc[dc][rr] * linv[rr]);
        }
    }
}

// ---------------- LN2 wave-per-row (bf16 in) + residual-add into t ----------------
__global__ __launch_bounds__(256)
void ln_add_kernel(const u16* __restrict__ in, u16* __restrict__ t,
                   const float* __restrict__ g, const float* __restrict__ be)
{
    const int row = blockIdx.x * 4 + (threadIdx.x >> 6);
    const int lane = threadIdx.x & 63;
    const u16* xp = in + (long)row * EMB;
    float v[12];
    #pragma unroll
    for (int s = 0; s < 3; s++) {
        const uint2 u = *(const uint2*)(xp + lane * 4 + s * 256);
        const u16* e = (const u16*)&u;
        #pragma unroll
        for (int jj = 0; jj < 4; jj++) v[s * 4 + jj] = bf2f(e[jj]);
    }
    float sum = 0.f;
    #pragma unroll
    for (int i = 0; i < 12; i++) sum += v[i];
    const float mu = wave_sum(sum) * (1.f / EMB);
    float vs = 0.f;
    #pragma unroll
    for (int i = 0; i < 12; i++) { v[i] -= mu; vs += v[i] * v[i]; }
    const float rs = rsqrtf(wave_sum(vs) * (1.f / EMB) + LN_EPS);
    u16* o = t + (long)row * EMB;
    #pragma unroll
    for (int s = 0; s < 3; s++) {
        const int col = lane * 4 + s * 256;
        const float4 gv = *(const float4*)(g + col);
        const float4 bv = *(const float4*)(be + col);
        const uint2 told = *(const uint2*)(o + col);
        const u16* te = (const u16*)&told;
        uint2 w;
        w.x = pk2(bf2f(te[0]) + v[s * 4 + 0] * rs * gv.x + bv.x,
                  bf2f(te[1]) + v[s * 4 + 1] * rs * gv.y + bv.y);
        w.y = pk2(bf2f(te[2]) + v[s * 4 + 2] * rs * gv.z + bv.z,
                  bf2f(te[3]) + v[s * 4 + 3] * rs * gv.w + bv.w);
        *(uint2*)(o + col) = w;
    }
}

// ---------------- mean over tokens v2: 8 token-groups x 32 cols ----------------
__global__ __launch_bounds__(256)
void meanpool_kernel(const u16* __restrict__ t, float* __restrict__ m)
{
    __shared__ float red[8][32];
    const int b = blockIdx.y, e0 = blockIdx.x * 32;
    const int tg = threadIdx.x >> 5, col = threadIdx.x & 31;
    const u16* p = t + (long)b * NTOK * EMB + e0 + col;
    float s = 0.f;
    for (int j = tg; j < NTOK; j += 8) s += bf2f(p[(long)j * EMB]);
    red[tg][col] = s;
    __syncthreads();
    if (tg == 0) {
        float a = s;
        #pragma unroll
        for (int i = 1; i < 8; i++) a += red[i][col];
        m[(long)b * EMB + e0 + col] = a * (1.f / NTOK);
    }
}

// ---------------- final GEMM with fused LN3: out = LN3(mp) @ Wf + bf ----------------
__global__ __launch_bounds__(256)
void final_gemm(const float* __restrict__ mp, const float* __restrict__ g3,
                const float* __restrict__ be3, const float* __restrict__ Wf,
                const float* __restrict__ bfv, float* __restrict__ out)
{
    __shared__ float sml[EMB];
    __shared__ float redb[256];
    __shared__ float red[8][32];
    const int b = blockIdx.y, e0 = blockIdx.x * 32;
    const int tid = threadIdx.x;
    const float* xr = mp + (long)b * EMB;
    const float v0 = xr[tid], v1 = xr[tid + 256], v2 = xr[tid + 512];
    const float mu = blk_sum(v0 + v1 + v2, redb, tid) * (1.f / EMB);
    const float d0 = v0 - mu, d1 = v1 - mu, d2 = v2 - mu;
    const float var = blk_sum(d0 * d0 + d1 * d1 + d2 * d2, redb, tid) * (1.f / EMB);
    const float rs = rsqrtf(var + LN_EPS);
    sml[tid]       = d0 * rs * g3[tid]       + be3[tid];
    sml[tid + 256] = d1 * rs * g3[tid + 256] + be3[tid + 256];
    sml[tid + 512] = d2 * rs * g3[tid + 512] + be3[tid + 512];
    __syncthreads();
    const int kg = tid >> 5, col = tid & 31, e = e0 + col;
    float acc = 0.f;
    const float* wp = Wf + (long)(kg * 96) * EMB + e;
    const float* mpp = sml + kg * 96;
    #pragma unroll 8
    for (int kk = 0; kk < 96; kk++) acc += mpp[kk] * wp[(long)kk * EMB];
    red[kg][col] = acc;
    __syncthreads();
    if (kg == 0) {
        float s = bfv[e];
        #pragma unroll
        for (int i = 0; i < 8; i++) s += red[i][col];
        out[(long)b * EMB + e] = s;
    }
}

extern "C" void kernel_launch(void* const* d_in, const int* in_sizes, int n_in,
                              void* d_out, int out_size, void* d_ws, size_t ws_size,
                              hipStream_t stream) {
    const float* x      = (const float*)d_in[0];
    const float* text   = (const float*)d_in[1];
    const float* Wpatch = (const float*)d_in[2];
    const float* bpatch = (const float*)d_in[3];
    const float* cls    = (const float*)d_in[4];
    const float* g1  = (const float*)d_in[5];
    const float* be1 = (const float*)d_in[6];
    const float* Wq  = (const float*)d_in[7];
    const float* bq  = (const float*)d_in[8];
    const float* Wk  = (const float*)d_in[9];
    const float* bk  = (const float*)d_in[10];
    const float* Wv  = (const float*)d_in[11];
    const float* bv  = (const float*)d_in[12];
    const float* Wp  = (const float*)d_in[13];
    const float* bp  = (const float*)d_in[14];
    const float* g2  = (const float*)d_in[15];
    const float* be2 = (const float*)d_in[16];
    const float* g3  = (const float*)d_in[17];
    const float* be3 = (const float*)d_in[18];
    const float* Wf  = (const float*)d_in[19];
    const float* bf  = (const float*)d_in[20];

    // ws layout (~167 MB): t | h | q | k | v (bf16, 5 x 32.1 MB)
    //  pat aliases qb (dead until QKV); o2 (bf16) aliases kbf (dead post-flash)
    //  Wt bf16 (5 x 1.18 MB) | mp fp32
    char* ws = (char*)d_ws;
    const size_t S2 = (size_t)MROWS * EMB * 2;   // 32,145,408
    u16*   t    = (u16*)ws;
    u16*   hb   = (u16*)(ws + S2);
    u16*   qb   = (u16*)(ws + 2 * S2);
    u16*   kbf  = (u16*)(ws + 3 * S2);
    u16*   vbf  = (u16*)(ws + 4 * S2);
    u16*   o2b  = kbf;   // after flash, k is dead
    u16*   wt   = (u16*)(ws + 5 * S2);
    float* mp   = (float*)(ws + 5 * S2 + (size_t)5 * EMB * EMB * 2);
    u16*   pat  = qb;    // im2col output aliases q
    const size_t WTS = (size_t)EMB * EMB;
    const int DLDS = 2 * 2 * DTILE_B;   // 65536

    // 1) prep: wt transpose + cls/text fill + im2col (one dispatch, 7680 blocks)
    prep_kernel<<<7680, 256, 0, stream>>>(Wpatch, Wq, Wk, Wv, Wp, wt,
                                          cls, text, t, x, pat);
    // 2) patch embed: dense GEMM with row remap -> t   (864 = 8*108 blocks)
    dense_gemm<true, true><<<864, 256, DLDS, stream>>>(
        pat, wt, bpatch, bpatch, bpatch, t, t, t, NBATCH * NPATCH, 6);
    // 3) h = LN1(t), wave-per-row
    ln_h_kernel<<<MROWS / 4, 256, 0, stream>>>(t, hb, g1, be1);
    // 4) fused QKV: nb=18, z selects Wq/Wk/Wv  (2952 = 8*369 blocks)
    dense_gemm<true, false><<<2952, 256, DLDS, stream>>>(
        hb, wt + WTS, bq, bk, bv, qb, kbf, vbf, MROWS, 18);
    // 5) flash attention v12 (o over q), 448 = 8*56 blocks, 384 thr
    flash_mfma<<<448, 384, FLASH_LDS, stream>>>(qb, kbf, vbf, qb);
    // 6) proj -> o2 bf16 (aliases kbf)   (984 = 8*123 blocks)
    dense_gemm<true, false><<<984, 256, DLDS, stream>>>(
        qb, wt + 4 * WTS, bp, bp, bp, o2b, o2b, o2b, MROWS, 6);
    // 7) t += LN2(o2), wave-per-row
    ln_add_kernel<<<MROWS / 4, 256, 0, stream>>>(o2b, t, g2, be2);
    // 8) mean pool v2
    meanpool_kernel<<<dim3(24, NBATCH), 256, 0, stream>>>(t, mp);
    // 9) final GEMM with fused LN3, 768 blocks
    final_gemm<<<dim3(24, NBATCH), 256, 0, stream>>>(mp, g3, be3, Wf, bf, (float*)d_out);
}